// Round 2
// baseline (1185.404 us; speedup 1.0000x reference)
//
#include <hip/hip_runtime.h>
#include <stdint.h>

#define DEVI __device__ __forceinline__

constexpr int N_   = 50000;
constexpr int ESC  = 600000;
constexpr int EBB  = 100000;
constexpr int NRES = 21;
constexpr float PI_F = 3.14159f;

// ---------- dtype helpers (runtime f32-vs-bf16 dispatch) ----------
DEVI float bf2f(unsigned short u){ return __uint_as_float(((unsigned)u)<<16); }
DEVI unsigned short f2bf(float f){
  unsigned x = __float_as_uint(f);
  unsigned r = (x + 0x7FFFu + ((x>>16)&1u))>>16;
  return (unsigned short)r;
}
DEVI float ldin(const void* p, long i, int f32){
  return f32 ? ((const float*)p)[i] : bf2f(((const unsigned short*)p)[i]);
}
DEVI void stout(void* p, long i, float v, int f32){
  if(f32) ((float*)p)[i]=v; else ((unsigned short*)p)[i]=f2bf(v);
}
DEVI float wrapf(float a){
  float t = a + PI_F;
  const float TP = 2.f*PI_F;
  t -= floorf(t/TP)*TP;
  return t - PI_F;
}

// ---------- weight arena offsets (floats) ----------
constexpr int OW_SC_LN_G=0;
constexpr int OW_SC_LN_B=OW_SC_LN_G+19;
constexpr int OW_SC_W  = OW_SC_LN_B+19;
constexpr int OW_SC_B  = OW_SC_W+19*128;
constexpr int OW_BB_LN_G=OW_SC_B+128;
constexpr int OW_BB_LN_B=OW_BB_LN_G+38;
constexpr int OW_BB_W = OW_BB_LN_B+38;
constexpr int OW_BB_B = OW_BB_W+38*128;
constexpr int OW_E_LN_G=OW_BB_B+128;
constexpr int OW_E_LN_B=OW_E_LN_G+66;
constexpr int OW_EW1 = OW_E_LN_B+66;
constexpr int OW_EB1 = OW_EW1+66*128;
constexpr int OW_GW  = OW_EB1+128;
constexpr int OW_GB  = OW_GW+128*128;
constexpr int OW_BGW = OW_GB+128;
constexpr int OW_BGB = OW_BGW+128*128;
constexpr int OW_IW1 = OW_BGB+128;
constexpr int OW_IB1 = OW_IW1+256*128;
constexpr int OW_IW2 = OW_IB1+128;
constexpr int OW_IB2 = OW_IW2+128*128;
constexpr int OW_AW  = OW_IB2+128;
constexpr int OW_AB  = OW_AW+128;
constexpr int OW_BAW = OW_AB+1;
constexpr int OW_BAB = OW_BAW+128;
constexpr int OW_CW  = OW_BAB+1;
constexpr int OW_CB  = OW_CW+128*3;
constexpr int OW_XW  = OW_CB+3;
constexpr int OW_XB  = OW_XW+128*3;
constexpr int OW_RES = OW_XB+3;
constexpr int OW_TOT = OW_RES+21*32;

// dv layout: A(128),C(128),G(128),B(128),v2m(128),usm(128),udm(128), dv[896]=eb2 mean, dv[897]=eub mean

// ---------- kernels ----------
__global__ void k_detect(const void* vcom, int* flag){
  // f32 data read as bf16 -> even uint16s are f32 low-mantissa bits (wild exponents)
  const unsigned short* u = (const unsigned short*)vcom;
  int insane=0;
  for(int i=0;i<64;i+=2){
    float f = bf2f(u[i]);
    float a = fabsf(f);
    if(!(a<1e5f) || (a!=0.0f && a<1e-5f)) insane++;
  }
  *flag = (insane>=8)?1:0;
}

struct CvtArgs { const void* src[29]; };

__global__ void k_cvtw(CvtArgs a, const int* flag, float* w){
  static constexpr int offs[30] = {
    OW_SC_LN_G,OW_SC_LN_B,OW_SC_W,OW_SC_B,OW_BB_LN_G,OW_BB_LN_B,OW_BB_W,OW_BB_B,
    OW_E_LN_G,OW_E_LN_B,OW_EW1,OW_EB1,OW_GW,OW_GB,OW_BGW,OW_BGB,OW_IW1,OW_IB1,
    OW_IW2,OW_IB2,OW_AW,OW_AB,OW_BAW,OW_BAB,OW_CW,OW_CB,OW_XW,OW_XB,OW_RES,OW_TOT};
  int f32=*flag;
  for(int t=blockIdx.x*blockDim.x+threadIdx.x; t<OW_TOT; t+=gridDim.x*blockDim.x){
    int s=0;
    while(t>=offs[s+1]) s++;
    w[t]=ldin(a.src[s], t-offs[s], f32);
  }
}

__global__ void k_prevec(const float* w, const void* eW2, const void* eb2,
                         const void* euW, const void* eub, const int* flag, float* dv){
  int j=threadIdx.x; int f32=*flag;
  const float* g=w+OW_E_LN_G; const float* b=w+OW_E_LN_B; const float* W1=w+OW_EW1;
  float A=g[0]*W1[j], C=g[1]*W1[128+j];
  float G=0,B=0;
  for(int i=0;i<66;i++){ float wij=W1[i*128+j]; G+=g[i]*wij; B+=b[i]*wij; }
  B += w[OW_EB1+j];
  float v2=0; for(int k=0;k<128;k++) v2+=ldin(eW2,(long)j*128+k,f32);
  float us=0,ud=0;
  for(int k=0;k<128;k++){ us+=ldin(euW,(long)j*128+k,f32); ud+=ldin(euW,(long)(128+j)*128+k,f32); }
  dv[j]=A; dv[128+j]=C; dv[256+j]=G; dv[384+j]=B;
  dv[512+j]=v2*(1.f/128.f); dv[640+j]=us*(1.f/128.f); dv[768+j]=ud*(1.f/128.f);
  if(j==0){
    float s=0,t=0;
    for(int k=0;k<128;k++){ s+=ldin(eb2,k,f32); t+=ldin(eub,k,f32); }
    dv[896]=s*(1.f/128.f); dv[897]=t*(1.f/128.f);
  }
}

__global__ void k_preP(const float* w, float* P, float* sp, float* qp){
  __shared__ float pv[64];
  int c=blockIdx.x, ri=c/NRES, rj=c%NRES, j=threadIdx.x;
  const float* res=w+OW_RES;
  if(j<32) pv[j]=res[ri*32+j];
  else if(j<64) pv[j]=res[rj*32+(j-32)];
  __syncthreads();
  const float* g=w+OW_E_LN_G; const float* W1=w+OW_EW1;
  float s=0;
  for(int i=0;i<64;i++) s += pv[i]*g[2+i]*W1[(2+i)*128+j];
  P[c*128+j]=s;
  if(j==0){ float a=0,q=0; for(int i=0;i<64;i++){a+=pv[i]; q+=pv[i]*pv[i];} sp[c]=a; qp[c]=q; }
}

__global__ void k_feat_sc(const void* vcom, const void* sbfchi, const int* flag,
                          const float* w, float* hat_h){
  __shared__ float x[19];
  int n=blockIdx.x, j=threadIdx.x, f32=*flag;
  if(j<3) x[j]=ldin(vcom,(long)n*3+j,f32);
  else if(j<19) x[j]=ldin(sbfchi,(long)n*16+(j-3),f32);
  __syncthreads();
  float m=0; for(int i=0;i<19;i++) m+=x[i]; m*=(1.f/19.f);
  float v=0; for(int i=0;i<19;i++){float d=x[i]-m; v+=d*d;} v*=(1.f/19.f);
  float istd=rsqrtf(v+1e-5f);
  float acc=w[OW_SC_B+j];
  for(int i=0;i<19;i++){
    float xn=(x[i]-m)*istd*w[OW_SC_LN_G+i]+w[OW_SC_LN_B+i];
    acc+=xn*w[OW_SC_W+i*128+j];
  }
  hat_h[(long)n*128+j]=acc;
}

__global__ void k_feat_bb(const void* xca, const void* vcb, const void* sphi, const void* spsi,
                          const int* flag, const float* w, float* h){
  __shared__ float x[38];
  int n=blockIdx.x, j=threadIdx.x, f32=*flag;
  if(j<3) x[j]=ldin(xca,(long)n*3+j,f32);
  else if(j<6) x[j]=ldin(vcb,(long)n*3+(j-3),f32);
  else if(j<22) x[j]=ldin(sphi,(long)n*16+(j-6),f32);
  else if(j<38) x[j]=ldin(spsi,(long)n*16+(j-22),f32);
  __syncthreads();
  float m=0; for(int i=0;i<38;i++) m+=x[i]; m*=(1.f/38.f);
  float v=0; for(int i=0;i<38;i++){float d=x[i]-m; v+=d*d;} v*=(1.f/38.f);
  float istd=rsqrtf(v+1e-5f);
  float acc=w[OW_BB_B+j];
  for(int i=0;i<38;i++){
    float xn=(x[i]-m)*istd*w[OW_BB_LN_G+i]+w[OW_BB_LN_B+i];
    acc+=xn*w[OW_BB_W+i*128+j];
  }
  h[(long)n*128+j]=acc;
}

// ---------- CSR build ----------
__global__ void k_count(const int* dst, int E, int* counts){
  int e=blockIdx.x*blockDim.x+threadIdx.x;
  if(e<E) atomicAdd(&counts[dst[e]],1);
}
__global__ void k_scan1(const int* in, int n, int* excl, int* part){
  __shared__ int s[1024];
  int i=blockIdx.x*1024+threadIdx.x;
  int v=(i<n)?in[i]:0;
  s[threadIdx.x]=v; __syncthreads();
  for(int off=1; off<1024; off<<=1){
    int t=(threadIdx.x>=off)?s[threadIdx.x-off]:0;
    __syncthreads();
    s[threadIdx.x]+=t; __syncthreads();
  }
  if(i<n) excl[i]=s[threadIdx.x]-v;
  if(threadIdx.x==1023) part[blockIdx.x]=s[1023];
}
__global__ void k_scan2(int* part, int nb){
  if(threadIdx.x==0 && blockIdx.x==0){
    int run=0;
    for(int b=0;b<nb;b++){ int t=part[b]; part[b]=run; run+=t; }
  }
}
__global__ void k_scan3(int* rp, int n, const int* part, int E){
  int i=blockIdx.x*1024+threadIdx.x;
  if(i<n) rp[i]+=part[blockIdx.x];
  if(i==n) rp[n]=E;
}
__global__ void k_fill(const int* src, const int* dst, int E, const int* rp,
                       int* cursor, int* csr_src, int* csr_eid){
  int e=blockIdx.x*blockDim.x+threadIdx.x;
  if(e>=E) return;
  int d=dst[e];
  int p=rp[d]+atomicAdd(&cursor[d],1);
  csr_src[p]=src[e];
  if(csr_eid) csr_eid[p]=e;
}
// deterministic order: per-node insertion sort (key unique eid, or src value for bb)
__global__ void k_sort2(const int* rp, int* key, int* val, int n){
  int v=blockIdx.x*blockDim.x+threadIdx.x;
  if(v>=n) return;
  int e0=rp[v], e1=rp[v+1];
  for(int i=e0+1;i<e1;i++){
    int kk=key[i], vv=val[i];
    int j=i-1;
    while(j>=e0 && key[j]>kk){ key[j+1]=key[j]; val[j+1]=val[j]; j--; }
    key[j+1]=kk; val[j+1]=vv;
  }
}
__global__ void k_sort1(const int* rp, int* key, int n){
  int v=blockIdx.x*blockDim.x+threadIdx.x;
  if(v>=n) return;
  int e0=rp[v], e1=rp[v+1];
  for(int i=e0+1;i<e1;i++){
    int kk=key[i];
    int j=i-1;
    while(j>=e0 && key[j]>kk){ key[j+1]=key[j]; j--; }
    key[j+1]=kk;
  }
}

// ---------- per-layer ----------
__global__ void k_deg_sc(const int* rp, const int* eid, const float* we, float* dis){
  int n=blockIdx.x*blockDim.x+threadIdx.x;
  if(n>=N_) return;
  float s=1.f;
  int e0=rp[n], e1=rp[n+1];
  for(int p=e0;p<e1;p++) s+=we[eid[p]];
  dis[n]=rsqrtf(fmaxf(s,1e-6f));
}
__global__ void k_deg_bb(const int* rp, float* dis){
  int n=blockIdx.x*blockDim.x+threadIdx.x;
  if(n>=N_) return;
  float s=1.f+(float)(rp[n+1]-rp[n]);
  dis[n]=rsqrtf(fmaxf(s,1e-6f));
}

__global__ void k_w0(const void* dsc, const void* dmin, const int* ri_, const int* rj_,
                     const int* flag, const float* dv, const float* P,
                     const float* sp, const float* qp, float* we){
  int tid=threadIdx.x, g=tid>>4, gl=tid&15;
  long e=(long)blockIdx.x*16+g;
  if(e>=ESC) return;
  int f32=*flag;
  float d1=ldin(dsc,e,f32), d2=ldin(dmin,e,f32);
  int c=ri_[e]*NRES+rj_[e];
  float m=(d1+d2+sp[c])*(1.f/66.f);
  float ms=(d1*d1+d2*d2+qp[c])*(1.f/66.f);
  float istd=rsqrtf(fmaxf(ms-m*m,0.f)+1e-5f);
  float mi=m*istd;
  float acc=0;
  #pragma unroll
  for(int t=0;t<8;t++){
    int j=gl+(t<<4);
    float hid=istd*(d1*dv[j]+d2*dv[128+j]+P[c*128+j])-mi*dv[256+j]+dv[384+j];
    acc+=fmaxf(hid,0.f)*dv[512+j];
  }
  for(int msk=1;msk<16;msk<<=1) acc+=__shfl_xor(acc,msk,64);
  if(gl==0) we[e]=acc+dv[896];
}

// C[M,128] = (relu?)(A1@W[0:128] (+ A2@W[128:256]) + bias) (+= if accum), all f32
template<int K>
__global__ void k_gemm(const float* A1, const float* A2, const float* W,
                       const float* bias, float* C, int relu, int accum, int M){
  __shared__ float At[16*K];
  int j=threadIdx.x;
  int m0=blockIdx.x*16;
  for(int r=0;r<16;r++){
    At[r*K+j]=A1[(long)(m0+r)*128+j];
    if(K==256) At[r*K+128+j]=A2[(long)(m0+r)*128+j];
  }
  __syncthreads();
  float acc[16];
  #pragma unroll
  for(int r=0;r<16;r++) acc[r]=0.f;
  const float4* At4=(const float4*)At;
  for(int k4=0;k4<K/4;k4++){
    float w0=W[(k4*4+0)*128+j], w1=W[(k4*4+1)*128+j];
    float w2=W[(k4*4+2)*128+j], w3=W[(k4*4+3)*128+j];
    #pragma unroll
    for(int r=0;r<16;r++){
      float4 a=At4[r*(K/4)+k4];
      acc[r]+=a.x*w0+a.y*w1+a.z*w2+a.w*w3;
    }
  }
  float bj=bias?bias[j]:0.f;
  for(int r=0;r<16;r++){
    long idx=(long)(m0+r)*128+j;
    float v=acc[r]+bj;
    if(relu) v=fmaxf(v,0.f);
    if(accum) v+=C[idx];
    C[idx]=v;
  }
}

__global__ void k_agg_sc(const int* rp, const int* csrc, const int* ceid,
                         const float* we, const float* dis, const float* xw,
                         const float* w, float* hat_h){
  int wv=threadIdx.x>>6, lane=threadIdx.x&63;
  int n=blockIdx.x*4+wv;
  float disn=dis[n];
  float a0=0,a1=0;
  int e0=rp[n], e1=rp[n+1];
  for(int p=e0;p<e1;p++){
    int s=csrc[p];
    float nw=dis[s]*we[ceid[p]]*disn;
    a0+=nw*xw[(long)s*128+lane];
    a1+=nw*xw[(long)s*128+64+lane];
  }
  float d2=disn*disn;
  a0+=d2*xw[(long)n*128+lane]+w[OW_GB+lane];
  a1+=d2*xw[(long)n*128+64+lane]+w[OW_GB+64+lane];
  hat_h[(long)n*128+lane]+=fmaxf(a0,0.f);
  hat_h[(long)n*128+64+lane]+=fmaxf(a1,0.f);
}

__global__ void k_ndot(const float* hat_h, const float* dv, float* an, float* bn){
  int wv=threadIdx.x>>6, lane=threadIdx.x&63;
  int n=blockIdx.x*4+wv;
  float h0=hat_h[(long)n*128+lane], h1=hat_h[(long)n*128+64+lane];
  float a=h0*dv[640+lane]+h1*dv[640+64+lane];
  float b=h0*dv[768+lane]+h1*dv[768+64+lane];
  for(int m=1;m<64;m<<=1){ a+=__shfl_xor(a,m,64); b+=__shfl_xor(b,m,64); }
  if(lane==0){ an[n]=a; bn[n]=b; }
}

__global__ void k_wupd(const int* src, const int* dst, const float* an, const float* bn,
                       const float* dv, float* we){
  int e=blockIdx.x*blockDim.x+threadIdx.x;
  if(e>=ESC) return;
  we[e]+=an[src[e]]+bn[dst[e]]+dv[897];
}

__global__ void k_agg_bb(const int* rp, const int* csrc, const float* dis,
                         const float* xw, const float* w, float* h){
  int wv=threadIdx.x>>6, lane=threadIdx.x&63;
  int n=blockIdx.x*4+wv;
  float disn=dis[n];
  float a0=0,a1=0;
  int e0=rp[n], e1=rp[n+1];
  for(int p=e0;p<e1;p++){
    int s=csrc[p];
    float nw=dis[s]*disn;
    a0+=nw*xw[(long)s*128+lane];
    a1+=nw*xw[(long)s*128+64+lane];
  }
  float d2=disn*disn;
  a0+=d2*xw[(long)n*128+lane]+w[OW_BGB+lane];
  a1+=d2*xw[(long)n*128+64+lane]+w[OW_BGB+64+lane];
  h[(long)n*128+lane]+=fmaxf(a0,0.f);
  h[(long)n*128+64+lane]+=fmaxf(a1,0.f);
}

__global__ void k_heads(const float* hat_h, const float* h, const float* w,
                        const void* old_chi, const void* old_phi, const void* old_psi,
                        const void* old_cb, const void* old_ca, const int* flag, void* out){
  int wv=threadIdx.x>>6, lane=threadIdx.x&63;
  int n=blockIdx.x*4+wv;
  int f32=*flag;
  float s0=fmaxf(hat_h[(long)n*128+lane],0.f), s1=fmaxf(hat_h[(long)n*128+64+lane],0.f);
  float b0=fmaxf(h[(long)n*128+lane],0.f),    b1=fmaxf(h[(long)n*128+64+lane],0.f);
  float r[8];
  r[0]=s0*w[OW_AW+lane]+s1*w[OW_AW+64+lane];
  r[1]=s0*w[OW_CW+lane*3+0]+s1*w[OW_CW+(64+lane)*3+0];
  r[2]=s0*w[OW_CW+lane*3+1]+s1*w[OW_CW+(64+lane)*3+1];
  r[3]=s0*w[OW_CW+lane*3+2]+s1*w[OW_CW+(64+lane)*3+2];
  r[4]=b0*w[OW_BAW+lane]+b1*w[OW_BAW+64+lane];
  r[5]=b0*w[OW_XW+lane*3+0]+b1*w[OW_XW+(64+lane)*3+0];
  r[6]=b0*w[OW_XW+lane*3+1]+b1*w[OW_XW+(64+lane)*3+1];
  r[7]=b0*w[OW_XW+lane*3+2]+b1*w[OW_XW+(64+lane)*3+2];
  for(int m=1;m<64;m<<=1){
    #pragma unroll
    for(int t=0;t<8;t++) r[t]+=__shfl_xor(r[t],m,64);
  }
  if(lane==0){
    float dchi=r[0]+w[OW_AB];
    for(int k=0;k<4;k++)
      stout(out,(long)k*N_+n, wrapf(ldin(old_chi,(long)k*N_+n,f32)+dchi), f32);
    float dphi=r[4]+w[OW_BAB];
    stout(out,(long)4*N_+n, wrapf(ldin(old_phi,n,f32)+dphi), f32);
    stout(out,(long)5*N_+n, wrapf(ldin(old_psi,n,f32)+dphi), f32);
    for(int t=0;t<3;t++){
      stout(out,(long)6*N_+(long)n*3+t, ldin(old_cb,(long)n*3+t,f32)+r[1+t]+w[OW_CB+t], f32);
      stout(out,(long)9*N_+(long)n*3+t, ldin(old_ca,(long)n*3+t,f32)+r[5+t]+w[OW_XB+t], f32);
    }
  }
}

// ---------- host ----------
extern "C" void kernel_launch(void* const* d_in, const int* in_sizes, int n_in,
                              void* d_out, int out_size, void* d_ws, size_t ws_size,
                              hipStream_t stream) {
  (void)in_sizes; (void)n_in; (void)out_size; (void)ws_size;

  // workspace bump allocator (256B aligned)
  char* p=(char*)d_ws;
  auto alloc=[&](size_t bytes)->void*{ void* r=(void*)p; p+=((bytes+255)&~(size_t)255); return r; };
  int*   flag   =(int*)  alloc(16);
  float* warena =(float*)alloc((size_t)OW_TOT*4);
  float* dv     =(float*)alloc(1024*4);
  float* P      =(float*)alloc((size_t)441*128*4);
  float* sp     =(float*)alloc(441*4);
  float* qp     =(float*)alloc(441*4);
  float* hat_h  =(float*)alloc((size_t)N_*128*4);
  float* hbuf   =(float*)alloc((size_t)N_*128*4);
  float* bufX   =(float*)alloc((size_t)N_*128*4);   // xw
  float* bufH   =(float*)alloc((size_t)N_*128*4);   // hidden
  float* we     =(float*)alloc((size_t)ESC*4);
  float* an     =(float*)alloc((size_t)N_*4);
  float* bn     =(float*)alloc((size_t)N_*4);
  float* dis    =(float*)alloc((size_t)N_*4);
  float* disb   =(float*)alloc((size_t)N_*4);
  int* counts   =(int*)  alloc((size_t)N_*4);
  int* rp_sc    =(int*)  alloc((size_t)(N_+1)*4);
  int* rp_bb    =(int*)  alloc((size_t)(N_+1)*4);
  int* csr_src_sc=(int*) alloc((size_t)ESC*4);
  int* csr_eid_sc=(int*) alloc((size_t)ESC*4);
  int* csr_src_bb=(int*) alloc((size_t)EBB*4);
  int* part     =(int*)  alloc(256*4);

  const int* src_sc=(const int*)d_in[48];
  const int* dst_sc=src_sc+ESC;
  const int* src_bb=(const int*)d_in[49];
  const int* dst_bb=src_bb+EBB;

  // 1. dtype detect
  k_detect<<<1,1,0,stream>>>(d_in[0], flag);

  // 2. weights -> f32 arena
  CvtArgs ca;
  {
    int map[29]={14,15,16,17,18,19,20,21,22,23,24,25,30,31,32,33,34,35,36,37,
                 38,39,40,41,42,43,44,45,13};
    for(int i=0;i<29;i++) ca.src[i]=d_in[map[i]];
  }
  k_cvtw<<<(OW_TOT+255)/256,256,0,stream>>>(ca, flag, warena);

  // 3. derived vectors + P table
  k_prevec<<<1,128,0,stream>>>(warena, d_in[26], d_in[27], d_in[28], d_in[29], flag, dv);
  k_preP<<<441,128,0,stream>>>(warena, P, sp, qp);

  // 4. node featurizers
  k_feat_sc<<<N_,128,0,stream>>>(d_in[0], d_in[1], flag, warena, hat_h);
  k_feat_bb<<<N_,128,0,stream>>>(d_in[2], d_in[3], d_in[4], d_in[5], flag, warena, hbuf);

  // 5. CSR build (sc then bb), deterministic via per-node sort
  const int SCAN_B=(N_+1023)/1024;
  hipMemsetAsync(counts,0,(size_t)N_*4,stream);
  k_count<<<(ESC+255)/256,256,0,stream>>>(dst_sc,ESC,counts);
  k_scan1<<<SCAN_B,1024,0,stream>>>(counts,N_,rp_sc,part);
  k_scan2<<<1,64,0,stream>>>(part,SCAN_B);
  k_scan3<<<SCAN_B,1024,0,stream>>>(rp_sc,N_,part,ESC);
  hipMemsetAsync(counts,0,(size_t)N_*4,stream);
  k_fill<<<(ESC+255)/256,256,0,stream>>>(src_sc,dst_sc,ESC,rp_sc,counts,csr_src_sc,csr_eid_sc);
  k_sort2<<<(N_+255)/256,256,0,stream>>>(rp_sc,csr_eid_sc,csr_src_sc,N_);

  hipMemsetAsync(counts,0,(size_t)N_*4,stream);
  k_count<<<(EBB+255)/256,256,0,stream>>>(dst_bb,EBB,counts);
  k_scan1<<<SCAN_B,1024,0,stream>>>(counts,N_,rp_bb,part);
  k_scan2<<<1,64,0,stream>>>(part,SCAN_B);
  k_scan3<<<SCAN_B,1024,0,stream>>>(rp_bb,N_,part,EBB);
  hipMemsetAsync(counts,0,(size_t)N_*4,stream);
  k_fill<<<(EBB+255)/256,256,0,stream>>>(src_bb,dst_bb,EBB,rp_bb,counts,csr_src_bb,(int*)nullptr);
  k_sort1<<<(N_+255)/256,256,0,stream>>>(rp_bb,csr_src_bb,N_);

  // 6. initial edge weights w0 = mean(hat_e_0)
  k_w0<<<ESC/16,256,0,stream>>>(d_in[6],d_in[7],(const int*)d_in[46],(const int*)d_in[47],
                                flag,dv,P,sp,qp,we);
  k_deg_bb<<<(N_+255)/256,256,0,stream>>>(rp_bb,disb);

  // 7. three sidechain GCN layers
  for(int l=0;l<3;l++){
    k_gemm<128><<<N_/16,128,0,stream>>>(hat_h, nullptr, warena+OW_GW, nullptr, bufX, 0, 0, N_);
    k_deg_sc<<<(N_+255)/256,256,0,stream>>>(rp_sc,csr_eid_sc,we,dis);
    k_agg_sc<<<N_/4,256,0,stream>>>(rp_sc,csr_src_sc,csr_eid_sc,we,dis,bufX,warena,hat_h);
    if(l<2){
      k_ndot<<<N_/4,256,0,stream>>>(hat_h,dv,an,bn);
      k_wupd<<<(ESC+255)/256,256,0,stream>>>(src_sc,dst_sc,an,bn,dv,we);
    }
  }

  // 8. backbone interaction layers
  for(int l=0;l<2;l++){
    // hidden = relu(h@iW1_top + hat_h@iW1_bot + ib1)
    k_gemm<256><<<N_/16,128,0,stream>>>(hbuf, hat_h, warena+OW_IW1, warena+OW_IB1, bufH, 1, 0, N_);
    // xw = h @ bgW
    k_gemm<128><<<N_/16,128,0,stream>>>(hbuf, nullptr, warena+OW_BGW, nullptr, bufX, 0, 0, N_);
    // h += relu(gcn agg)
    k_agg_bb<<<N_/4,256,0,stream>>>(rp_bb,csr_src_bb,disb,bufX,warena,hbuf);
    // h += hidden@iW2 + ib2
    k_gemm<128><<<N_/16,128,0,stream>>>(bufH, nullptr, warena+OW_IW2, warena+OW_IB2, hbuf, 0, 1, N_);
  }

  // 9. heads -> d_out
  k_heads<<<N_/4,256,0,stream>>>(hat_h,hbuf,warena,
                                 d_in[8],d_in[9],d_in[10],d_in[11],d_in[12],flag,d_out);
}

// Round 3
// 1091.034 us; speedup vs baseline: 1.0865x; 1.0865x over previous
//
#include <hip/hip_runtime.h>
#include <stdint.h>

#define DEVI __device__ __forceinline__

constexpr int N_   = 50000;
constexpr int ESC  = 600000;
constexpr int EBB  = 100000;
constexpr int NRES = 21;
constexpr float PI_F = 3.14159f;

// ---------- dtype helpers (runtime f32-vs-bf16 dispatch) ----------
DEVI float bf2f(unsigned short u){ return __uint_as_float(((unsigned)u)<<16); }
DEVI unsigned short f2bf(float f){
  unsigned x = __float_as_uint(f);
  unsigned r = (x + 0x7FFFu + ((x>>16)&1u))>>16;
  return (unsigned short)r;
}
DEVI float ldin(const void* p, long i, int f32){
  return f32 ? ((const float*)p)[i] : bf2f(((const unsigned short*)p)[i]);
}
DEVI void stout(void* p, long i, float v, int f32){
  if(f32) ((float*)p)[i]=v; else ((unsigned short*)p)[i]=f2bf(v);
}
DEVI float wrapf(float a){
  float t = a + PI_F;
  const float TP = 2.f*PI_F;
  t -= floorf(t/TP)*TP;
  return t - PI_F;
}

// ---------- weight arena offsets (floats) ----------
constexpr int OW_SC_LN_G=0;
constexpr int OW_SC_LN_B=OW_SC_LN_G+19;
constexpr int OW_SC_W  = OW_SC_LN_B+19;
constexpr int OW_SC_B  = OW_SC_W+19*128;
constexpr int OW_BB_LN_G=OW_SC_B+128;
constexpr int OW_BB_LN_B=OW_BB_LN_G+38;
constexpr int OW_BB_W = OW_BB_LN_B+38;
constexpr int OW_BB_B = OW_BB_W+38*128;
constexpr int OW_E_LN_G=OW_BB_B+128;
constexpr int OW_E_LN_B=OW_E_LN_G+66;
constexpr int OW_EW1 = OW_E_LN_B+66;
constexpr int OW_EB1 = OW_EW1+66*128;
constexpr int OW_GW  = OW_EB1+128;
constexpr int OW_GB  = OW_GW+128*128;
constexpr int OW_BGW = OW_GB+128;
constexpr int OW_BGB = OW_BGW+128*128;
constexpr int OW_IW1 = OW_BGB+128;
constexpr int OW_IB1 = OW_IW1+256*128;
constexpr int OW_IW2 = OW_IB1+128;
constexpr int OW_IB2 = OW_IW2+128*128;
constexpr int OW_AW  = OW_IB2+128;
constexpr int OW_AB  = OW_AW+128;
constexpr int OW_BAW = OW_AB+1;
constexpr int OW_BAB = OW_BAW+128;
constexpr int OW_CW  = OW_BAB+1;
constexpr int OW_CB  = OW_CW+128*3;
constexpr int OW_XW  = OW_CB+3;
constexpr int OW_XB  = OW_XW+128*3;
constexpr int OW_RES = OW_XB+3;
constexpr int OW_TOT = OW_RES+21*32;

// dv layout: A(128),C(128),G(128),B(128),v2m(128),usm(128),udm(128), dv[896]=eb2 mean, dv[897]=eub mean

// ---------- kernels ----------
__global__ void k_detect(const void* vcom, int* flag){
  const unsigned short* u = (const unsigned short*)vcom;
  int insane=0;
  for(int i=0;i<64;i+=2){
    float f = bf2f(u[i]);
    float a = fabsf(f);
    if(!(a<1e5f) || (a!=0.0f && a<1e-5f)) insane++;
  }
  *flag = (insane>=8)?1:0;
}

struct CvtArgs { const void* src[29]; };

__global__ void k_cvtw(CvtArgs a, const int* flag, float* w){
  static constexpr int offs[30] = {
    OW_SC_LN_G,OW_SC_LN_B,OW_SC_W,OW_SC_B,OW_BB_LN_G,OW_BB_LN_B,OW_BB_W,OW_BB_B,
    OW_E_LN_G,OW_E_LN_B,OW_EW1,OW_EB1,OW_GW,OW_GB,OW_BGW,OW_BGB,OW_IW1,OW_IB1,
    OW_IW2,OW_IB2,OW_AW,OW_AB,OW_BAW,OW_BAB,OW_CW,OW_CB,OW_XW,OW_XB,OW_RES,OW_TOT};
  int f32=*flag;
  for(int t=blockIdx.x*blockDim.x+threadIdx.x; t<OW_TOT; t+=gridDim.x*blockDim.x){
    int s=0;
    while(t>=offs[s+1]) s++;
    w[t]=ldin(a.src[s], t-offs[s], f32);
  }
}

__global__ void k_prevec(const float* w, const void* eW2, const void* eb2,
                         const void* euW, const void* eub, const int* flag, float* dv){
  int j=threadIdx.x; int f32=*flag;
  const float* g=w+OW_E_LN_G; const float* b=w+OW_E_LN_B; const float* W1=w+OW_EW1;
  float A=g[0]*W1[j], C=g[1]*W1[128+j];
  float G=0,B=0;
  for(int i=0;i<66;i++){ float wij=W1[i*128+j]; G+=g[i]*wij; B+=b[i]*wij; }
  B += w[OW_EB1+j];
  float v2=0; for(int k=0;k<128;k++) v2+=ldin(eW2,(long)j*128+k,f32);
  float us=0,ud=0;
  for(int k=0;k<128;k++){ us+=ldin(euW,(long)j*128+k,f32); ud+=ldin(euW,(long)(128+j)*128+k,f32); }
  dv[j]=A; dv[128+j]=C; dv[256+j]=G; dv[384+j]=B;
  dv[512+j]=v2*(1.f/128.f); dv[640+j]=us*(1.f/128.f); dv[768+j]=ud*(1.f/128.f);
  if(j==0){
    float s=0,t=0;
    for(int k=0;k<128;k++){ s+=ldin(eb2,k,f32); t+=ldin(eub,k,f32); }
    dv[896]=s*(1.f/128.f); dv[897]=t*(1.f/128.f);
  }
}

__global__ void k_preP(const float* w, float* P, float* sp, float* qp){
  __shared__ float pv[64];
  int c=blockIdx.x, ri=c/NRES, rj=c%NRES, j=threadIdx.x;
  const float* res=w+OW_RES;
  if(j<32) pv[j]=res[ri*32+j];
  else if(j<64) pv[j]=res[rj*32+(j-32)];
  __syncthreads();
  const float* g=w+OW_E_LN_G; const float* W1=w+OW_EW1;
  float s=0;
  for(int i=0;i<64;i++) s += pv[i]*g[2+i]*W1[(2+i)*128+j];
  P[c*128+j]=s;
  if(j==0){ float a=0,q=0; for(int i=0;i<64;i++){a+=pv[i]; q+=pv[i]*pv[i];} sp[c]=a; qp[c]=q; }
}

__global__ void k_feat_sc(const void* vcom, const void* sbfchi, const int* flag,
                          const float* w, float* hat_h){
  __shared__ float x[19];
  int n=blockIdx.x, j=threadIdx.x, f32=*flag;
  if(j<3) x[j]=ldin(vcom,(long)n*3+j,f32);
  else if(j<19) x[j]=ldin(sbfchi,(long)n*16+(j-3),f32);
  __syncthreads();
  float m=0; for(int i=0;i<19;i++) m+=x[i]; m*=(1.f/19.f);
  float v=0; for(int i=0;i<19;i++){float d=x[i]-m; v+=d*d;} v*=(1.f/19.f);
  float istd=rsqrtf(v+1e-5f);
  float acc=w[OW_SC_B+j];
  for(int i=0;i<19;i++){
    float xn=(x[i]-m)*istd*w[OW_SC_LN_G+i]+w[OW_SC_LN_B+i];
    acc+=xn*w[OW_SC_W+i*128+j];
  }
  hat_h[(long)n*128+j]=acc;
}

__global__ void k_feat_bb(const void* xca, const void* vcb, const void* sphi, const void* spsi,
                          const int* flag, const float* w, float* h){
  __shared__ float x[38];
  int n=blockIdx.x, j=threadIdx.x, f32=*flag;
  if(j<3) x[j]=ldin(xca,(long)n*3+j,f32);
  else if(j<6) x[j]=ldin(vcb,(long)n*3+(j-3),f32);
  else if(j<22) x[j]=ldin(sphi,(long)n*16+(j-6),f32);
  else if(j<38) x[j]=ldin(spsi,(long)n*16+(j-22),f32);
  __syncthreads();
  float m=0; for(int i=0;i<38;i++) m+=x[i]; m*=(1.f/38.f);
  float v=0; for(int i=0;i<38;i++){float d=x[i]-m; v+=d*d;} v*=(1.f/38.f);
  float istd=rsqrtf(v+1e-5f);
  float acc=w[OW_BB_B+j];
  for(int i=0;i<38;i++){
    float xn=(x[i]-m)*istd*w[OW_BB_LN_G+i]+w[OW_BB_LN_B+i];
    acc+=xn*w[OW_BB_W+i*128+j];
  }
  h[(long)n*128+j]=acc;
}

// ---------- CSR build ----------
__global__ void k_count(const int* dst, int E, int* counts){
  int e=blockIdx.x*blockDim.x+threadIdx.x;
  if(e<E) atomicAdd(&counts[dst[e]],1);
}
__global__ void k_scan1(const int* in, int n, int* excl, int* part){
  __shared__ int s[1024];
  int i=blockIdx.x*1024+threadIdx.x;
  int v=(i<n)?in[i]:0;
  s[threadIdx.x]=v; __syncthreads();
  for(int off=1; off<1024; off<<=1){
    int t=(threadIdx.x>=off)?s[threadIdx.x-off]:0;
    __syncthreads();
    s[threadIdx.x]+=t; __syncthreads();
  }
  if(i<n) excl[i]=s[threadIdx.x]-v;
  if(threadIdx.x==1023) part[blockIdx.x]=s[1023];
}
__global__ void k_scan2(int* part, int nb){
  if(threadIdx.x==0 && blockIdx.x==0){
    int run=0;
    for(int b=0;b<nb;b++){ int t=part[b]; part[b]=run; run+=t; }
  }
}
__global__ void k_scan3(int* rp, int n, const int* part, int E){
  int i=blockIdx.x*1024+threadIdx.x;
  if(i<n) rp[i]+=part[blockIdx.x];
  if(i==n) rp[n]=E;
}
__global__ void k_fill(const int* src, const int* dst, int E, const int* rp,
                       int* cursor, int* csr_src, int* csr_eid){
  int e=blockIdx.x*blockDim.x+threadIdx.x;
  if(e>=E) return;
  int d=dst[e];
  int p=rp[d]+atomicAdd(&cursor[d],1);
  csr_src[p]=src[e];
  if(csr_eid) csr_eid[p]=e;
}
__global__ void k_sort2(const int* rp, int* key, int* val, int n){
  int v=blockIdx.x*blockDim.x+threadIdx.x;
  if(v>=n) return;
  int e0=rp[v], e1=rp[v+1];
  for(int i=e0+1;i<e1;i++){
    int kk=key[i], vv=val[i];
    int j=i-1;
    while(j>=e0 && key[j]>kk){ key[j+1]=key[j]; val[j+1]=val[j]; j--; }
    key[j+1]=kk; val[j+1]=vv;
  }
}
__global__ void k_sort1(const int* rp, int* key, int n){
  int v=blockIdx.x*blockDim.x+threadIdx.x;
  if(v>=n) return;
  int e0=rp[v], e1=rp[v+1];
  for(int i=e0+1;i<e1;i++){
    int kk=key[i];
    int j=i-1;
    while(j>=e0 && key[j]>kk){ key[j+1]=key[j]; j--; }
    key[j+1]=kk;
  }
}

// ---------- per-layer ----------
__global__ void k_deg_sc(const int* rp, const int* eid, const float* we, float* dis){
  int n=blockIdx.x*blockDim.x+threadIdx.x;
  if(n>=N_) return;
  float s=1.f;
  int e0=rp[n], e1=rp[n+1];
  for(int p=e0;p<e1;p++) s+=we[eid[p]];
  dis[n]=rsqrtf(fmaxf(s,1e-6f));
}
__global__ void k_deg_bb(const int* rp, float* dis){
  int n=blockIdx.x*blockDim.x+threadIdx.x;
  if(n>=N_) return;
  float s=1.f+(float)(rp[n+1]-rp[n]);
  dis[n]=rsqrtf(fmaxf(s,1e-6f));
}

__global__ void k_w0(const void* dsc, const void* dmin, const int* ri_, const int* rj_,
                     const int* flag, const float* dv, const float* P,
                     const float* sp, const float* qp, float* we){
  int tid=threadIdx.x, g=tid>>4, gl=tid&15;
  long e=(long)blockIdx.x*16+g;
  if(e>=ESC) return;
  int f32=*flag;
  float d1=ldin(dsc,e,f32), d2=ldin(dmin,e,f32);
  int c=ri_[e]*NRES+rj_[e];
  float m=(d1+d2+sp[c])*(1.f/66.f);
  float ms=(d1*d1+d2*d2+qp[c])*(1.f/66.f);
  float istd=rsqrtf(fmaxf(ms-m*m,0.f)+1e-5f);
  float mi=m*istd;
  float acc=0;
  #pragma unroll
  for(int t=0;t<8;t++){
    int j=gl+(t<<4);
    float hid=istd*(d1*dv[j]+d2*dv[128+j]+P[c*128+j])-mi*dv[256+j]+dv[384+j];
    acc+=fmaxf(hid,0.f)*dv[512+j];
  }
  for(int msk=1;msk<16;msk<<=1) acc+=__shfl_xor(acc,msk,64);
  if(gl==0) we[e]=acc+dv[896];
}

// ---------- register-tiled f32 GEMM ----------
// C[M,128] = (relu?)(A1@W[0:128] (+ A2@W[128:256]) + bias) (+= C if accum)
// 64 rows x 128 cols per 256-thread block; 8x4 register tile per thread.
// As staged transposed [k][m] (8KB); Ws [k][c] padded stride 132 (16.5KB).
constexpr int WS_LD = 132;
template<int K>
__global__ __launch_bounds__(256,4) void k_gemm(const float* A1, const float* A2,
                       const float* W, const float* bias, float* C,
                       int relu, int accum, int M){
  __shared__ float As[32*64];
  __shared__ float Ws[32*WS_LD];
  const int tid = threadIdx.x;
  const int ct = tid & 31;       // col group: cols ct*4..ct*4+3
  const int rt = tid >> 5;       // row group: rows rt*8..rt*8+7
  const int m0 = blockIdx.x * 64;
  // staging assignments
  const int ar = tid >> 2;            // 0..63  (row within tile)
  const int ac = (tid & 3) * 8;       // 0,8,16,24 (k within chunk)
  const int wk = tid & 31;            // 0..31 (k within chunk)
  const int wc = (tid >> 5) * 16;     // 0..112 (col)

  float acc[8][4];
  #pragma unroll
  for(int r=0;r<8;r++){
    #pragma unroll
    for(int c=0;c<4;c++) acc[r][c]=0.f;
  }

  long arow = (long)min(m0 + ar, M-1);

  // prefetch chunk 0
  float4 pa0, pa1, pw0, pw1, pw2, pw3;
  {
    const float* Asrc = A1;
    pa0 = *(const float4*)&Asrc[arow*128 + ac];
    pa1 = *(const float4*)&Asrc[arow*128 + ac + 4];
    const float* wsrc = &W[(long)wk*128 + wc];
    pw0 = *(const float4*)(wsrc+0);  pw1 = *(const float4*)(wsrc+4);
    pw2 = *(const float4*)(wsrc+8);  pw3 = *(const float4*)(wsrc+12);
  }

  const int NCH = K/32;
  for(int t=0;t<NCH;t++){
    // write staged regs to LDS
    As[(ac+0)*64+ar]=pa0.x; As[(ac+1)*64+ar]=pa0.y; As[(ac+2)*64+ar]=pa0.z; As[(ac+3)*64+ar]=pa0.w;
    As[(ac+4)*64+ar]=pa1.x; As[(ac+5)*64+ar]=pa1.y; As[(ac+6)*64+ar]=pa1.z; As[(ac+7)*64+ar]=pa1.w;
    *(float4*)&Ws[wk*WS_LD+wc+0] = pw0;
    *(float4*)&Ws[wk*WS_LD+wc+4] = pw1;
    *(float4*)&Ws[wk*WS_LD+wc+8] = pw2;
    *(float4*)&Ws[wk*WS_LD+wc+12]= pw3;
    __syncthreads();
    // prefetch next chunk while computing
    if(t+1<NCH){
      int k0=(t+1)*32;
      const float* Asrc = (K==256 && k0>=128) ? A2 : A1;
      int kk0 = k0 & 127;
      pa0 = *(const float4*)&Asrc[arow*128 + kk0 + ac];
      pa1 = *(const float4*)&Asrc[arow*128 + kk0 + ac + 4];
      const float* wsrc = &W[(long)(k0+wk)*128 + wc];
      pw0 = *(const float4*)(wsrc+0);  pw1 = *(const float4*)(wsrc+4);
      pw2 = *(const float4*)(wsrc+8);  pw3 = *(const float4*)(wsrc+12);
    }
    #pragma unroll
    for(int k=0;k<32;k++){
      float4 a0 = *(const float4*)&As[k*64 + rt*8];
      float4 a1 = *(const float4*)&As[k*64 + rt*8 + 4];
      float4 wv = *(const float4*)&Ws[k*WS_LD + ct*4];
      acc[0][0]+=a0.x*wv.x; acc[0][1]+=a0.x*wv.y; acc[0][2]+=a0.x*wv.z; acc[0][3]+=a0.x*wv.w;
      acc[1][0]+=a0.y*wv.x; acc[1][1]+=a0.y*wv.y; acc[1][2]+=a0.y*wv.z; acc[1][3]+=a0.y*wv.w;
      acc[2][0]+=a0.z*wv.x; acc[2][1]+=a0.z*wv.y; acc[2][2]+=a0.z*wv.z; acc[2][3]+=a0.z*wv.w;
      acc[3][0]+=a0.w*wv.x; acc[3][1]+=a0.w*wv.y; acc[3][2]+=a0.w*wv.z; acc[3][3]+=a0.w*wv.w;
      acc[4][0]+=a1.x*wv.x; acc[4][1]+=a1.x*wv.y; acc[4][2]+=a1.x*wv.z; acc[4][3]+=a1.x*wv.w;
      acc[5][0]+=a1.y*wv.x; acc[5][1]+=a1.y*wv.y; acc[5][2]+=a1.y*wv.z; acc[5][3]+=a1.y*wv.w;
      acc[6][0]+=a1.z*wv.x; acc[6][1]+=a1.z*wv.y; acc[6][2]+=a1.z*wv.z; acc[6][3]+=a1.z*wv.w;
      acc[7][0]+=a1.w*wv.x; acc[7][1]+=a1.w*wv.y; acc[7][2]+=a1.w*wv.z; acc[7][3]+=a1.w*wv.w;
    }
    __syncthreads();
  }

  float4 bv = make_float4(0.f,0.f,0.f,0.f);
  if(bias) bv = *(const float4*)&bias[ct*4];
  #pragma unroll
  for(int r=0;r<8;r++){
    int row = m0 + rt*8 + r;
    if(row >= M) continue;
    long idx = (long)row*128 + ct*4;
    float4 v;
    v.x=acc[r][0]+bv.x; v.y=acc[r][1]+bv.y; v.z=acc[r][2]+bv.z; v.w=acc[r][3]+bv.w;
    if(relu){ v.x=fmaxf(v.x,0.f); v.y=fmaxf(v.y,0.f); v.z=fmaxf(v.z,0.f); v.w=fmaxf(v.w,0.f); }
    if(accum){
      float4 o=*(const float4*)&C[idx];
      v.x+=o.x; v.y+=o.y; v.z+=o.z; v.w+=o.w;
    }
    *(float4*)&C[idx]=v;
  }
}

__global__ void k_agg_sc(const int* rp, const int* csrc, const int* ceid,
                         const float* we, const float* dis, const float* xw,
                         const float* w, float* hat_h){
  int wv=threadIdx.x>>6, lane=threadIdx.x&63;
  int n=blockIdx.x*4+wv;
  float disn=dis[n];
  float a0=0,a1=0;
  int e0=rp[n], e1=rp[n+1];
  for(int p=e0;p<e1;p++){
    int s=csrc[p];
    float nw=dis[s]*we[ceid[p]]*disn;
    a0+=nw*xw[(long)s*128+lane];
    a1+=nw*xw[(long)s*128+64+lane];
  }
  float d2=disn*disn;
  a0+=d2*xw[(long)n*128+lane]+w[OW_GB+lane];
  a1+=d2*xw[(long)n*128+64+lane]+w[OW_GB+64+lane];
  hat_h[(long)n*128+lane]+=fmaxf(a0,0.f);
  hat_h[(long)n*128+64+lane]+=fmaxf(a1,0.f);
}

__global__ void k_ndot(const float* hat_h, const float* dv, float* an, float* bn){
  int wv=threadIdx.x>>6, lane=threadIdx.x&63;
  int n=blockIdx.x*4+wv;
  float h0=hat_h[(long)n*128+lane], h1=hat_h[(long)n*128+64+lane];
  float a=h0*dv[640+lane]+h1*dv[640+64+lane];
  float b=h0*dv[768+lane]+h1*dv[768+64+lane];
  for(int m=1;m<64;m<<=1){ a+=__shfl_xor(a,m,64); b+=__shfl_xor(b,m,64); }
  if(lane==0){ an[n]=a; bn[n]=b; }
}

__global__ void k_wupd(const int* src, const int* dst, const float* an, const float* bn,
                       const float* dv, float* we){
  int e=blockIdx.x*blockDim.x+threadIdx.x;
  if(e>=ESC) return;
  we[e]+=an[src[e]]+bn[dst[e]]+dv[897];
}

__global__ void k_agg_bb(const int* rp, const int* csrc, const float* dis,
                         const float* xw, const float* w, float* h){
  int wv=threadIdx.x>>6, lane=threadIdx.x&63;
  int n=blockIdx.x*4+wv;
  float disn=dis[n];
  float a0=0,a1=0;
  int e0=rp[n], e1=rp[n+1];
  for(int p=e0;p<e1;p++){
    int s=csrc[p];
    float nw=dis[s]*disn;
    a0+=nw*xw[(long)s*128+lane];
    a1+=nw*xw[(long)s*128+64+lane];
  }
  float d2=disn*disn;
  a0+=d2*xw[(long)n*128+lane]+w[OW_BGB+lane];
  a1+=d2*xw[(long)n*128+64+lane]+w[OW_BGB+64+lane];
  h[(long)n*128+lane]+=fmaxf(a0,0.f);
  h[(long)n*128+64+lane]+=fmaxf(a1,0.f);
}

__global__ void k_heads(const float* hat_h, const float* h, const float* w,
                        const void* old_chi, const void* old_phi, const void* old_psi,
                        const void* old_cb, const void* old_ca, const int* flag, void* out){
  int wv=threadIdx.x>>6, lane=threadIdx.x&63;
  int n=blockIdx.x*4+wv;
  int f32=*flag;
  float s0=fmaxf(hat_h[(long)n*128+lane],0.f), s1=fmaxf(hat_h[(long)n*128+64+lane],0.f);
  float b0=fmaxf(h[(long)n*128+lane],0.f),    b1=fmaxf(h[(long)n*128+64+lane],0.f);
  float r[8];
  r[0]=s0*w[OW_AW+lane]+s1*w[OW_AW+64+lane];
  r[1]=s0*w[OW_CW+lane*3+0]+s1*w[OW_CW+(64+lane)*3+0];
  r[2]=s0*w[OW_CW+lane*3+1]+s1*w[OW_CW+(64+lane)*3+1];
  r[3]=s0*w[OW_CW+lane*3+2]+s1*w[OW_CW+(64+lane)*3+2];
  r[4]=b0*w[OW_BAW+lane]+b1*w[OW_BAW+64+lane];
  r[5]=b0*w[OW_XW+lane*3+0]+b1*w[OW_XW+(64+lane)*3+0];
  r[6]=b0*w[OW_XW+lane*3+1]+b1*w[OW_XW+(64+lane)*3+1];
  r[7]=b0*w[OW_XW+lane*3+2]+b1*w[OW_XW+(64+lane)*3+2];
  for(int m=1;m<64;m<<=1){
    #pragma unroll
    for(int t=0;t<8;t++) r[t]+=__shfl_xor(r[t],m,64);
  }
  if(lane==0){
    float dchi=r[0]+w[OW_AB];
    for(int k=0;k<4;k++)
      stout(out,(long)k*N_+n, wrapf(ldin(old_chi,(long)k*N_+n,f32)+dchi), f32);
    float dphi=r[4]+w[OW_BAB];
    stout(out,(long)4*N_+n, wrapf(ldin(old_phi,n,f32)+dphi), f32);
    stout(out,(long)5*N_+n, wrapf(ldin(old_psi,n,f32)+dphi), f32);
    for(int t=0;t<3;t++){
      stout(out,(long)6*N_+(long)n*3+t, ldin(old_cb,(long)n*3+t,f32)+r[1+t]+w[OW_CB+t], f32);
      stout(out,(long)9*N_+(long)n*3+t, ldin(old_ca,(long)n*3+t,f32)+r[5+t]+w[OW_XB+t], f32);
    }
  }
}

// ---------- host ----------
extern "C" void kernel_launch(void* const* d_in, const int* in_sizes, int n_in,
                              void* d_out, int out_size, void* d_ws, size_t ws_size,
                              hipStream_t stream) {
  (void)in_sizes; (void)n_in; (void)out_size; (void)ws_size;

  char* p=(char*)d_ws;
  auto alloc=[&](size_t bytes)->void*{ void* r=(void*)p; p+=((bytes+255)&~(size_t)255); return r; };
  int*   flag   =(int*)  alloc(16);
  float* warena =(float*)alloc((size_t)OW_TOT*4);
  float* dv     =(float*)alloc(1024*4);
  float* P      =(float*)alloc((size_t)441*128*4);
  float* sp     =(float*)alloc(441*4);
  float* qp     =(float*)alloc(441*4);
  float* hat_h  =(float*)alloc((size_t)N_*128*4);
  float* hbuf   =(float*)alloc((size_t)N_*128*4);
  float* bufX   =(float*)alloc((size_t)N_*128*4);
  float* bufH   =(float*)alloc((size_t)N_*128*4);
  float* we     =(float*)alloc((size_t)ESC*4);
  float* an     =(float*)alloc((size_t)N_*4);
  float* bn     =(float*)alloc((size_t)N_*4);
  float* dis    =(float*)alloc((size_t)N_*4);
  float* disb   =(float*)alloc((size_t)N_*4);
  int* counts   =(int*)  alloc((size_t)N_*4);
  int* rp_sc    =(int*)  alloc((size_t)(N_+1)*4);
  int* rp_bb    =(int*)  alloc((size_t)(N_+1)*4);
  int* csr_src_sc=(int*) alloc((size_t)ESC*4);
  int* csr_eid_sc=(int*) alloc((size_t)ESC*4);
  int* csr_src_bb=(int*) alloc((size_t)EBB*4);
  int* part     =(int*)  alloc(256*4);

  const int* src_sc=(const int*)d_in[48];
  const int* dst_sc=src_sc+ESC;
  const int* src_bb=(const int*)d_in[49];
  const int* dst_bb=src_bb+EBB;

  k_detect<<<1,1,0,stream>>>(d_in[0], flag);

  CvtArgs ca;
  {
    int map[29]={14,15,16,17,18,19,20,21,22,23,24,25,30,31,32,33,34,35,36,37,
                 38,39,40,41,42,43,44,45,13};
    for(int i=0;i<29;i++) ca.src[i]=d_in[map[i]];
  }
  k_cvtw<<<(OW_TOT+255)/256,256,0,stream>>>(ca, flag, warena);

  k_prevec<<<1,128,0,stream>>>(warena, d_in[26], d_in[27], d_in[28], d_in[29], flag, dv);
  k_preP<<<441,128,0,stream>>>(warena, P, sp, qp);

  k_feat_sc<<<N_,128,0,stream>>>(d_in[0], d_in[1], flag, warena, hat_h);
  k_feat_bb<<<N_,128,0,stream>>>(d_in[2], d_in[3], d_in[4], d_in[5], flag, warena, hbuf);

  const int SCAN_B=(N_+1023)/1024;
  hipMemsetAsync(counts,0,(size_t)N_*4,stream);
  k_count<<<(ESC+255)/256,256,0,stream>>>(dst_sc,ESC,counts);
  k_scan1<<<SCAN_B,1024,0,stream>>>(counts,N_,rp_sc,part);
  k_scan2<<<1,64,0,stream>>>(part,SCAN_B);
  k_scan3<<<SCAN_B,1024,0,stream>>>(rp_sc,N_,part,ESC);
  hipMemsetAsync(counts,0,(size_t)N_*4,stream);
  k_fill<<<(ESC+255)/256,256,0,stream>>>(src_sc,dst_sc,ESC,rp_sc,counts,csr_src_sc,csr_eid_sc);
  k_sort2<<<(N_+255)/256,256,0,stream>>>(rp_sc,csr_eid_sc,csr_src_sc,N_);

  hipMemsetAsync(counts,0,(size_t)N_*4,stream);
  k_count<<<(EBB+255)/256,256,0,stream>>>(dst_bb,EBB,counts);
  k_scan1<<<SCAN_B,1024,0,stream>>>(counts,N_,rp_bb,part);
  k_scan2<<<1,64,0,stream>>>(part,SCAN_B);
  k_scan3<<<SCAN_B,1024,0,stream>>>(rp_bb,N_,part,EBB);
  hipMemsetAsync(counts,0,(size_t)N_*4,stream);
  k_fill<<<(EBB+255)/256,256,0,stream>>>(src_bb,dst_bb,EBB,rp_bb,counts,csr_src_bb,(int*)nullptr);
  k_sort1<<<(N_+255)/256,256,0,stream>>>(rp_bb,csr_src_bb,N_);

  k_w0<<<ESC/16,256,0,stream>>>(d_in[6],d_in[7],(const int*)d_in[46],(const int*)d_in[47],
                                flag,dv,P,sp,qp,we);
  k_deg_bb<<<(N_+255)/256,256,0,stream>>>(rp_bb,disb);

  const int GB = (N_+63)/64;
  for(int l=0;l<3;l++){
    k_gemm<128><<<GB,256,0,stream>>>(hat_h, nullptr, warena+OW_GW, nullptr, bufX, 0, 0, N_);
    k_deg_sc<<<(N_+255)/256,256,0,stream>>>(rp_sc,csr_eid_sc,we,dis);
    k_agg_sc<<<N_/4,256,0,stream>>>(rp_sc,csr_src_sc,csr_eid_sc,we,dis,bufX,warena,hat_h);
    if(l<2){
      k_ndot<<<N_/4,256,0,stream>>>(hat_h,dv,an,bn);
      k_wupd<<<(ESC+255)/256,256,0,stream>>>(src_sc,dst_sc,an,bn,dv,we);
    }
  }

  for(int l=0;l<2;l++){
    k_gemm<256><<<GB,256,0,stream>>>(hbuf, hat_h, warena+OW_IW1, warena+OW_IB1, bufH, 1, 0, N_);
    k_gemm<128><<<GB,256,0,stream>>>(hbuf, nullptr, warena+OW_BGW, nullptr, bufX, 0, 0, N_);
    k_agg_bb<<<N_/4,256,0,stream>>>(rp_bb,csr_src_bb,disb,bufX,warena,hbuf);
    k_gemm<128><<<GB,256,0,stream>>>(bufH, nullptr, warena+OW_IW2, warena+OW_IB2, hbuf, 0, 1, N_);
  }

  k_heads<<<N_/4,256,0,stream>>>(hat_h,hbuf,warena,
                                 d_in[8],d_in[9],d_in[10],d_in[11],d_in[12],flag,d_out);
}

// Round 4
// 990.963 us; speedup vs baseline: 1.1962x; 1.1010x over previous
//
#include <hip/hip_runtime.h>
#include <stdint.h>

#define DEVI __device__ __forceinline__

constexpr int N_   = 50000;
constexpr int ESC  = 600000;
constexpr int EBB  = 100000;
constexpr int NRES = 21;
constexpr float PI_F = 3.14159f;

typedef __attribute__((ext_vector_type(8))) short short8v;
typedef __attribute__((ext_vector_type(4))) float f32x4;

// ---------- dtype helpers (runtime f32-vs-bf16 dispatch) ----------
DEVI float bf2f(unsigned short u){ return __uint_as_float(((unsigned)u)<<16); }
DEVI unsigned short f2bf(float f){
  unsigned x = __float_as_uint(f);
  unsigned r = (x + 0x7FFFu + ((x>>16)&1u))>>16;
  return (unsigned short)r;
}
DEVI float ldin(const void* p, long i, int f32){
  return f32 ? ((const float*)p)[i] : bf2f(((const unsigned short*)p)[i]);
}
DEVI void stout(void* p, long i, float v, int f32){
  if(f32) ((float*)p)[i]=v; else ((unsigned short*)p)[i]=f2bf(v);
}
DEVI float wrapf(float a){
  float t = a + PI_F;
  const float TP = 2.f*PI_F;
  t -= floorf(t/TP)*TP;
  return t - PI_F;
}

// ---------- weight arena offsets (floats) ----------
constexpr int OW_SC_LN_G=0;
constexpr int OW_SC_LN_B=OW_SC_LN_G+19;
constexpr int OW_SC_W  = OW_SC_LN_B+19;
constexpr int OW_SC_B  = OW_SC_W+19*128;
constexpr int OW_BB_LN_G=OW_SC_B+128;
constexpr int OW_BB_LN_B=OW_BB_LN_G+38;
constexpr int OW_BB_W = OW_BB_LN_B+38;
constexpr int OW_BB_B = OW_BB_W+38*128;
constexpr int OW_E_LN_G=OW_BB_B+128;
constexpr int OW_E_LN_B=OW_E_LN_G+66;
constexpr int OW_EW1 = OW_E_LN_B+66;
constexpr int OW_EB1 = OW_EW1+66*128;
constexpr int OW_GW  = OW_EB1+128;
constexpr int OW_GB  = OW_GW+128*128;
constexpr int OW_BGW = OW_GB+128;
constexpr int OW_BGB = OW_BGW+128*128;
constexpr int OW_IW1 = OW_BGB+128;
constexpr int OW_IB1 = OW_IW1+256*128;
constexpr int OW_IW2 = OW_IB1+128;
constexpr int OW_IB2 = OW_IW2+128*128;
constexpr int OW_AW  = OW_IB2+128;
constexpr int OW_AB  = OW_AW+128;
constexpr int OW_BAW = OW_AB+1;
constexpr int OW_BAB = OW_BAW+128;
constexpr int OW_CW  = OW_BAB+1;
constexpr int OW_CB  = OW_CW+128*3;
constexpr int OW_XW  = OW_CB+3;
constexpr int OW_XB  = OW_XW+128*3;
constexpr int OW_RES = OW_XB+3;
constexpr int OW_TOT = OW_RES+21*32;

// ---------- kernels ----------
__global__ void k_detect(const void* vcom, int* flag){
  const unsigned short* u = (const unsigned short*)vcom;
  int insane=0;
  for(int i=0;i<64;i+=2){
    float f = bf2f(u[i]);
    float a = fabsf(f);
    if(!(a<1e5f) || (a!=0.0f && a<1e-5f)) insane++;
  }
  *flag = (insane>=8)?1:0;
}

struct CvtArgs { const void* src[29]; };

__global__ void k_cvtw(CvtArgs a, const int* flag, float* w){
  static constexpr int offs[30] = {
    OW_SC_LN_G,OW_SC_LN_B,OW_SC_W,OW_SC_B,OW_BB_LN_G,OW_BB_LN_B,OW_BB_W,OW_BB_B,
    OW_E_LN_G,OW_E_LN_B,OW_EW1,OW_EB1,OW_GW,OW_GB,OW_BGW,OW_BGB,OW_IW1,OW_IB1,
    OW_IW2,OW_IB2,OW_AW,OW_AB,OW_BAW,OW_BAB,OW_CW,OW_CB,OW_XW,OW_XB,OW_RES,OW_TOT};
  int f32=*flag;
  for(int t=blockIdx.x*blockDim.x+threadIdx.x; t<OW_TOT; t+=gridDim.x*blockDim.x){
    int s=0;
    while(t>=offs[s+1]) s++;
    w[t]=ldin(a.src[s], t-offs[s], f32);
  }
}

// W[K x 128] -> MFMA fragment order, split hi/lo bf16.
// slot (kt,nt,lane,i): k = kt*32 + (lane>>4)*8 + i, n = nt*16 + (lane&15)
__global__ void k_wprep(const float* W, unsigned short* hi, unsigned short* lo, int KT){
  int idx = blockIdx.x*blockDim.x + threadIdx.x;
  int tot = KT*8*64;
  if(idx>=tot) return;
  int lane=idx&63, nt=(idx>>6)&7, kt=idx>>9;
  int n = nt*16 + (lane&15);
  int kbase = kt*32 + (lane>>4)*8;
  #pragma unroll
  for(int i=0;i<8;i++){
    float v = W[(long)(kbase+i)*128 + n];
    unsigned short h = f2bf(v);
    float r = v - bf2f(h);
    hi[(long)idx*8+i]=h;
    lo[(long)idx*8+i]=f2bf(r);
  }
}

__global__ void k_prevec(const float* w, const void* eW2, const void* eb2,
                         const void* euW, const void* eub, const int* flag, float* dv){
  int j=threadIdx.x; int f32=*flag;
  const float* g=w+OW_E_LN_G; const float* b=w+OW_E_LN_B; const float* W1=w+OW_EW1;
  float A=g[0]*W1[j], C=g[1]*W1[128+j];
  float G=0,B=0;
  for(int i=0;i<66;i++){ float wij=W1[i*128+j]; G+=g[i]*wij; B+=b[i]*wij; }
  B += w[OW_EB1+j];
  float v2=0; for(int k=0;k<128;k++) v2+=ldin(eW2,(long)j*128+k,f32);
  float us=0,ud=0;
  for(int k=0;k<128;k++){ us+=ldin(euW,(long)j*128+k,f32); ud+=ldin(euW,(long)(128+j)*128+k,f32); }
  dv[j]=A; dv[128+j]=C; dv[256+j]=G; dv[384+j]=B;
  dv[512+j]=v2*(1.f/128.f); dv[640+j]=us*(1.f/128.f); dv[768+j]=ud*(1.f/128.f);
  if(j==0){
    float s=0,t=0;
    for(int k=0;k<128;k++){ s+=ldin(eb2,k,f32); t+=ldin(eub,k,f32); }
    dv[896]=s*(1.f/128.f); dv[897]=t*(1.f/128.f);
  }
}

__global__ void k_preP(const float* w, float* P, float* sp, float* qp){
  __shared__ float pv[64];
  int c=blockIdx.x, ri=c/NRES, rj=c%NRES, j=threadIdx.x;
  const float* res=w+OW_RES;
  if(j<32) pv[j]=res[ri*32+j];
  else if(j<64) pv[j]=res[rj*32+(j-32)];
  __syncthreads();
  const float* g=w+OW_E_LN_G; const float* W1=w+OW_EW1;
  float s=0;
  for(int i=0;i<64;i++) s += pv[i]*g[2+i]*W1[(2+i)*128+j];
  P[c*128+j]=s;
  if(j==0){ float a=0,q=0; for(int i=0;i<64;i++){a+=pv[i]; q+=pv[i]*pv[i];} sp[c]=a; qp[c]=q; }
}

__global__ void k_feat_sc(const void* vcom, const void* sbfchi, const int* flag,
                          const float* w, float* hat_h){
  __shared__ float x[19];
  int n=blockIdx.x, j=threadIdx.x, f32=*flag;
  if(j<3) x[j]=ldin(vcom,(long)n*3+j,f32);
  else if(j<19) x[j]=ldin(sbfchi,(long)n*16+(j-3),f32);
  __syncthreads();
  float m=0; for(int i=0;i<19;i++) m+=x[i]; m*=(1.f/19.f);
  float v=0; for(int i=0;i<19;i++){float d=x[i]-m; v+=d*d;} v*=(1.f/19.f);
  float istd=rsqrtf(v+1e-5f);
  float acc=w[OW_SC_B+j];
  for(int i=0;i<19;i++){
    float xn=(x[i]-m)*istd*w[OW_SC_LN_G+i]+w[OW_SC_LN_B+i];
    acc+=xn*w[OW_SC_W+i*128+j];
  }
  hat_h[(long)n*128+j]=acc;
}

__global__ void k_feat_bb(const void* xca, const void* vcb, const void* sphi, const void* spsi,
                          const int* flag, const float* w, float* h){
  __shared__ float x[38];
  int n=blockIdx.x, j=threadIdx.x, f32=*flag;
  if(j<3) x[j]=ldin(xca,(long)n*3+j,f32);
  else if(j<6) x[j]=ldin(vcb,(long)n*3+(j-3),f32);
  else if(j<22) x[j]=ldin(sphi,(long)n*16+(j-6),f32);
  else if(j<38) x[j]=ldin(spsi,(long)n*16+(j-22),f32);
  __syncthreads();
  float m=0; for(int i=0;i<38;i++) m+=x[i]; m*=(1.f/38.f);
  float v=0; for(int i=0;i<38;i++){float d=x[i]-m; v+=d*d;} v*=(1.f/38.f);
  float istd=rsqrtf(v+1e-5f);
  float acc=w[OW_BB_B+j];
  for(int i=0;i<38;i++){
    float xn=(x[i]-m)*istd*w[OW_BB_LN_G+i]+w[OW_BB_LN_B+i];
    acc+=xn*w[OW_BB_W+i*128+j];
  }
  h[(long)n*128+j]=acc;
}

// ---------- CSR build ----------
__global__ void k_count(const int* dst, int E, int* counts){
  int e=blockIdx.x*blockDim.x+threadIdx.x;
  if(e<E) atomicAdd(&counts[dst[e]],1);
}
__global__ void k_scan1(const int* in, int n, int* excl, int* part){
  __shared__ int s[1024];
  int i=blockIdx.x*1024+threadIdx.x;
  int v=(i<n)?in[i]:0;
  s[threadIdx.x]=v; __syncthreads();
  for(int off=1; off<1024; off<<=1){
    int t=(threadIdx.x>=off)?s[threadIdx.x-off]:0;
    __syncthreads();
    s[threadIdx.x]+=t; __syncthreads();
  }
  if(i<n) excl[i]=s[threadIdx.x]-v;
  if(threadIdx.x==1023) part[blockIdx.x]=s[1023];
}
__global__ void k_scan2(int* part, int nb){
  if(threadIdx.x==0 && blockIdx.x==0){
    int run=0;
    for(int b=0;b<nb;b++){ int t=part[b]; part[b]=run; run+=t; }
  }
}
__global__ void k_scan3(int* rp, int n, const int* part, int E){
  int i=blockIdx.x*1024+threadIdx.x;
  if(i<n) rp[i]+=part[blockIdx.x];
  if(i==n) rp[n]=E;
}
__global__ void k_fill(const int* src, const int* dst, int E, const int* rp,
                       int* cursor, int* csr_src, int* csr_eid){
  int e=blockIdx.x*blockDim.x+threadIdx.x;
  if(e>=E) return;
  int d=dst[e];
  int p=rp[d]+atomicAdd(&cursor[d],1);
  csr_src[p]=src[e];
  if(csr_eid) csr_eid[p]=e;
}
__global__ void k_sort2(const int* rp, int* key, int* val, int n){
  int v=blockIdx.x*blockDim.x+threadIdx.x;
  if(v>=n) return;
  int e0=rp[v], e1=rp[v+1];
  for(int i=e0+1;i<e1;i++){
    int kk=key[i], vv=val[i];
    int j=i-1;
    while(j>=e0 && key[j]>kk){ key[j+1]=key[j]; val[j+1]=val[j]; j--; }
    key[j+1]=kk; val[j+1]=vv;
  }
}
__global__ void k_sort1(const int* rp, int* key, int n){
  int v=blockIdx.x*blockDim.x+threadIdx.x;
  if(v>=n) return;
  int e0=rp[v], e1=rp[v+1];
  for(int i=e0+1;i<e1;i++){
    int kk=key[i];
    int j=i-1;
    while(j>=e0 && key[j]>kk){ key[j+1]=key[j]; j--; }
    key[j+1]=kk;
  }
}

// ---------- per-layer ----------
__global__ void k_deg_sc(const int* rp, const int* eid, const float* we, float* dis){
  int n=blockIdx.x*blockDim.x+threadIdx.x;
  if(n>=N_) return;
  float s=1.f;
  int e0=rp[n], e1=rp[n+1];
  for(int p=e0;p<e1;p++) s+=we[eid[p]];
  dis[n]=rsqrtf(fmaxf(s,1e-6f));
}
__global__ void k_deg_bb(const int* rp, float* dis){
  int n=blockIdx.x*blockDim.x+threadIdx.x;
  if(n>=N_) return;
  float s=1.f+(float)(rp[n+1]-rp[n]);
  dis[n]=rsqrtf(fmaxf(s,1e-6f));
}

__global__ void k_w0(const void* dsc, const void* dmin, const int* ri_, const int* rj_,
                     const int* flag, const float* dv, const float* P,
                     const float* sp, const float* qp, float* we){
  int tid=threadIdx.x, g=tid>>4, gl=tid&15;
  long e=(long)blockIdx.x*16+g;
  if(e>=ESC) return;
  int f32=*flag;
  float d1=ldin(dsc,e,f32), d2=ldin(dmin,e,f32);
  int c=ri_[e]*NRES+rj_[e];
  float m=(d1+d2+sp[c])*(1.f/66.f);
  float ms=(d1*d1+d2*d2+qp[c])*(1.f/66.f);
  float istd=rsqrtf(fmaxf(ms-m*m,0.f)+1e-5f);
  float mi=m*istd;
  float acc=0;
  #pragma unroll
  for(int t=0;t<8;t++){
    int j=gl+(t<<4);
    float hid=istd*(d1*dv[j]+d2*dv[128+j]+P[c*128+j])-mi*dv[256+j]+dv[384+j];
    acc+=fmaxf(hid,0.f)*dv[512+j];
  }
  for(int msk=1;msk<16;msk<<=1) acc+=__shfl_xor(acc,msk,64);
  if(gl==0) we[e]=acc+dv[896];
}

// ---------- split-bf16 MFMA GEMM ----------
// C[M,128] = (relu?)(A1@W[0:128] (+A2@W[128:256]) + bias) (+=C if accum)
// Per block: 4 waves x 16 rows = 64 rows. Per wave: 8 n-tiles of 16 cols.
// Fragments: A row = lane&15, k-slot group = lane>>4 (same slot->k map used
// for W in k_wprep, so the result is invariant to HW k-permutation).
// C/D layout (verified): col = lane&15, row = (lane>>4)*4 + reg.
DEVI f32x4 MFMA(short8v a, short8v b, f32x4 c){
  return __builtin_amdgcn_mfma_f32_16x16x32_bf16(a,b,c,0,0,0);
}
DEVI void cvt8(float4 a0, float4 a1, short8v& hi, short8v& lo){
  float av[8]={a0.x,a0.y,a0.z,a0.w,a1.x,a1.y,a1.z,a1.w};
  union{short8v v; unsigned short u[8];} H,L;
  #pragma unroll
  for(int i=0;i<8;i++){
    unsigned short h=f2bf(av[i]);
    float r=av[i]-bf2f(h);
    H.u[i]=h; L.u[i]=f2bf(r);
  }
  hi=H.v; lo=L.v;
}

template<int KT>
__global__ __launch_bounds__(256,4) void k_mgemm(const float* A1, const float* A2,
    const unsigned short* Whi, const unsigned short* Wlo,
    const float* bias, float* C, int relu, int accum, int M){
  const int lane = threadIdx.x & 63;
  const int wid  = threadIdx.x >> 6;
  const int r0   = blockIdx.x*64 + wid*16;
  const int mrow = lane & 15;
  const int kg   = lane >> 4;
  long arow = (long)min(r0 + mrow, M-1);
  f32x4 acc[8];
  #pragma unroll
  for(int t=0;t<8;t++) acc[t]=(f32x4){0.f,0.f,0.f,0.f};

  #pragma unroll
  for(int kt=0; kt<KT; kt++){
    const float* A = (KT==8 && kt>=4) ? A2 : A1;
    int kb = (kt&3)*32 + kg*8;
    float4 a0 = *(const float4*)&A[arow*128 + kb];
    float4 a1 = *(const float4*)&A[arow*128 + kb + 4];
    short8v ah, al; cvt8(a0,a1,ah,al);
    #pragma unroll
    for(int nt=0;nt<8;nt++){
      long off = (((long)kt*8+nt)*64 + lane)*8;
      short8v wh = *(const short8v*)&Whi[off];
      short8v wl = *(const short8v*)&Wlo[off];
      acc[nt] = MFMA(ah, wh, acc[nt]);
      acc[nt] = MFMA(al, wh, acc[nt]);
      acc[nt] = MFMA(ah, wl, acc[nt]);
      acc[nt] = MFMA(al, wl, acc[nt]);
    }
  }

  #pragma unroll
  for(int nt=0;nt<8;nt++){
    int col = nt*16 + mrow;
    float bj = bias ? bias[col] : 0.f;
    #pragma unroll
    for(int r=0;r<4;r++){
      int row = r0 + kg*4 + r;
      if(row >= M) continue;
      long idx = (long)row*128 + col;
      float v = acc[nt][r] + bj;
      if(relu) v = fmaxf(v,0.f);
      if(accum) v += C[idx];
      C[idx] = v;
    }
  }
}

__global__ void k_agg_sc(const int* rp, const int* csrc, const int* ceid,
                         const float* we, const float* dis, const float* xw,
                         const float* w, float* hat_h){
  int wv=threadIdx.x>>6, lane=threadIdx.x&63;
  int n=blockIdx.x*4+wv;
  float disn=dis[n];
  float ax=0.f, ay=0.f;
  int e0=rp[n], e1=rp[n+1];
  int p=e0;
  for(; p+1<e1; p+=2){
    int s0=csrc[p], s1=csrc[p+1];
    float nw0=dis[s0]*we[ceid[p]]*disn;
    float nw1=dis[s1]*we[ceid[p+1]]*disn;
    float2 x0=*(const float2*)&xw[(long)s0*128+lane*2];
    float2 x1=*(const float2*)&xw[(long)s1*128+lane*2];
    ax+=nw0*x0.x+nw1*x1.x;
    ay+=nw0*x0.y+nw1*x1.y;
  }
  if(p<e1){
    int s0=csrc[p];
    float nw0=dis[s0]*we[ceid[p]]*disn;
    float2 x0=*(const float2*)&xw[(long)s0*128+lane*2];
    ax+=nw0*x0.x; ay+=nw0*x0.y;
  }
  float d2=disn*disn;
  float2 xs=*(const float2*)&xw[(long)n*128+lane*2];
  ax+=d2*xs.x+w[OW_GB+lane*2];
  ay+=d2*xs.y+w[OW_GB+lane*2+1];
  float2 h=*(float2*)&hat_h[(long)n*128+lane*2];
  h.x+=fmaxf(ax,0.f); h.y+=fmaxf(ay,0.f);
  *(float2*)&hat_h[(long)n*128+lane*2]=h;
}

__global__ void k_ndot(const float* hat_h, const float* dv, float* an, float* bn){
  int wv=threadIdx.x>>6, lane=threadIdx.x&63;
  int n=blockIdx.x*4+wv;
  float h0=hat_h[(long)n*128+lane], h1=hat_h[(long)n*128+64+lane];
  float a=h0*dv[640+lane]+h1*dv[640+64+lane];
  float b=h0*dv[768+lane]+h1*dv[768+64+lane];
  for(int m=1;m<64;m<<=1){ a+=__shfl_xor(a,m,64); b+=__shfl_xor(b,m,64); }
  if(lane==0){ an[n]=a; bn[n]=b; }
}

__global__ void k_wupd(const int* src, const int* dst, const float* an, const float* bn,
                       const float* dv, float* we){
  int e=blockIdx.x*blockDim.x+threadIdx.x;
  if(e>=ESC) return;
  we[e]+=an[src[e]]+bn[dst[e]]+dv[897];
}

__global__ void k_agg_bb(const int* rp, const int* csrc, const float* dis,
                         const float* xw, const float* w, float* h){
  int wv=threadIdx.x>>6, lane=threadIdx.x&63;
  int n=blockIdx.x*4+wv;
  float disn=dis[n];
  float ax=0.f, ay=0.f;
  int e0=rp[n], e1=rp[n+1];
  int p=e0;
  for(; p+1<e1; p+=2){
    int s0=csrc[p], s1=csrc[p+1];
    float nw0=dis[s0]*disn, nw1=dis[s1]*disn;
    float2 x0=*(const float2*)&xw[(long)s0*128+lane*2];
    float2 x1=*(const float2*)&xw[(long)s1*128+lane*2];
    ax+=nw0*x0.x+nw1*x1.x;
    ay+=nw0*x0.y+nw1*x1.y;
  }
  if(p<e1){
    int s0=csrc[p];
    float nw0=dis[s0]*disn;
    float2 x0=*(const float2*)&xw[(long)s0*128+lane*2];
    ax+=nw0*x0.x; ay+=nw0*x0.y;
  }
  float d2=disn*disn;
  float2 xs=*(const float2*)&xw[(long)n*128+lane*2];
  ax+=d2*xs.x+w[OW_BGB+lane*2];
  ay+=d2*xs.y+w[OW_BGB+lane*2+1];
  float2 hv=*(float2*)&h[(long)n*128+lane*2];
  hv.x+=fmaxf(ax,0.f); hv.y+=fmaxf(ay,0.f);
  *(float2*)&h[(long)n*128+lane*2]=hv;
}

__global__ void k_heads(const float* hat_h, const float* h, const float* w,
                        const void* old_chi, const void* old_phi, const void* old_psi,
                        const void* old_cb, const void* old_ca, const int* flag, void* out){
  int wv=threadIdx.x>>6, lane=threadIdx.x&63;
  int n=blockIdx.x*4+wv;
  int f32=*flag;
  float s0=fmaxf(hat_h[(long)n*128+lane],0.f), s1=fmaxf(hat_h[(long)n*128+64+lane],0.f);
  float b0=fmaxf(h[(long)n*128+lane],0.f),    b1=fmaxf(h[(long)n*128+64+lane],0.f);
  float r[8];
  r[0]=s0*w[OW_AW+lane]+s1*w[OW_AW+64+lane];
  r[1]=s0*w[OW_CW+lane*3+0]+s1*w[OW_CW+(64+lane)*3+0];
  r[2]=s0*w[OW_CW+lane*3+1]+s1*w[OW_CW+(64+lane)*3+1];
  r[3]=s0*w[OW_CW+lane*3+2]+s1*w[OW_CW+(64+lane)*3+2];
  r[4]=b0*w[OW_BAW+lane]+b1*w[OW_BAW+64+lane];
  r[5]=b0*w[OW_XW+lane*3+0]+b1*w[OW_XW+(64+lane)*3+0];
  r[6]=b0*w[OW_XW+lane*3+1]+b1*w[OW_XW+(64+lane)*3+1];
  r[7]=b0*w[OW_XW+lane*3+2]+b1*w[OW_XW+(64+lane)*3+2];
  for(int m=1;m<64;m<<=1){
    #pragma unroll
    for(int t=0;t<8;t++) r[t]+=__shfl_xor(r[t],m,64);
  }
  if(lane==0){
    float dchi=r[0]+w[OW_AB];
    for(int k=0;k<4;k++)
      stout(out,(long)k*N_+n, wrapf(ldin(old_chi,(long)k*N_+n,f32)+dchi), f32);
    float dphi=r[4]+w[OW_BAB];
    stout(out,(long)4*N_+n, wrapf(ldin(old_phi,n,f32)+dphi), f32);
    stout(out,(long)5*N_+n, wrapf(ldin(old_psi,n,f32)+dphi), f32);
    for(int t=0;t<3;t++){
      stout(out,(long)6*N_+(long)n*3+t, ldin(old_cb,(long)n*3+t,f32)+r[1+t]+w[OW_CB+t], f32);
      stout(out,(long)9*N_+(long)n*3+t, ldin(old_ca,(long)n*3+t,f32)+r[5+t]+w[OW_XB+t], f32);
    }
  }
}

// ---------- host ----------
extern "C" void kernel_launch(void* const* d_in, const int* in_sizes, int n_in,
                              void* d_out, int out_size, void* d_ws, size_t ws_size,
                              hipStream_t stream) {
  (void)in_sizes; (void)n_in; (void)out_size; (void)ws_size;

  char* p=(char*)d_ws;
  auto alloc=[&](size_t bytes)->void*{ void* r=(void*)p; p+=((bytes+255)&~(size_t)255); return r; };
  int*   flag   =(int*)  alloc(16);
  float* warena =(float*)alloc((size_t)OW_TOT*4);
  float* dv     =(float*)alloc(1024*4);
  float* P      =(float*)alloc((size_t)441*128*4);
  float* sp     =(float*)alloc(441*4);
  float* qp     =(float*)alloc(441*4);
  float* hat_h  =(float*)alloc((size_t)N_*128*4);
  float* hbuf   =(float*)alloc((size_t)N_*128*4);
  float* bufX   =(float*)alloc((size_t)N_*128*4);
  float* bufH   =(float*)alloc((size_t)N_*128*4);
  float* we     =(float*)alloc((size_t)ESC*4);
  float* an     =(float*)alloc((size_t)N_*4);
  float* bn     =(float*)alloc((size_t)N_*4);
  float* dis    =(float*)alloc((size_t)N_*4);
  float* disb   =(float*)alloc((size_t)N_*4);
  int* counts   =(int*)  alloc((size_t)N_*4);
  int* rp_sc    =(int*)  alloc((size_t)(N_+1)*4);
  int* rp_bb    =(int*)  alloc((size_t)(N_+1)*4);
  int* csr_src_sc=(int*) alloc((size_t)ESC*4);
  int* csr_eid_sc=(int*) alloc((size_t)ESC*4);
  int* csr_src_bb=(int*) alloc((size_t)EBB*4);
  int* part     =(int*)  alloc(256*4);
  // MFMA weight fragments (hi/lo bf16), 2048 slots per 128-K matrix
  unsigned short* wfg_hi =(unsigned short*)alloc(2048*8*2);
  unsigned short* wfg_lo =(unsigned short*)alloc(2048*8*2);
  unsigned short* wfbg_hi=(unsigned short*)alloc(2048*8*2);
  unsigned short* wfbg_lo=(unsigned short*)alloc(2048*8*2);
  unsigned short* wfi2_hi=(unsigned short*)alloc(2048*8*2);
  unsigned short* wfi2_lo=(unsigned short*)alloc(2048*8*2);
  unsigned short* wfi1_hi=(unsigned short*)alloc(4096*8*2);
  unsigned short* wfi1_lo=(unsigned short*)alloc(4096*8*2);

  const int* src_sc=(const int*)d_in[48];
  const int* dst_sc=src_sc+ESC;
  const int* src_bb=(const int*)d_in[49];
  const int* dst_bb=src_bb+EBB;

  k_detect<<<1,1,0,stream>>>(d_in[0], flag);

  CvtArgs ca;
  {
    int map[29]={14,15,16,17,18,19,20,21,22,23,24,25,30,31,32,33,34,35,36,37,
                 38,39,40,41,42,43,44,45,13};
    for(int i=0;i<29;i++) ca.src[i]=d_in[map[i]];
  }
  k_cvtw<<<(OW_TOT+255)/256,256,0,stream>>>(ca, flag, warena);

  // weight fragment prep (after cvtw)
  k_wprep<<<(2048+255)/256,256,0,stream>>>(warena+OW_GW,  wfg_hi,  wfg_lo,  4);
  k_wprep<<<(2048+255)/256,256,0,stream>>>(warena+OW_BGW, wfbg_hi, wfbg_lo, 4);
  k_wprep<<<(2048+255)/256,256,0,stream>>>(warena+OW_IW2, wfi2_hi, wfi2_lo, 4);
  k_wprep<<<(4096+255)/256,256,0,stream>>>(warena+OW_IW1, wfi1_hi, wfi1_lo, 8);

  k_prevec<<<1,128,0,stream>>>(warena, d_in[26], d_in[27], d_in[28], d_in[29], flag, dv);
  k_preP<<<441,128,0,stream>>>(warena, P, sp, qp);

  k_feat_sc<<<N_,128,0,stream>>>(d_in[0], d_in[1], flag, warena, hat_h);
  k_feat_bb<<<N_,128,0,stream>>>(d_in[2], d_in[3], d_in[4], d_in[5], flag, warena, hbuf);

  const int SCAN_B=(N_+1023)/1024;
  hipMemsetAsync(counts,0,(size_t)N_*4,stream);
  k_count<<<(ESC+255)/256,256,0,stream>>>(dst_sc,ESC,counts);
  k_scan1<<<SCAN_B,1024,0,stream>>>(counts,N_,rp_sc,part);
  k_scan2<<<1,64,0,stream>>>(part,SCAN_B);
  k_scan3<<<SCAN_B,1024,0,stream>>>(rp_sc,N_,part,ESC);
  hipMemsetAsync(counts,0,(size_t)N_*4,stream);
  k_fill<<<(ESC+255)/256,256,0,stream>>>(src_sc,dst_sc,ESC,rp_sc,counts,csr_src_sc,csr_eid_sc);
  k_sort2<<<(N_+255)/256,256,0,stream>>>(rp_sc,csr_eid_sc,csr_src_sc,N_);

  hipMemsetAsync(counts,0,(size_t)N_*4,stream);
  k_count<<<(EBB+255)/256,256,0,stream>>>(dst_bb,EBB,counts);
  k_scan1<<<SCAN_B,1024,0,stream>>>(counts,N_,rp_bb,part);
  k_scan2<<<1,64,0,stream>>>(part,SCAN_B);
  k_scan3<<<SCAN_B,1024,0,stream>>>(rp_bb,N_,part,EBB);
  hipMemsetAsync(counts,0,(size_t)N_*4,stream);
  k_fill<<<(EBB+255)/256,256,0,stream>>>(src_bb,dst_bb,EBB,rp_bb,counts,csr_src_bb,(int*)nullptr);
  k_sort1<<<(N_+255)/256,256,0,stream>>>(rp_bb,csr_src_bb,N_);

  k_w0<<<ESC/16,256,0,stream>>>(d_in[6],d_in[7],(const int*)d_in[46],(const int*)d_in[47],
                                flag,dv,P,sp,qp,we);
  k_deg_bb<<<(N_+255)/256,256,0,stream>>>(rp_bb,disb);

  const int GB = (N_+63)/64;
  for(int l=0;l<3;l++){
    k_mgemm<4><<<GB,256,0,stream>>>(hat_h, nullptr, wfg_hi, wfg_lo, nullptr, bufX, 0, 0, N_);
    k_deg_sc<<<(N_+255)/256,256,0,stream>>>(rp_sc,csr_eid_sc,we,dis);
    k_agg_sc<<<N_/4,256,0,stream>>>(rp_sc,csr_src_sc,csr_eid_sc,we,dis,bufX,warena,hat_h);
    if(l<2){
      k_ndot<<<N_/4,256,0,stream>>>(hat_h,dv,an,bn);
      k_wupd<<<(ESC+255)/256,256,0,stream>>>(src_sc,dst_sc,an,bn,dv,we);
    }
  }

  for(int l=0;l<2;l++){
    k_mgemm<8><<<GB,256,0,stream>>>(hbuf, hat_h, wfi1_hi, wfi1_lo, warena+OW_IB1, bufH, 1, 0, N_);
    k_mgemm<4><<<GB,256,0,stream>>>(hbuf, nullptr, wfbg_hi, wfbg_lo, nullptr, bufX, 0, 0, N_);
    k_agg_bb<<<N_/4,256,0,stream>>>(rp_bb,csr_src_bb,disb,bufX,warena,hbuf);
    k_mgemm<4><<<GB,256,0,stream>>>(bufH, nullptr, wfi2_hi, wfi2_lo, warena+OW_IB2, hbuf, 0, 1, N_);
  }

  k_heads<<<N_/4,256,0,stream>>>(hat_h,hbuf,warena,
                                 d_in[8],d_in[9],d_in[10],d_in[11],d_in[12],flag,d_out);
}

// Round 5
// 821.096 us; speedup vs baseline: 1.4437x; 1.2069x over previous
//
#include <hip/hip_runtime.h>
#include <stdint.h>

#define DEVI __device__ __forceinline__

constexpr int N_   = 50000;
constexpr int ESC  = 600000;
constexpr int EBB  = 100000;
constexpr int NRES = 21;
constexpr int SCB  = (N_+1023)/1024;   // 49 scan blocks per array
constexpr float PI_F = 3.14159f;

typedef __attribute__((ext_vector_type(8))) short short8v;
typedef __attribute__((ext_vector_type(4))) float f32x4;

// ---------- dtype helpers (runtime f32-vs-bf16 dispatch) ----------
DEVI float bf2f(unsigned short u){ return __uint_as_float(((unsigned)u)<<16); }
DEVI unsigned short f2bf(float f){
  unsigned x = __float_as_uint(f);
  unsigned r = (x + 0x7FFFu + ((x>>16)&1u))>>16;
  return (unsigned short)r;
}
DEVI float ldin(const void* p, long i, int f32){
  return f32 ? ((const float*)p)[i] : bf2f(((const unsigned short*)p)[i]);
}
DEVI void stout(void* p, long i, float v, int f32){
  if(f32) ((float*)p)[i]=v; else ((unsigned short*)p)[i]=f2bf(v);
}
DEVI float wrapf(float a){
  float t = a + PI_F;
  const float TP = 2.f*PI_F;
  t -= floorf(t/TP)*TP;
  return t - PI_F;
}

// ---------- weight arena offsets (floats) ----------
constexpr int OW_SC_LN_G=0;
constexpr int OW_SC_LN_B=OW_SC_LN_G+19;
constexpr int OW_SC_W  = OW_SC_LN_B+19;
constexpr int OW_SC_B  = OW_SC_W+19*128;
constexpr int OW_BB_LN_G=OW_SC_B+128;
constexpr int OW_BB_LN_B=OW_BB_LN_G+38;
constexpr int OW_BB_W = OW_BB_LN_B+38;
constexpr int OW_BB_B = OW_BB_W+38*128;
constexpr int OW_E_LN_G=OW_BB_B+128;
constexpr int OW_E_LN_B=OW_E_LN_G+66;
constexpr int OW_EW1 = OW_E_LN_B+66;
constexpr int OW_EB1 = OW_EW1+66*128;
constexpr int OW_GW  = OW_EB1+128;
constexpr int OW_GB  = OW_GW+128*128;
constexpr int OW_BGW = OW_GB+128;
constexpr int OW_BGB = OW_BGW+128*128;
constexpr int OW_IW1 = OW_BGB+128;
constexpr int OW_IB1 = OW_IW1+256*128;
constexpr int OW_IW2 = OW_IB1+128;
constexpr int OW_IB2 = OW_IW2+128*128;
constexpr int OW_AW  = OW_IB2+128;
constexpr int OW_AB  = OW_AW+128;
constexpr int OW_BAW = OW_AB+1;
constexpr int OW_BAB = OW_BAW+128;
constexpr int OW_CW  = OW_BAB+1;
constexpr int OW_CB  = OW_CW+128*3;
constexpr int OW_XW  = OW_CB+3;
constexpr int OW_XB  = OW_XW+128*3;
constexpr int OW_RES = OW_XB+3;
constexpr int OW_TOT = OW_RES+21*32;

// dv: usm at 640, udm at 768, dv[896]=eb2m, dv[897]=eubm
// dv4: per j4 (0..31): 20 floats = {A4,C4,G4,B4,V4}; dv4[640]=eb2m

// ---------- kernels ----------
__global__ void k_detect(const void* vcom, int* flag){
  const unsigned short* u = (const unsigned short*)vcom;
  int insane=0;
  for(int i=0;i<64;i+=2){
    float f = bf2f(u[i]);
    float a = fabsf(f);
    if(!(a<1e5f) || (a!=0.0f && a<1e-5f)) insane++;
  }
  *flag = (insane>=8)?1:0;
}

struct CvtArgs { const void* src[29]; };

__global__ void k_cvtw(CvtArgs a, const int* flag, float* w){
  static constexpr int offs[30] = {
    OW_SC_LN_G,OW_SC_LN_B,OW_SC_W,OW_SC_B,OW_BB_LN_G,OW_BB_LN_B,OW_BB_W,OW_BB_B,
    OW_E_LN_G,OW_E_LN_B,OW_EW1,OW_EB1,OW_GW,OW_GB,OW_BGW,OW_BGB,OW_IW1,OW_IB1,
    OW_IW2,OW_IB2,OW_AW,OW_AB,OW_BAW,OW_BAB,OW_CW,OW_CB,OW_XW,OW_XB,OW_RES,OW_TOT};
  int f32=*flag;
  for(int t=blockIdx.x*blockDim.x+threadIdx.x; t<OW_TOT; t+=gridDim.x*blockDim.x){
    int s=0;
    while(t>=offs[s+1]) s++;
    w[t]=ldin(a.src[s], t-offs[s], f32);
  }
}

// W[K x 128] -> MFMA fragment order, split hi/lo bf16.
// slot (kt,nt,lane,i): k = kt*32 + (lane>>4)*8 + i, n = nt*16 + (lane&15)
DEVI void wprep_one(const float* W, unsigned short* hi, unsigned short* lo, int idx){
  int lane=idx&63, nt=(idx>>6)&7, kt=idx>>9;
  int n = nt*16 + (lane&15);
  int kbase = kt*32 + (lane>>4)*8;
  #pragma unroll
  for(int i=0;i<8;i++){
    float v = W[(long)(kbase+i)*128 + n];
    unsigned short h = f2bf(v);
    float r = v - bf2f(h);
    hi[(long)idx*8+i]=h;
    lo[(long)idx*8+i]=f2bf(r);
  }
}
__global__ void k_wprep4(const float* w,
    unsigned short* g_hi, unsigned short* g_lo,
    unsigned short* bg_hi, unsigned short* bg_lo,
    unsigned short* i2_hi, unsigned short* i2_lo,
    unsigned short* i1_hi, unsigned short* i1_lo){
  int idx = blockIdx.x*blockDim.x + threadIdx.x;
  if(idx<2048)       wprep_one(w+OW_GW,  g_hi,  g_lo,  idx);
  else if(idx<4096)  wprep_one(w+OW_BGW, bg_hi, bg_lo, idx-2048);
  else if(idx<6144)  wprep_one(w+OW_IW2, i2_hi, i2_lo, idx-4096);
  else if(idx<10240) wprep_one(w+OW_IW1, i1_hi, i1_lo, idx-6144);
}

__global__ void k_prevec(const float* w, const void* eW2, const void* eb2,
                         const void* euW, const void* eub, const int* flag,
                         float* dv, float* dv4){
  int j=threadIdx.x; int f32=*flag;
  const float* g=w+OW_E_LN_G; const float* b=w+OW_E_LN_B; const float* W1=w+OW_EW1;
  float A=g[0]*W1[j], C=g[1]*W1[128+j];
  float G=0,B=0;
  for(int i=0;i<66;i++){ float wij=W1[i*128+j]; G+=g[i]*wij; B+=b[i]*wij; }
  B += w[OW_EB1+j];
  float v2=0; for(int k=0;k<128;k++) v2+=ldin(eW2,(long)j*128+k,f32);
  float us=0,ud=0;
  for(int k=0;k<128;k++){ us+=ldin(euW,(long)j*128+k,f32); ud+=ldin(euW,(long)(128+j)*128+k,f32); }
  float v2m=v2*(1.f/128.f);
  dv[640+j]=us*(1.f/128.f); dv[768+j]=ud*(1.f/128.f);
  int j4=j>>2, r=j&3;
  dv4[j4*20+0+r]=A; dv4[j4*20+4+r]=C; dv4[j4*20+8+r]=G; dv4[j4*20+12+r]=B; dv4[j4*20+16+r]=v2m;
  if(j==0){
    float s=0,t=0;
    for(int k=0;k<128;k++){ s+=ldin(eb2,k,f32); t+=ldin(eub,k,f32); }
    dv[896]=s*(1.f/128.f); dv[897]=t*(1.f/128.f);
    dv4[640]=s*(1.f/128.f);
  }
}

__global__ void k_preP(const float* w, float* P, float* sp, float* qp){
  __shared__ float pv[64];
  int c=blockIdx.x, ri=c/NRES, rj=c%NRES, j=threadIdx.x;
  const float* res=w+OW_RES;
  if(j<32) pv[j]=res[ri*32+j];
  else if(j<64) pv[j]=res[rj*32+(j-32)];
  __syncthreads();
  const float* g=w+OW_E_LN_G; const float* W1=w+OW_EW1;
  float s=0;
  for(int i=0;i<64;i++) s += pv[i]*g[2+i]*W1[(2+i)*128+j];
  P[c*128+j]=s;
  if(j==0){ float a=0,q=0; for(int i=0;i<64;i++){a+=pv[i]; q+=pv[i]*pv[i];} sp[c]=a; qp[c]=q; }
}

// merged node featurizer: blocks [0,N) -> sidechain, [N,2N) -> backbone
__global__ void k_feat(const void* vcom, const void* sbfchi,
                       const void* xca, const void* vcb, const void* sphi, const void* spsi,
                       const int* flag, const float* w, float* hat_h, float* h){
  __shared__ float x[38];
  int nb=blockIdx.x, j=threadIdx.x, f32=*flag;
  if(nb<N_){
    int n=nb;
    if(j<3) x[j]=ldin(vcom,(long)n*3+j,f32);
    else if(j<19) x[j]=ldin(sbfchi,(long)n*16+(j-3),f32);
    __syncthreads();
    float m=0; for(int i=0;i<19;i++) m+=x[i]; m*=(1.f/19.f);
    float v=0; for(int i=0;i<19;i++){float d=x[i]-m; v+=d*d;} v*=(1.f/19.f);
    float istd=rsqrtf(v+1e-5f);
    float acc=w[OW_SC_B+j];
    for(int i=0;i<19;i++){
      float xn=(x[i]-m)*istd*w[OW_SC_LN_G+i]+w[OW_SC_LN_B+i];
      acc+=xn*w[OW_SC_W+i*128+j];
    }
    hat_h[(long)n*128+j]=acc;
  } else {
    int n=nb-N_;
    if(j<3) x[j]=ldin(xca,(long)n*3+j,f32);
    else if(j<6) x[j]=ldin(vcb,(long)n*3+(j-3),f32);
    else if(j<22) x[j]=ldin(sphi,(long)n*16+(j-6),f32);
    else if(j<38) x[j]=ldin(spsi,(long)n*16+(j-22),f32);
    __syncthreads();
    float m=0; for(int i=0;i<38;i++) m+=x[i]; m*=(1.f/38.f);
    float v=0; for(int i=0;i<38;i++){float d=x[i]-m; v+=d*d;} v*=(1.f/38.f);
    float istd=rsqrtf(v+1e-5f);
    float acc=w[OW_BB_B+j];
    for(int i=0;i<38;i++){
      float xn=(x[i]-m)*istd*w[OW_BB_LN_G+i]+w[OW_BB_LN_B+i];
      acc+=xn*w[OW_BB_W+i*128+j];
    }
    h[(long)n*128+j]=acc;
  }
}

// ---------- CSR build (merged sc+bb) ----------
__global__ void k_count2(const int* dst_sc, const int* dst_bb, int* c_sc, int* c_bb){
  int i=blockIdx.x*blockDim.x+threadIdx.x;
  if(i<ESC) atomicAdd(&c_sc[dst_sc[i]],1);
  else if(i<ESC+EBB) atomicAdd(&c_bb[dst_bb[i-ESC]],1);
}
__global__ void k_scan1x2(const int* c_sc, const int* c_bb, int* rp_sc, int* rp_bb, int* part){
  __shared__ int s[1024];
  int half = (blockIdx.x>=SCB);
  int b = half? blockIdx.x-SCB : blockIdx.x;
  const int* in = half? c_bb : c_sc;
  int* excl = half? rp_bb : rp_sc;
  int* pt = part + half*64;
  int i=b*1024+threadIdx.x;
  int v=(i<N_)?in[i]:0;
  s[threadIdx.x]=v; __syncthreads();
  for(int off=1; off<1024; off<<=1){
    int t=(threadIdx.x>=off)?s[threadIdx.x-off]:0;
    __syncthreads();
    s[threadIdx.x]+=t; __syncthreads();
  }
  if(i<N_) excl[i]=s[threadIdx.x]-v;
  if(threadIdx.x==1023) pt[b]=s[1023];
}
__global__ void k_scan2x2(int* part){
  int t=threadIdx.x;
  if(t<2){
    int* pp=part+t*64;
    int run=0;
    for(int b=0;b<SCB;b++){ int v=pp[b]; pp[b]=run; run+=v; }
  }
}
__global__ void k_scan3x2(int* rp_sc, int* rp_bb, const int* part){
  int half = (blockIdx.x>=SCB);
  int b = half? blockIdx.x-SCB : blockIdx.x;
  int* rp = half? rp_bb : rp_sc;
  const int* pt = part + half*64;
  int E = half? EBB : ESC;
  int i=b*1024+threadIdx.x;
  if(i<N_) rp[i]+=pt[b];
  if(i==N_) rp[N_]=E;
}
__global__ void k_fill2(const int* src_sc, const int* dst_sc, const int* src_bb, const int* dst_bb,
                        const int* rp_sc, const int* rp_bb, int* cur_sc, int* cur_bb,
                        int* csr_src_sc, int* csr_eid_sc, int* csr_src_bb){
  int i=blockIdx.x*blockDim.x+threadIdx.x;
  if(i<ESC){
    int d=dst_sc[i];
    int p=rp_sc[d]+atomicAdd(&cur_sc[d],1);
    csr_src_sc[p]=src_sc[i];
    csr_eid_sc[p]=i;
  } else if(i<ESC+EBB){
    int e=i-ESC;
    int d=dst_bb[e];
    int p=rp_bb[d]+atomicAdd(&cur_bb[d],1);
    csr_src_bb[p]=src_bb[e];
  }
}
// deterministic order: per-node insertion sort (sc: by unique eid; bb: by src value)
__global__ void k_sortx(const int* rp_sc, int* key_sc, int* val_sc,
                        const int* rp_bb, int* key_bb){
  int v=blockIdx.x*blockDim.x+threadIdx.x;
  if(v<N_){
    int e0=rp_sc[v], e1=rp_sc[v+1];
    for(int i=e0+1;i<e1;i++){
      int kk=key_sc[i], vv=val_sc[i];
      int j=i-1;
      while(j>=e0 && key_sc[j]>kk){ key_sc[j+1]=key_sc[j]; val_sc[j+1]=val_sc[j]; j--; }
      key_sc[j+1]=kk; val_sc[j+1]=vv;
    }
  } else if(v<2*N_){
    int n=v-N_;
    int e0=rp_bb[n], e1=rp_bb[n+1];
    for(int i=e0+1;i<e1;i++){
      int kk=key_bb[i];
      int j=i-1;
      while(j>=e0 && key_bb[j]>kk){ key_bb[j+1]=key_bb[j]; j--; }
      key_bb[j+1]=kk;
    }
  }
}

// ---------- edge MLP: one edge per lane, float4 over 128 hidden dims ----------
__global__ void k_w0(const void* dsc, const void* dmin, const int* ri_, const int* rj_,
                     const int* flag, const float* dv4, const float* P,
                     const float* sp, const float* qp, float* we){
  int e=blockIdx.x*blockDim.x+threadIdx.x;
  if(e>=ESC) return;
  int f32=*flag;
  float d1=ldin(dsc,e,f32), d2=ldin(dmin,e,f32);
  int c=ri_[e]*NRES+rj_[e];
  float m=(d1+d2+sp[c])*(1.f/66.f);
  float ms=(d1*d1+d2*d2+qp[c])*(1.f/66.f);
  float istd=rsqrtf(fmaxf(ms-m*m,0.f)+1e-5f);
  float nmi=-m*istd;
  const float4* Pr=(const float4*)&P[(long)c*128];
  float acc=0.f;
  #pragma unroll 8
  for(int j4=0;j4<32;j4++){
    const float4* q=(const float4*)&dv4[j4*20];
    float4 A4=q[0], C4=q[1], G4=q[2], B4=q[3], V4=q[4];
    float4 P4=Pr[j4];
    float t,hid;
    t=fmaf(d1,A4.x,fmaf(d2,C4.x,P4.x)); hid=fmaf(istd,t,fmaf(nmi,G4.x,B4.x)); acc=fmaf(fmaxf(hid,0.f),V4.x,acc);
    t=fmaf(d1,A4.y,fmaf(d2,C4.y,P4.y)); hid=fmaf(istd,t,fmaf(nmi,G4.y,B4.y)); acc=fmaf(fmaxf(hid,0.f),V4.y,acc);
    t=fmaf(d1,A4.z,fmaf(d2,C4.z,P4.z)); hid=fmaf(istd,t,fmaf(nmi,G4.z,B4.z)); acc=fmaf(fmaxf(hid,0.f),V4.z,acc);
    t=fmaf(d1,A4.w,fmaf(d2,C4.w,P4.w)); hid=fmaf(istd,t,fmaf(nmi,G4.w,B4.w)); acc=fmaf(fmaxf(hid,0.f),V4.w,acc);
  }
  we[e]=acc+dv4[640];
}

// ---------- degree passes (maintain we in CSR order) ----------
__global__ void k_deg0(const int* rp, const int* eid, const float* we_edge,
                       float* we_csr, float* dis){
  int n=blockIdx.x*blockDim.x+threadIdx.x;
  if(n>=N_) return;
  float s=1.f;
  int e0=rp[n], e1=rp[n+1];
  for(int p=e0;p<e1;p++){ float w=we_edge[eid[p]]; we_csr[p]=w; s+=w; }
  dis[n]=rsqrtf(fmaxf(s,1e-6f));
}
__global__ void k_degu(const int* rp, const int* csrc, const float* an, const float* bn,
                       const float* dv, float* we_csr, float* dis){
  int n=blockIdx.x*blockDim.x+threadIdx.x;
  if(n>=N_) return;
  float add_n = bn[n] + dv[897];
  float s=1.f;
  int e0=rp[n], e1=rp[n+1];
  for(int p=e0;p<e1;p++){
    float w=we_csr[p] + an[csrc[p]] + add_n;
    we_csr[p]=w; s+=w;
  }
  dis[n]=rsqrtf(fmaxf(s,1e-6f));
}
__global__ void k_deg_bb(const int* rp, float* dis){
  int n=blockIdx.x*blockDim.x+threadIdx.x;
  if(n>=N_) return;
  float s=1.f+(float)(rp[n+1]-rp[n]);
  dis[n]=rsqrtf(fmaxf(s,1e-6f));
}

// ---------- split-bf16 MFMA GEMM ----------
DEVI f32x4 MFMA(short8v a, short8v b, f32x4 c){
  return __builtin_amdgcn_mfma_f32_16x16x32_bf16(a,b,c,0,0,0);
}
DEVI void cvt8(float4 a0, float4 a1, short8v& hi, short8v& lo){
  float av[8]={a0.x,a0.y,a0.z,a0.w,a1.x,a1.y,a1.z,a1.w};
  union{short8v v; unsigned short u[8];} H,L;
  #pragma unroll
  for(int i=0;i<8;i++){
    unsigned short h=f2bf(av[i]);
    float r=av[i]-bf2f(h);
    H.u[i]=h; L.u[i]=f2bf(r);
  }
  hi=H.v; lo=L.v;
}

template<int KT>
__global__ __launch_bounds__(256,4) void k_mgemm(const float* A1, const float* A2,
    const unsigned short* Whi, const unsigned short* Wlo,
    const float* bias, float* C, int relu, int accum, int M){
  const int lane = threadIdx.x & 63;
  const int wid  = threadIdx.x >> 6;
  const int r0   = blockIdx.x*64 + wid*16;
  const int mrow = lane & 15;
  const int kg   = lane >> 4;
  long arow = (long)min(r0 + mrow, M-1);
  f32x4 acc[8];
  #pragma unroll
  for(int t=0;t<8;t++) acc[t]=(f32x4){0.f,0.f,0.f,0.f};

  #pragma unroll
  for(int kt=0; kt<KT; kt++){
    const float* A = (KT==8 && kt>=4) ? A2 : A1;
    int kb = (kt&3)*32 + kg*8;
    float4 a0 = *(const float4*)&A[arow*128 + kb];
    float4 a1 = *(const float4*)&A[arow*128 + kb + 4];
    short8v ah, al; cvt8(a0,a1,ah,al);
    #pragma unroll
    for(int nt=0;nt<8;nt++){
      long off = (((long)kt*8+nt)*64 + lane)*8;
      short8v wh = *(const short8v*)&Whi[off];
      short8v wl = *(const short8v*)&Wlo[off];
      acc[nt] = MFMA(ah, wh, acc[nt]);
      acc[nt] = MFMA(al, wh, acc[nt]);
      acc[nt] = MFMA(ah, wl, acc[nt]);
      acc[nt] = MFMA(al, wl, acc[nt]);
    }
  }

  #pragma unroll
  for(int nt=0;nt<8;nt++){
    int col = nt*16 + mrow;
    float bj = bias ? bias[col] : 0.f;
    #pragma unroll
    for(int r=0;r<4;r++){
      int row = r0 + kg*4 + r;
      if(row >= M) continue;
      long idx = (long)row*128 + col;
      float v = acc[nt][r] + bj;
      if(relu) v = fmaxf(v,0.f);
      if(accum) v += C[idx];
      C[idx] = v;
    }
  }
}

// fused dual GEMM: C1 = relu(A1@W1[0:128] + A2@W1[128:256] + b1); C2 = A1@W2
__global__ __launch_bounds__(256,4) void k_mgemm2(const float* A1, const float* A2,
    const unsigned short* W1hi, const unsigned short* W1lo,
    const unsigned short* W2hi, const unsigned short* W2lo,
    const float* b1, float* C1, float* C2, int M){
  const int lane = threadIdx.x & 63;
  const int wid  = threadIdx.x >> 6;
  const int r0   = blockIdx.x*64 + wid*16;
  const int mrow = lane & 15;
  const int kg   = lane >> 4;
  long arow = (long)min(r0 + mrow, M-1);
  f32x4 acc1[8], acc2[8];
  #pragma unroll
  for(int t=0;t<8;t++){ acc1[t]=(f32x4){0,0,0,0}; acc2[t]=(f32x4){0,0,0,0}; }

  #pragma unroll
  for(int kt=0; kt<8; kt++){
    const float* A = (kt>=4) ? A2 : A1;
    int kb = (kt&3)*32 + kg*8;
    float4 a0 = *(const float4*)&A[arow*128 + kb];
    float4 a1 = *(const float4*)&A[arow*128 + kb + 4];
    short8v ah, al; cvt8(a0,a1,ah,al);
    #pragma unroll
    for(int nt=0;nt<8;nt++){
      long off = (((long)kt*8+nt)*64 + lane)*8;
      short8v wh = *(const short8v*)&W1hi[off];
      short8v wl = *(const short8v*)&W1lo[off];
      acc1[nt] = MFMA(ah, wh, acc1[nt]);
      acc1[nt] = MFMA(al, wh, acc1[nt]);
      acc1[nt] = MFMA(ah, wl, acc1[nt]);
      acc1[nt] = MFMA(al, wl, acc1[nt]);
    }
    if(kt<4){
      #pragma unroll
      for(int nt=0;nt<8;nt++){
        long off = (((long)kt*8+nt)*64 + lane)*8;
        short8v wh = *(const short8v*)&W2hi[off];
        short8v wl = *(const short8v*)&W2lo[off];
        acc2[nt] = MFMA(ah, wh, acc2[nt]);
        acc2[nt] = MFMA(al, wh, acc2[nt]);
        acc2[nt] = MFMA(ah, wl, acc2[nt]);
        acc2[nt] = MFMA(al, wl, acc2[nt]);
      }
    }
  }

  #pragma unroll
  for(int nt=0;nt<8;nt++){
    int col = nt*16 + mrow;
    float bj = b1[col];
    #pragma unroll
    for(int r=0;r<4;r++){
      int row = r0 + kg*4 + r;
      if(row >= M) continue;
      long idx = (long)row*128 + col;
      C1[idx] = fmaxf(acc1[nt][r] + bj, 0.f);
      C2[idx] = acc2[nt][r];
    }
  }
}

// ---------- aggregation (one wave per node; optional fused an/bn dot) ----------
__global__ void k_agg_sc(const int* rp, const int* csrc, const float* wc,
                         const float* dis, const float* xw, const float* w,
                         float* hat_h, const float* dv, float* an, float* bn, int withdot){
  int wv=threadIdx.x>>6, lane=threadIdx.x&63;
  int n=blockIdx.x*4+wv;
  float disn=dis[n];
  float ax=0.f, ay=0.f;
  int e0=rp[n], e1=rp[n+1];
  int p=e0;
  for(; p+1<e1; p+=2){
    int s0=csrc[p], s1=csrc[p+1];
    float nw0=dis[s0]*wc[p]*disn;
    float nw1=dis[s1]*wc[p+1]*disn;
    float2 x0=*(const float2*)&xw[(long)s0*128+lane*2];
    float2 x1=*(const float2*)&xw[(long)s1*128+lane*2];
    ax+=nw0*x0.x+nw1*x1.x;
    ay+=nw0*x0.y+nw1*x1.y;
  }
  if(p<e1){
    int s0=csrc[p];
    float nw0=dis[s0]*wc[p]*disn;
    float2 x0=*(const float2*)&xw[(long)s0*128+lane*2];
    ax+=nw0*x0.x; ay+=nw0*x0.y;
  }
  float d2=disn*disn;
  float2 xs=*(const float2*)&xw[(long)n*128+lane*2];
  ax+=d2*xs.x+w[OW_GB+lane*2];
  ay+=d2*xs.y+w[OW_GB+lane*2+1];
  float2 h=*(float2*)&hat_h[(long)n*128+lane*2];
  h.x+=fmaxf(ax,0.f); h.y+=fmaxf(ay,0.f);
  *(float2*)&hat_h[(long)n*128+lane*2]=h;
  if(withdot){
    float a=h.x*dv[640+lane*2]+h.y*dv[641+lane*2];
    float b=h.x*dv[768+lane*2]+h.y*dv[769+lane*2];
    for(int m=1;m<64;m<<=1){ a+=__shfl_xor(a,m,64); b+=__shfl_xor(b,m,64); }
    if(lane==0){ an[n]=a; bn[n]=b; }
  }
}

__global__ void k_agg_bb(const int* rp, const int* csrc, const float* dis,
                         const float* xw, const float* w, float* h){
  int wv=threadIdx.x>>6, lane=threadIdx.x&63;
  int n=blockIdx.x*4+wv;
  float disn=dis[n];
  float ax=0.f, ay=0.f;
  int e0=rp[n], e1=rp[n+1];
  int p=e0;
  for(; p+1<e1; p+=2){
    int s0=csrc[p], s1=csrc[p+1];
    float nw0=dis[s0]*disn, nw1=dis[s1]*disn;
    float2 x0=*(const float2*)&xw[(long)s0*128+lane*2];
    float2 x1=*(const float2*)&xw[(long)s1*128+lane*2];
    ax+=nw0*x0.x+nw1*x1.x;
    ay+=nw0*x0.y+nw1*x1.y;
  }
  if(p<e1){
    int s0=csrc[p];
    float nw0=dis[s0]*disn;
    float2 x0=*(const float2*)&xw[(long)s0*128+lane*2];
    ax+=nw0*x0.x; ay+=nw0*x0.y;
  }
  float d2=disn*disn;
  float2 xs=*(const float2*)&xw[(long)n*128+lane*2];
  ax+=d2*xs.x+w[OW_BGB+lane*2];
  ay+=d2*xs.y+w[OW_BGB+lane*2+1];
  float2 hv=*(float2*)&h[(long)n*128+lane*2];
  hv.x+=fmaxf(ax,0.f); hv.y+=fmaxf(ay,0.f);
  *(float2*)&h[(long)n*128+lane*2]=hv;
}

__global__ void k_heads(const float* hat_h, const float* h, const float* w,
                        const void* old_chi, const void* old_phi, const void* old_psi,
                        const void* old_cb, const void* old_ca, const int* flag, void* out){
  int wv=threadIdx.x>>6, lane=threadIdx.x&63;
  int n=blockIdx.x*4+wv;
  int f32=*flag;
  float s0=fmaxf(hat_h[(long)n*128+lane],0.f), s1=fmaxf(hat_h[(long)n*128+64+lane],0.f);
  float b0=fmaxf(h[(long)n*128+lane],0.f),    b1=fmaxf(h[(long)n*128+64+lane],0.f);
  float r[8];
  r[0]=s0*w[OW_AW+lane]+s1*w[OW_AW+64+lane];
  r[1]=s0*w[OW_CW+lane*3+0]+s1*w[OW_CW+(64+lane)*3+0];
  r[2]=s0*w[OW_CW+lane*3+1]+s1*w[OW_CW+(64+lane)*3+1];
  r[3]=s0*w[OW_CW+lane*3+2]+s1*w[OW_CW+(64+lane)*3+2];
  r[4]=b0*w[OW_BAW+lane]+b1*w[OW_BAW+64+lane];
  r[5]=b0*w[OW_XW+lane*3+0]+b1*w[OW_XW+(64+lane)*3+0];
  r[6]=b0*w[OW_XW+lane*3+1]+b1*w[OW_XW+(64+lane)*3+1];
  r[7]=b0*w[OW_XW+lane*3+2]+b1*w[OW_XW+(64+lane)*3+2];
  for(int m=1;m<64;m<<=1){
    #pragma unroll
    for(int t=0;t<8;t++) r[t]+=__shfl_xor(r[t],m,64);
  }
  if(lane==0){
    float dchi=r[0]+w[OW_AB];
    for(int k=0;k<4;k++)
      stout(out,(long)k*N_+n, wrapf(ldin(old_chi,(long)k*N_+n,f32)+dchi), f32);
    float dphi=r[4]+w[OW_BAB];
    stout(out,(long)4*N_+n, wrapf(ldin(old_phi,n,f32)+dphi), f32);
    stout(out,(long)5*N_+n, wrapf(ldin(old_psi,n,f32)+dphi), f32);
    for(int t=0;t<3;t++){
      stout(out,(long)6*N_+(long)n*3+t, ldin(old_cb,(long)n*3+t,f32)+r[1+t]+w[OW_CB+t], f32);
      stout(out,(long)9*N_+(long)n*3+t, ldin(old_ca,(long)n*3+t,f32)+r[5+t]+w[OW_XB+t], f32);
    }
  }
}

// ---------- host ----------
extern "C" void kernel_launch(void* const* d_in, const int* in_sizes, int n_in,
                              void* d_out, int out_size, void* d_ws, size_t ws_size,
                              hipStream_t stream) {
  (void)in_sizes; (void)n_in; (void)out_size; (void)ws_size;

  char* p=(char*)d_ws;
  auto alloc=[&](size_t bytes)->void*{ void* r=(void*)p; p+=((bytes+255)&~(size_t)255); return r; };
  int*   flag   =(int*)  alloc(16);
  float* warena =(float*)alloc((size_t)OW_TOT*4);
  float* dv     =(float*)alloc(1024*4);
  float* dv4    =(float*)alloc(1024*4);
  float* P      =(float*)alloc((size_t)441*128*4);
  float* sp     =(float*)alloc(441*4);
  float* qp     =(float*)alloc(441*4);
  float* hat_h  =(float*)alloc((size_t)N_*128*4);
  float* hbuf   =(float*)alloc((size_t)N_*128*4);
  float* bufX   =(float*)alloc((size_t)N_*128*4);
  float* bufH   =(float*)alloc((size_t)N_*128*4);
  float* we     =(float*)alloc((size_t)ESC*4);
  float* we_csr =(float*)alloc((size_t)ESC*4);
  float* an     =(float*)alloc((size_t)N_*4);
  float* bn     =(float*)alloc((size_t)N_*4);
  float* dis    =(float*)alloc((size_t)N_*4);
  float* disb   =(float*)alloc((size_t)N_*4);
  int* cnt4     =(int*)  alloc((size_t)4*N_*4);   // c_sc | c_bb | cur_sc | cur_bb
  int* rp_sc    =(int*)  alloc((size_t)(N_+1)*4);
  int* rp_bb    =(int*)  alloc((size_t)(N_+1)*4);
  int* csr_src_sc=(int*) alloc((size_t)ESC*4);
  int* csr_eid_sc=(int*) alloc((size_t)ESC*4);
  int* csr_src_bb=(int*) alloc((size_t)EBB*4);
  int* part     =(int*)  alloc(256*4);
  unsigned short* wfg_hi =(unsigned short*)alloc(2048*8*2);
  unsigned short* wfg_lo =(unsigned short*)alloc(2048*8*2);
  unsigned short* wfbg_hi=(unsigned short*)alloc(2048*8*2);
  unsigned short* wfbg_lo=(unsigned short*)alloc(2048*8*2);
  unsigned short* wfi2_hi=(unsigned short*)alloc(2048*8*2);
  unsigned short* wfi2_lo=(unsigned short*)alloc(2048*8*2);
  unsigned short* wfi1_hi=(unsigned short*)alloc(4096*8*2);
  unsigned short* wfi1_lo=(unsigned short*)alloc(4096*8*2);

  int* c_sc=cnt4, *c_bb=cnt4+N_, *cur_sc=cnt4+2*N_, *cur_bb=cnt4+3*N_;

  const int* src_sc=(const int*)d_in[48];
  const int* dst_sc=src_sc+ESC;
  const int* src_bb=(const int*)d_in[49];
  const int* dst_bb=src_bb+EBB;

  k_detect<<<1,1,0,stream>>>(d_in[0], flag);

  CvtArgs ca;
  {
    int map[29]={14,15,16,17,18,19,20,21,22,23,24,25,30,31,32,33,34,35,36,37,
                 38,39,40,41,42,43,44,45,13};
    for(int i=0;i<29;i++) ca.src[i]=d_in[map[i]];
  }
  k_cvtw<<<(OW_TOT+255)/256,256,0,stream>>>(ca, flag, warena);

  k_wprep4<<<(10240+255)/256,256,0,stream>>>(warena, wfg_hi,wfg_lo, wfbg_hi,wfbg_lo,
                                             wfi2_hi,wfi2_lo, wfi1_hi,wfi1_lo);
  k_prevec<<<1,128,0,stream>>>(warena, d_in[26], d_in[27], d_in[28], d_in[29], flag, dv, dv4);
  k_preP<<<441,128,0,stream>>>(warena, P, sp, qp);

  k_feat<<<2*N_,128,0,stream>>>(d_in[0], d_in[1], d_in[2], d_in[3], d_in[4], d_in[5],
                                flag, warena, hat_h, hbuf);

  hipMemsetAsync(cnt4,0,(size_t)4*N_*4,stream);
  k_count2<<<(ESC+EBB+255)/256,256,0,stream>>>(dst_sc,dst_bb,c_sc,c_bb);
  k_scan1x2<<<2*SCB,1024,0,stream>>>(c_sc,c_bb,rp_sc,rp_bb,part);
  k_scan2x2<<<1,64,0,stream>>>(part);
  k_scan3x2<<<2*SCB,1024,0,stream>>>(rp_sc,rp_bb,part);
  k_fill2<<<(ESC+EBB+255)/256,256,0,stream>>>(src_sc,dst_sc,src_bb,dst_bb,rp_sc,rp_bb,
                                              cur_sc,cur_bb,csr_src_sc,csr_eid_sc,csr_src_bb);
  k_sortx<<<(2*N_+255)/256,256,0,stream>>>(rp_sc,csr_eid_sc,csr_src_sc,rp_bb,csr_src_bb);

  k_w0<<<(ESC+255)/256,256,0,stream>>>(d_in[6],d_in[7],(const int*)d_in[46],(const int*)d_in[47],
                                       flag,dv4,P,sp,qp,we);
  k_deg_bb<<<(N_+255)/256,256,0,stream>>>(rp_bb,disb);

  const int GB = (N_+63)/64;
  for(int l=0;l<3;l++){
    if(l==0) k_deg0<<<(N_+255)/256,256,0,stream>>>(rp_sc,csr_eid_sc,we,we_csr,dis);
    else     k_degu<<<(N_+255)/256,256,0,stream>>>(rp_sc,csr_src_sc,an,bn,dv,we_csr,dis);
    k_mgemm<4><<<GB,256,0,stream>>>(hat_h, nullptr, wfg_hi, wfg_lo, nullptr, bufX, 0, 0, N_);
    k_agg_sc<<<N_/4,256,0,stream>>>(rp_sc,csr_src_sc,we_csr,dis,bufX,warena,hat_h,dv,an,bn,(l<2)?1:0);
  }

  for(int l=0;l<2;l++){
    k_mgemm2<<<GB,256,0,stream>>>(hbuf, hat_h, wfi1_hi, wfi1_lo, wfbg_hi, wfbg_lo,
                                  warena+OW_IB1, bufH, bufX, N_);
    k_agg_bb<<<N_/4,256,0,stream>>>(rp_bb,csr_src_bb,disb,bufX,warena,hbuf);
    k_mgemm<4><<<GB,256,0,stream>>>(bufH, nullptr, wfi2_hi, wfi2_lo, warena+OW_IB2, hbuf, 0, 1, N_);
  }

  k_heads<<<N_/4,256,0,stream>>>(hat_h,hbuf,warena,
                                 d_in[8],d_in[9],d_in[10],d_in[11],d_in[12],flag,d_out);
}

// Round 6
// 779.218 us; speedup vs baseline: 1.5213x; 1.0537x over previous
//
#include <hip/hip_runtime.h>
#include <stdint.h>

#define DEVI __device__ __forceinline__

constexpr int N_   = 50000;
constexpr int ESC  = 600000;
constexpr int EBB  = 100000;
constexpr int NRES = 21;
constexpr int SCB  = (N_+1023)/1024;   // 49 scan blocks per array
constexpr float PI_F = 3.14159f;

typedef __attribute__((ext_vector_type(8))) short short8v;
typedef __attribute__((ext_vector_type(4))) float f32x4;

// ---------- dtype helpers (runtime f32-vs-bf16 dispatch) ----------
DEVI float bf2f(unsigned short u){ return __uint_as_float(((unsigned)u)<<16); }
DEVI unsigned short f2bf(float f){
  unsigned x = __float_as_uint(f);
  unsigned r = (x + 0x7FFFu + ((x>>16)&1u))>>16;
  return (unsigned short)r;
}
DEVI float ldin(const void* p, long i, int f32){
  return f32 ? ((const float*)p)[i] : bf2f(((const unsigned short*)p)[i]);
}
DEVI void stout(void* p, long i, float v, int f32){
  if(f32) ((float*)p)[i]=v; else ((unsigned short*)p)[i]=f2bf(v);
}
DEVI float wrapf(float a){
  float t = a + PI_F;
  const float TP = 2.f*PI_F;
  t -= floorf(t/TP)*TP;
  return t - PI_F;
}

// ---------- weight arena offsets (floats) ----------
constexpr int OW_SC_LN_G=0;
constexpr int OW_SC_LN_B=OW_SC_LN_G+19;
constexpr int OW_SC_W  = OW_SC_LN_B+19;
constexpr int OW_SC_B  = OW_SC_W+19*128;
constexpr int OW_BB_LN_G=OW_SC_B+128;
constexpr int OW_BB_LN_B=OW_BB_LN_G+38;
constexpr int OW_BB_W = OW_BB_LN_B+38;
constexpr int OW_BB_B = OW_BB_W+38*128;
constexpr int OW_E_LN_G=OW_BB_B+128;
constexpr int OW_E_LN_B=OW_E_LN_G+66;
constexpr int OW_EW1 = OW_E_LN_B+66;
constexpr int OW_EB1 = OW_EW1+66*128;
constexpr int OW_GW  = OW_EB1+128;
constexpr int OW_GB  = OW_GW+128*128;
constexpr int OW_BGW = OW_GB+128;
constexpr int OW_BGB = OW_BGW+128*128;
constexpr int OW_IW1 = OW_BGB+128;
constexpr int OW_IB1 = OW_IW1+256*128;
constexpr int OW_IW2 = OW_IB1+128;
constexpr int OW_IB2 = OW_IW2+128*128;
constexpr int OW_AW  = OW_IB2+128;
constexpr int OW_AB  = OW_AW+128;
constexpr int OW_BAW = OW_AB+1;
constexpr int OW_BAB = OW_BAW+128;
constexpr int OW_CW  = OW_BAB+1;
constexpr int OW_CB  = OW_CW+128*3;
constexpr int OW_XW  = OW_CB+3;
constexpr int OW_XB  = OW_XW+128*3;
constexpr int OW_RES = OW_XB+3;
constexpr int OW_TOT = OW_RES+21*32;

// dv: usm at 640, udm at 768, dv[896]=eb2m, dv[897]=eubm
// dv4: per j4 (0..31): 20 floats = {A4,C4,G4,B4,V4}; dv4[640]=eb2m

// ---------- kernels ----------
__global__ void k_detect(const void* vcom, int* flag){
  const unsigned short* u = (const unsigned short*)vcom;
  int insane=0;
  for(int i=0;i<64;i+=2){
    float f = bf2f(u[i]);
    float a = fabsf(f);
    if(!(a<1e5f) || (a!=0.0f && a<1e-5f)) insane++;
  }
  *flag = (insane>=8)?1:0;
}

struct CvtArgs { const void* src[29]; };

__global__ void k_cvtw(CvtArgs a, const int* flag, float* w){
  static constexpr int offs[30] = {
    OW_SC_LN_G,OW_SC_LN_B,OW_SC_W,OW_SC_B,OW_BB_LN_G,OW_BB_LN_B,OW_BB_W,OW_BB_B,
    OW_E_LN_G,OW_E_LN_B,OW_EW1,OW_EB1,OW_GW,OW_GB,OW_BGW,OW_BGB,OW_IW1,OW_IB1,
    OW_IW2,OW_IB2,OW_AW,OW_AB,OW_BAW,OW_BAB,OW_CW,OW_CB,OW_XW,OW_XB,OW_RES,OW_TOT};
  int f32=*flag;
  for(int t=blockIdx.x*blockDim.x+threadIdx.x; t<OW_TOT; t+=gridDim.x*blockDim.x){
    int s=0;
    while(t>=offs[s+1]) s++;
    w[t]=ldin(a.src[s], t-offs[s], f32);
  }
}

// W[K x 128] -> MFMA fragment order (zero-padded past Kreal), split hi/lo bf16.
// slot (kt,nt,lane,i): k = kt*32 + (lane>>4)*8 + i, n = nt*16 + (lane&15)
DEVI void wprep_pad(const float* W, int Kreal, unsigned short* hi, unsigned short* lo, int idx){
  int lane=idx&63, nt=(idx>>6)&7, kt=idx>>9;
  int n = nt*16 + (lane&15);
  int kbase = kt*32 + (lane>>4)*8;
  #pragma unroll
  for(int i=0;i<8;i++){
    int k=kbase+i;
    float v = (k<Kreal) ? W[(long)k*128 + n] : 0.f;
    unsigned short h = f2bf(v);
    float r = v - bf2f(h);
    hi[(long)idx*8+i]=h;
    lo[(long)idx*8+i]=f2bf(r);
  }
}
__global__ void k_wprep4(const float* w,
    unsigned short* g_hi, unsigned short* g_lo,
    unsigned short* bg_hi, unsigned short* bg_lo,
    unsigned short* i2_hi, unsigned short* i2_lo,
    unsigned short* i1_hi, unsigned short* i1_lo,
    unsigned short* sc_hi, unsigned short* sc_lo,
    unsigned short* bb_hi, unsigned short* bb_lo){
  int idx = blockIdx.x*blockDim.x + threadIdx.x;
  if(idx<2048)       wprep_pad(w+OW_GW,  128, g_hi,  g_lo,  idx);
  else if(idx<4096)  wprep_pad(w+OW_BGW, 128, bg_hi, bg_lo, idx-2048);
  else if(idx<6144)  wprep_pad(w+OW_IW2, 128, i2_hi, i2_lo, idx-4096);
  else if(idx<10240) wprep_pad(w+OW_IW1, 256, i1_hi, i1_lo, idx-6144);
  else if(idx<10752) wprep_pad(w+OW_SC_W, 19, sc_hi, sc_lo, idx-10240);
  else if(idx<11776) wprep_pad(w+OW_BB_W, 38, bb_hi, bb_lo, idx-10752);
}

__global__ void k_prevec(const float* w, const void* eW2, const void* eb2,
                         const void* euW, const void* eub, const int* flag,
                         float* dv, float* dv4){
  int j=threadIdx.x; int f32=*flag;
  const float* g=w+OW_E_LN_G; const float* b=w+OW_E_LN_B; const float* W1=w+OW_EW1;
  float A=g[0]*W1[j], C=g[1]*W1[128+j];
  float G=0,B=0;
  for(int i=0;i<66;i++){ float wij=W1[i*128+j]; G+=g[i]*wij; B+=b[i]*wij; }
  B += w[OW_EB1+j];
  float v2=0; for(int k=0;k<128;k++) v2+=ldin(eW2,(long)j*128+k,f32);
  float us=0,ud=0;
  for(int k=0;k<128;k++){ us+=ldin(euW,(long)j*128+k,f32); ud+=ldin(euW,(long)(128+j)*128+k,f32); }
  float v2m=v2*(1.f/128.f);
  dv[640+j]=us*(1.f/128.f); dv[768+j]=ud*(1.f/128.f);
  int j4=j>>2, r=j&3;
  dv4[j4*20+0+r]=A; dv4[j4*20+4+r]=C; dv4[j4*20+8+r]=G; dv4[j4*20+12+r]=B; dv4[j4*20+16+r]=v2m;
  if(j==0){
    float s=0,t=0;
    for(int k=0;k<128;k++){ s+=ldin(eb2,k,f32); t+=ldin(eub,k,f32); }
    dv[896]=s*(1.f/128.f); dv[897]=t*(1.f/128.f);
    dv4[640]=s*(1.f/128.f);
  }
}

__global__ void k_preP(const float* w, float* P, float* sp, float* qp){
  __shared__ float pv[64];
  int c=blockIdx.x, ri=c/NRES, rj=c%NRES, j=threadIdx.x;
  const float* res=w+OW_RES;
  if(j<32) pv[j]=res[ri*32+j];
  else if(j<64) pv[j]=res[rj*32+(j-32)];
  __syncthreads();
  const float* g=w+OW_E_LN_G; const float* W1=w+OW_EW1;
  float s=0;
  for(int i=0;i<64;i++) s += pv[i]*g[2+i]*W1[(2+i)*128+j];
  P[c*128+j]=s;
  if(j==0){ float a=0,q=0; for(int i=0;i<64;i++){a+=pv[i]; q+=pv[i]*pv[i];} sp[c]=a; qp[c]=q; }
}

// LN pass: one wave per node (sc: waves [0,N), bb: waves [N,2N)),
// writes normalized features to padded xn buffers for the MFMA featurizer GEMM.
__global__ void k_ln(const void* vcom, const void* sbfchi,
                     const void* xca, const void* vcb, const void* sphi, const void* spsi,
                     const int* flag, const float* w, float* xn_sc, float* xn_bb){
  int wv=threadIdx.x>>6, lane=threadIdx.x&63;
  long gw=(long)blockIdx.x*4+wv;
  int f32=*flag;
  if(gw<N_){
    int n=(int)gw;
    float x=0.f;
    if(lane<3) x=ldin(vcom,(long)n*3+lane,f32);
    else if(lane<19) x=ldin(sbfchi,(long)n*16+(lane-3),f32);
    float s=x, q=x*x;
    for(int m=1;m<64;m<<=1){ s+=__shfl_xor(s,m,64); q+=__shfl_xor(q,m,64); }
    float mean=s*(1.f/19.f);
    float var=fmaxf(q*(1.f/19.f)-mean*mean,0.f);
    float istd=rsqrtf(var+1e-5f);
    if(lane<32){
      float xn=(lane<19)? (x-mean)*istd*w[OW_SC_LN_G+lane]+w[OW_SC_LN_B+lane] : 0.f;
      xn_sc[(long)n*32+lane]=xn;
    }
  } else if(gw<2L*N_){
    int n=(int)(gw-N_);
    float x=0.f;
    if(lane<3) x=ldin(xca,(long)n*3+lane,f32);
    else if(lane<6) x=ldin(vcb,(long)n*3+(lane-3),f32);
    else if(lane<22) x=ldin(sphi,(long)n*16+(lane-6),f32);
    else if(lane<38) x=ldin(spsi,(long)n*16+(lane-22),f32);
    float s=x, q=x*x;
    for(int m=1;m<64;m<<=1){ s+=__shfl_xor(s,m,64); q+=__shfl_xor(q,m,64); }
    float mean=s*(1.f/38.f);
    float var=fmaxf(q*(1.f/38.f)-mean*mean,0.f);
    float istd=rsqrtf(var+1e-5f);
    float xn=(lane<38)? (x-mean)*istd*w[OW_BB_LN_G+lane]+w[OW_BB_LN_B+lane] : 0.f;
    xn_bb[(long)n*64+lane]=xn;
  }
}

// ---------- CSR build (merged sc+bb) ----------
__global__ void k_count2(const int* dst_sc, const int* dst_bb, int* c_sc, int* c_bb){
  int i=blockIdx.x*blockDim.x+threadIdx.x;
  if(i<ESC) atomicAdd(&c_sc[dst_sc[i]],1);
  else if(i<ESC+EBB) atomicAdd(&c_bb[dst_bb[i-ESC]],1);
}
__global__ void k_scan1x2(const int* c_sc, const int* c_bb, int* rp_sc, int* rp_bb, int* part){
  __shared__ int s[1024];
  int half = (blockIdx.x>=SCB);
  int b = half? blockIdx.x-SCB : blockIdx.x;
  const int* in = half? c_bb : c_sc;
  int* excl = half? rp_bb : rp_sc;
  int* pt = part + half*64;
  int i=b*1024+threadIdx.x;
  int v=(i<N_)?in[i]:0;
  s[threadIdx.x]=v; __syncthreads();
  for(int off=1; off<1024; off<<=1){
    int t=(threadIdx.x>=off)?s[threadIdx.x-off]:0;
    __syncthreads();
    s[threadIdx.x]+=t; __syncthreads();
  }
  if(i<N_) excl[i]=s[threadIdx.x]-v;
  if(threadIdx.x==1023) pt[b]=s[1023];
}
__global__ void k_scan2x2(int* part){
  int t=threadIdx.x;
  if(t<2){
    int* pp=part+t*64;
    int run=0;
    for(int b=0;b<SCB;b++){ int v=pp[b]; pp[b]=run; run+=v; }
  }
}
__global__ void k_scan3x2(int* rp_sc, int* rp_bb, const int* part){
  int half = (blockIdx.x>=SCB);
  int b = half? blockIdx.x-SCB : blockIdx.x;
  int* rp = half? rp_bb : rp_sc;
  const int* pt = part + half*64;
  int E = half? EBB : ESC;
  int i=b*1024+threadIdx.x;
  if(i<N_) rp[i]+=pt[b];
  if(i==N_) rp[N_]=E;
}
__global__ void k_fill2(const int* src_sc, const int* dst_sc, const int* src_bb, const int* dst_bb,
                        const int* rp_sc, const int* rp_bb, int* cur_sc, int* cur_bb,
                        int* csr_src_sc, int* csr_eid_sc, int* csr_src_bb){
  int i=blockIdx.x*blockDim.x+threadIdx.x;
  if(i<ESC){
    int d=dst_sc[i];
    int p=rp_sc[d]+atomicAdd(&cur_sc[d],1);
    csr_src_sc[p]=src_sc[i];
    csr_eid_sc[p]=i;
  } else if(i<ESC+EBB){
    int e=i-ESC;
    int d=dst_bb[e];
    int p=rp_bb[d]+atomicAdd(&cur_bb[d],1);
    csr_src_bb[p]=src_bb[e];
  }
}
// deterministic order: per-node insertion sort (sc: by unique eid; bb: by src value)
__global__ void k_sortx(const int* rp_sc, int* key_sc, int* val_sc,
                        const int* rp_bb, int* key_bb){
  int v=blockIdx.x*blockDim.x+threadIdx.x;
  if(v<N_){
    int e0=rp_sc[v], e1=rp_sc[v+1];
    for(int i=e0+1;i<e1;i++){
      int kk=key_sc[i], vv=val_sc[i];
      int j=i-1;
      while(j>=e0 && key_sc[j]>kk){ key_sc[j+1]=key_sc[j]; val_sc[j+1]=val_sc[j]; j--; }
      key_sc[j+1]=kk; val_sc[j+1]=vv;
    }
  } else if(v<2*N_){
    int n=v-N_;
    int e0=rp_bb[n], e1=rp_bb[n+1];
    for(int i=e0+1;i<e1;i++){
      int kk=key_bb[i];
      int j=i-1;
      while(j>=e0 && key_bb[j]>kk){ key_bb[j+1]=key_bb[j]; j--; }
      key_bb[j+1]=kk;
    }
  }
}

// ---------- edge MLP: one edge per lane, float4 over 128 hidden dims ----------
__global__ void k_w0(const void* dsc, const void* dmin, const int* ri_, const int* rj_,
                     const int* flag, const float* dv4, const float* P,
                     const float* sp, const float* qp, float* we){
  int e=blockIdx.x*blockDim.x+threadIdx.x;
  if(e>=ESC) return;
  int f32=*flag;
  float d1=ldin(dsc,e,f32), d2=ldin(dmin,e,f32);
  int c=ri_[e]*NRES+rj_[e];
  float m=(d1+d2+sp[c])*(1.f/66.f);
  float ms=(d1*d1+d2*d2+qp[c])*(1.f/66.f);
  float istd=rsqrtf(fmaxf(ms-m*m,0.f)+1e-5f);
  float nmi=-m*istd;
  const float4* Pr=(const float4*)&P[(long)c*128];
  float acc=0.f;
  #pragma unroll 8
  for(int j4=0;j4<32;j4++){
    const float4* q=(const float4*)&dv4[j4*20];
    float4 A4=q[0], C4=q[1], G4=q[2], B4=q[3], V4=q[4];
    float4 P4=Pr[j4];
    float t,hid;
    t=fmaf(d1,A4.x,fmaf(d2,C4.x,P4.x)); hid=fmaf(istd,t,fmaf(nmi,G4.x,B4.x)); acc=fmaf(fmaxf(hid,0.f),V4.x,acc);
    t=fmaf(d1,A4.y,fmaf(d2,C4.y,P4.y)); hid=fmaf(istd,t,fmaf(nmi,G4.y,B4.y)); acc=fmaf(fmaxf(hid,0.f),V4.y,acc);
    t=fmaf(d1,A4.z,fmaf(d2,C4.z,P4.z)); hid=fmaf(istd,t,fmaf(nmi,G4.z,B4.z)); acc=fmaf(fmaxf(hid,0.f),V4.z,acc);
    t=fmaf(d1,A4.w,fmaf(d2,C4.w,P4.w)); hid=fmaf(istd,t,fmaf(nmi,G4.w,B4.w)); acc=fmaf(fmaxf(hid,0.f),V4.w,acc);
  }
  we[e]=acc+dv4[640];
}

// ---------- degree passes (maintain we in CSR order) ----------
__global__ void k_deg0(const int* rp, const int* eid, const float* we_edge,
                       float* we_csr, float* dis){
  int n=blockIdx.x*blockDim.x+threadIdx.x;
  if(n>=N_) return;
  float s=1.f;
  int e0=rp[n], e1=rp[n+1];
  for(int p=e0;p<e1;p++){ float w=we_edge[eid[p]]; we_csr[p]=w; s+=w; }
  dis[n]=rsqrtf(fmaxf(s,1e-6f));
}
__global__ void k_degu(const int* rp, const int* csrc, const float* an, const float* bn,
                       const float* dv, float* we_csr, float* dis){
  int n=blockIdx.x*blockDim.x+threadIdx.x;
  if(n>=N_) return;
  float add_n = bn[n] + dv[897];
  float s=1.f;
  int e0=rp[n], e1=rp[n+1];
  for(int p=e0;p<e1;p++){
    float w=we_csr[p] + an[csrc[p]] + add_n;
    we_csr[p]=w; s+=w;
  }
  dis[n]=rsqrtf(fmaxf(s,1e-6f));
}
__global__ void k_deg_bb(const int* rp, float* dis){
  int n=blockIdx.x*blockDim.x+threadIdx.x;
  if(n>=N_) return;
  float s=1.f+(float)(rp[n+1]-rp[n]);
  dis[n]=rsqrtf(fmaxf(s,1e-6f));
}

// ---------- split-bf16 MFMA GEMM ----------
DEVI f32x4 MFMA(short8v a, short8v b, f32x4 c){
  return __builtin_amdgcn_mfma_f32_16x16x32_bf16(a,b,c,0,0,0);
}
DEVI void cvt8(float4 a0, float4 a1, short8v& hi, short8v& lo){
  float av[8]={a0.x,a0.y,a0.z,a0.w,a1.x,a1.y,a1.z,a1.w};
  union{short8v v; unsigned short u[8];} H,L;
  #pragma unroll
  for(int i=0;i<8;i++){
    unsigned short h=f2bf(av[i]);
    float r=av[i]-bf2f(h);
    H.u[i]=h; L.u[i]=f2bf(r);
  }
  hi=H.v; lo=L.v;
}

// C[M,128] = (relu?)(A1@W + bias) (+=C if accum); A row stride LDA; K = KT*32.
// For KT==8: A = [A1 | A2] (two 128-wide halves).
template<int KT, int LDA>
__global__ __launch_bounds__(256,4) void k_mgemm(const float* A1, const float* A2,
    const unsigned short* Whi, const unsigned short* Wlo,
    const float* bias, float* C, int relu, int accum, int M){
  const int lane = threadIdx.x & 63;
  const int wid  = threadIdx.x >> 6;
  const int r0   = blockIdx.x*64 + wid*16;
  const int mrow = lane & 15;
  const int kg   = lane >> 4;
  long arow = (long)min(r0 + mrow, M-1);
  f32x4 acc[8];
  #pragma unroll
  for(int t=0;t<8;t++) acc[t]=(f32x4){0.f,0.f,0.f,0.f};

  #pragma unroll
  for(int kt=0; kt<KT; kt++){
    const float* A = (KT==8 && kt>=4) ? A2 : A1;
    int kb = (kt&3)*32 + kg*8;
    float4 a0 = *(const float4*)&A[arow*LDA + kb];
    float4 a1 = *(const float4*)&A[arow*LDA + kb + 4];
    short8v ah, al; cvt8(a0,a1,ah,al);
    #pragma unroll
    for(int nt=0;nt<8;nt++){
      long off = (((long)kt*8+nt)*64 + lane)*8;
      short8v wh = *(const short8v*)&Whi[off];
      short8v wl = *(const short8v*)&Wlo[off];
      acc[nt] = MFMA(ah, wh, acc[nt]);
      acc[nt] = MFMA(al, wh, acc[nt]);
      acc[nt] = MFMA(ah, wl, acc[nt]);
      acc[nt] = MFMA(al, wl, acc[nt]);
    }
  }

  #pragma unroll
  for(int nt=0;nt<8;nt++){
    int col = nt*16 + mrow;
    float bj = bias ? bias[col] : 0.f;
    #pragma unroll
    for(int r=0;r<4;r++){
      int row = r0 + kg*4 + r;
      if(row >= M) continue;
      long idx = (long)row*128 + col;
      float v = acc[nt][r] + bj;
      if(relu) v = fmaxf(v,0.f);
      if(accum) v += C[idx];
      C[idx] = v;
    }
  }
}

// fused dual GEMM: C1 = relu(A1@W1[0:128] + A2@W1[128:256] + b1); C2 = A1@W2
__global__ __launch_bounds__(256,4) void k_mgemm2(const float* A1, const float* A2,
    const unsigned short* W1hi, const unsigned short* W1lo,
    const unsigned short* W2hi, const unsigned short* W2lo,
    const float* b1, float* C1, float* C2, int M){
  const int lane = threadIdx.x & 63;
  const int wid  = threadIdx.x >> 6;
  const int r0   = blockIdx.x*64 + wid*16;
  const int mrow = lane & 15;
  const int kg   = lane >> 4;
  long arow = (long)min(r0 + mrow, M-1);
  f32x4 acc1[8], acc2[8];
  #pragma unroll
  for(int t=0;t<8;t++){ acc1[t]=(f32x4){0,0,0,0}; acc2[t]=(f32x4){0,0,0,0}; }

  #pragma unroll
  for(int kt=0; kt<8; kt++){
    const float* A = (kt>=4) ? A2 : A1;
    int kb = (kt&3)*32 + kg*8;
    float4 a0 = *(const float4*)&A[arow*128 + kb];
    float4 a1 = *(const float4*)&A[arow*128 + kb + 4];
    short8v ah, al; cvt8(a0,a1,ah,al);
    #pragma unroll
    for(int nt=0;nt<8;nt++){
      long off = (((long)kt*8+nt)*64 + lane)*8;
      short8v wh = *(const short8v*)&W1hi[off];
      short8v wl = *(const short8v*)&W1lo[off];
      acc1[nt] = MFMA(ah, wh, acc1[nt]);
      acc1[nt] = MFMA(al, wh, acc1[nt]);
      acc1[nt] = MFMA(ah, wl, acc1[nt]);
      acc1[nt] = MFMA(al, wl, acc1[nt]);
    }
    if(kt<4){
      #pragma unroll
      for(int nt=0;nt<8;nt++){
        long off = (((long)kt*8+nt)*64 + lane)*8;
        short8v wh = *(const short8v*)&W2hi[off];
        short8v wl = *(const short8v*)&W2lo[off];
        acc2[nt] = MFMA(ah, wh, acc2[nt]);
        acc2[nt] = MFMA(al, wh, acc2[nt]);
        acc2[nt] = MFMA(ah, wl, acc2[nt]);
        acc2[nt] = MFMA(al, wl, acc2[nt]);
      }
    }
  }

  #pragma unroll
  for(int nt=0;nt<8;nt++){
    int col = nt*16 + mrow;
    float bj = b1[col];
    #pragma unroll
    for(int r=0;r<4;r++){
      int row = r0 + kg*4 + r;
      if(row >= M) continue;
      long idx = (long)row*128 + col;
      C1[idx] = fmaxf(acc1[nt][r] + bj, 0.f);
      C2[idx] = acc2[nt][r];
    }
  }
}

// ---------- aggregation: wave per node, 2 edges in flight via 32-lane halves ----------
__global__ void k_agg_sc(const int* rp, const int* csrc, const float* wc,
                         const float* dis, const float* xw, const float* w,
                         float* hat_h, const float* dv, float* an, float* bn, int withdot){
  int wv=threadIdx.x>>6, lane=threadIdx.x&63;
  int n=blockIdx.x*4+wv;
  int half=lane>>5, l4=(lane&31)*4;
  float disn=dis[n];
  float4 acc={0,0,0,0};
  int e0=rp[n], e1=rp[n+1];
  int p=e0+half;
  for(; p+2<e1; p+=4){
    int s0=csrc[p], s1=csrc[p+2];
    float nw0=dis[s0]*wc[p]*disn;
    float nw1=dis[s1]*wc[p+2]*disn;
    float4 x0=*(const float4*)&xw[(long)s0*128+l4];
    float4 x1=*(const float4*)&xw[(long)s1*128+l4];
    acc.x+=nw0*x0.x+nw1*x1.x; acc.y+=nw0*x0.y+nw1*x1.y;
    acc.z+=nw0*x0.z+nw1*x1.z; acc.w+=nw0*x0.w+nw1*x1.w;
  }
  if(p<e1){
    int s0=csrc[p];
    float nw0=dis[s0]*wc[p]*disn;
    float4 x0=*(const float4*)&xw[(long)s0*128+l4];
    acc.x+=nw0*x0.x; acc.y+=nw0*x0.y; acc.z+=nw0*x0.z; acc.w+=nw0*x0.w;
  }
  acc.x+=__shfl_xor(acc.x,32,64); acc.y+=__shfl_xor(acc.y,32,64);
  acc.z+=__shfl_xor(acc.z,32,64); acc.w+=__shfl_xor(acc.w,32,64);
  float d2=disn*disn;
  float4 xs=*(const float4*)&xw[(long)n*128+l4];
  float4 gb=*(const float4*)&w[OW_GB+l4];
  float4 ho=*(const float4*)&hat_h[(long)n*128+l4];
  float4 h;
  h.x=ho.x+fmaxf(acc.x+d2*xs.x+gb.x,0.f);
  h.y=ho.y+fmaxf(acc.y+d2*xs.y+gb.y,0.f);
  h.z=ho.z+fmaxf(acc.z+d2*xs.z+gb.z,0.f);
  h.w=ho.w+fmaxf(acc.w+d2*xs.w+gb.w,0.f);
  if(half==0) *(float4*)&hat_h[(long)n*128+l4]=h;
  if(withdot){
    float4 us=*(const float4*)&dv[640+l4];
    float4 ud=*(const float4*)&dv[768+l4];
    float a = (half==0)? h.x*us.x+h.y*us.y+h.z*us.z+h.w*us.w : 0.f;
    float b = (half==0)? h.x*ud.x+h.y*ud.y+h.z*ud.z+h.w*ud.w : 0.f;
    for(int m=1;m<64;m<<=1){ a+=__shfl_xor(a,m,64); b+=__shfl_xor(b,m,64); }
    if(lane==0){ an[n]=a; bn[n]=b; }
  }
}

__global__ void k_agg_bb(const int* rp, const int* csrc, const float* dis,
                         const float* xw, const float* w, float* h){
  int wv=threadIdx.x>>6, lane=threadIdx.x&63;
  int n=blockIdx.x*4+wv;
  int half=lane>>5, l4=(lane&31)*4;
  float disn=dis[n];
  float4 acc={0,0,0,0};
  int e0=rp[n], e1=rp[n+1];
  int p=e0+half;
  for(; p+2<e1; p+=4){
    int s0=csrc[p], s1=csrc[p+2];
    float nw0=dis[s0]*disn, nw1=dis[s1]*disn;
    float4 x0=*(const float4*)&xw[(long)s0*128+l4];
    float4 x1=*(const float4*)&xw[(long)s1*128+l4];
    acc.x+=nw0*x0.x+nw1*x1.x; acc.y+=nw0*x0.y+nw1*x1.y;
    acc.z+=nw0*x0.z+nw1*x1.z; acc.w+=nw0*x0.w+nw1*x1.w;
  }
  if(p<e1){
    int s0=csrc[p];
    float nw0=dis[s0]*disn;
    float4 x0=*(const float4*)&xw[(long)s0*128+l4];
    acc.x+=nw0*x0.x; acc.y+=nw0*x0.y; acc.z+=nw0*x0.z; acc.w+=nw0*x0.w;
  }
  acc.x+=__shfl_xor(acc.x,32,64); acc.y+=__shfl_xor(acc.y,32,64);
  acc.z+=__shfl_xor(acc.z,32,64); acc.w+=__shfl_xor(acc.w,32,64);
  if(half==0){
    float d2=disn*disn;
    float4 xs=*(const float4*)&xw[(long)n*128+l4];
    float4 gb=*(const float4*)&w[OW_BGB+l4];
    float4 hv=*(float4*)&h[(long)n*128+l4];
    hv.x+=fmaxf(acc.x+d2*xs.x+gb.x,0.f);
    hv.y+=fmaxf(acc.y+d2*xs.y+gb.y,0.f);
    hv.z+=fmaxf(acc.z+d2*xs.z+gb.z,0.f);
    hv.w+=fmaxf(acc.w+d2*xs.w+gb.w,0.f);
    *(float4*)&h[(long)n*128+l4]=hv;
  }
}

__global__ void k_heads(const float* hat_h, const float* h, const float* w,
                        const void* old_chi, const void* old_phi, const void* old_psi,
                        const void* old_cb, const void* old_ca, const int* flag, void* out){
  int wv=threadIdx.x>>6, lane=threadIdx.x&63;
  int n=blockIdx.x*4+wv;
  int f32=*flag;
  float s0=fmaxf(hat_h[(long)n*128+lane],0.f), s1=fmaxf(hat_h[(long)n*128+64+lane],0.f);
  float b0=fmaxf(h[(long)n*128+lane],0.f),    b1=fmaxf(h[(long)n*128+64+lane],0.f);
  float r[8];
  r[0]=s0*w[OW_AW+lane]+s1*w[OW_AW+64+lane];
  r[1]=s0*w[OW_CW+lane*3+0]+s1*w[OW_CW+(64+lane)*3+0];
  r[2]=s0*w[OW_CW+lane*3+1]+s1*w[OW_CW+(64+lane)*3+1];
  r[3]=s0*w[OW_CW+lane*3+2]+s1*w[OW_CW+(64+lane)*3+2];
  r[4]=b0*w[OW_BAW+lane]+b1*w[OW_BAW+64+lane];
  r[5]=b0*w[OW_XW+lane*3+0]+b1*w[OW_XW+(64+lane)*3+0];
  r[6]=b0*w[OW_XW+lane*3+1]+b1*w[OW_XW+(64+lane)*3+1];
  r[7]=b0*w[OW_XW+lane*3+2]+b1*w[OW_XW+(64+lane)*3+2];
  for(int m=1;m<64;m<<=1){
    #pragma unroll
    for(int t=0;t<8;t++) r[t]+=__shfl_xor(r[t],m,64);
  }
  if(lane==0){
    float dchi=r[0]+w[OW_AB];
    for(int k=0;k<4;k++)
      stout(out,(long)k*N_+n, wrapf(ldin(old_chi,(long)k*N_+n,f32)+dchi), f32);
    float dphi=r[4]+w[OW_BAB];
    stout(out,(long)4*N_+n, wrapf(ldin(old_phi,n,f32)+dphi), f32);
    stout(out,(long)5*N_+n, wrapf(ldin(old_psi,n,f32)+dphi), f32);
    for(int t=0;t<3;t++){
      stout(out,(long)6*N_+(long)n*3+t, ldin(old_cb,(long)n*3+t,f32)+r[1+t]+w[OW_CB+t], f32);
      stout(out,(long)9*N_+(long)n*3+t, ldin(old_ca,(long)n*3+t,f32)+r[5+t]+w[OW_XB+t], f32);
    }
  }
}

// ---------- host ----------
extern "C" void kernel_launch(void* const* d_in, const int* in_sizes, int n_in,
                              void* d_out, int out_size, void* d_ws, size_t ws_size,
                              hipStream_t stream) {
  (void)in_sizes; (void)n_in; (void)out_size; (void)ws_size;

  char* p=(char*)d_ws;
  auto alloc=[&](size_t bytes)->void*{ void* r=(void*)p; p+=((bytes+255)&~(size_t)255); return r; };
  int*   flag   =(int*)  alloc(16);
  float* warena =(float*)alloc((size_t)OW_TOT*4);
  float* dv     =(float*)alloc(1024*4);
  float* dv4    =(float*)alloc(1024*4);
  float* P      =(float*)alloc((size_t)441*128*4);
  float* sp     =(float*)alloc(441*4);
  float* qp     =(float*)alloc(441*4);
  float* hat_h  =(float*)alloc((size_t)N_*128*4);
  float* hbuf   =(float*)alloc((size_t)N_*128*4);
  float* bufX   =(float*)alloc((size_t)N_*128*4);
  float* bufH   =(float*)alloc((size_t)N_*128*4);
  float* xn_sc  =(float*)alloc((size_t)N_*32*4);
  float* xn_bb  =(float*)alloc((size_t)N_*64*4);
  float* we     =(float*)alloc((size_t)ESC*4);
  float* we_csr =(float*)alloc((size_t)ESC*4);
  float* an     =(float*)alloc((size_t)N_*4);
  float* bn     =(float*)alloc((size_t)N_*4);
  float* dis    =(float*)alloc((size_t)N_*4);
  float* disb   =(float*)alloc((size_t)N_*4);
  int* cnt4     =(int*)  alloc((size_t)4*N_*4);   // c_sc | c_bb | cur_sc | cur_bb
  int* rp_sc    =(int*)  alloc((size_t)(N_+1)*4);
  int* rp_bb    =(int*)  alloc((size_t)(N_+1)*4);
  int* csr_src_sc=(int*) alloc((size_t)ESC*4);
  int* csr_eid_sc=(int*) alloc((size_t)ESC*4);
  int* csr_src_bb=(int*) alloc((size_t)EBB*4);
  int* part     =(int*)  alloc(256*4);
  unsigned short* wfg_hi =(unsigned short*)alloc(2048*8*2);
  unsigned short* wfg_lo =(unsigned short*)alloc(2048*8*2);
  unsigned short* wfbg_hi=(unsigned short*)alloc(2048*8*2);
  unsigned short* wfbg_lo=(unsigned short*)alloc(2048*8*2);
  unsigned short* wfi2_hi=(unsigned short*)alloc(2048*8*2);
  unsigned short* wfi2_lo=(unsigned short*)alloc(2048*8*2);
  unsigned short* wfi1_hi=(unsigned short*)alloc(4096*8*2);
  unsigned short* wfi1_lo=(unsigned short*)alloc(4096*8*2);
  unsigned short* wfsc_hi=(unsigned short*)alloc(512*8*2);
  unsigned short* wfsc_lo=(unsigned short*)alloc(512*8*2);
  unsigned short* wfbb_hi=(unsigned short*)alloc(1024*8*2);
  unsigned short* wfbb_lo=(unsigned short*)alloc(1024*8*2);

  int* c_sc=cnt4, *c_bb=cnt4+N_, *cur_sc=cnt4+2*N_, *cur_bb=cnt4+3*N_;

  const int* src_sc=(const int*)d_in[48];
  const int* dst_sc=src_sc+ESC;
  const int* src_bb=(const int*)d_in[49];
  const int* dst_bb=src_bb+EBB;

  k_detect<<<1,1,0,stream>>>(d_in[0], flag);

  CvtArgs ca;
  {
    int map[29]={14,15,16,17,18,19,20,21,22,23,24,25,30,31,32,33,34,35,36,37,
                 38,39,40,41,42,43,44,45,13};
    for(int i=0;i<29;i++) ca.src[i]=d_in[map[i]];
  }
  k_cvtw<<<(OW_TOT+255)/256,256,0,stream>>>(ca, flag, warena);

  k_wprep4<<<(11776+255)/256,256,0,stream>>>(warena, wfg_hi,wfg_lo, wfbg_hi,wfbg_lo,
                                             wfi2_hi,wfi2_lo, wfi1_hi,wfi1_lo,
                                             wfsc_hi,wfsc_lo, wfbb_hi,wfbb_lo);
  k_prevec<<<1,128,0,stream>>>(warena, d_in[26], d_in[27], d_in[28], d_in[29], flag, dv, dv4);
  k_preP<<<441,128,0,stream>>>(warena, P, sp, qp);

  // featurizer: LN pass -> padded xn, then MFMA GEMM (+bias)
  k_ln<<<(2*N_+3)/4,256,0,stream>>>(d_in[0], d_in[1], d_in[2], d_in[3], d_in[4], d_in[5],
                                    flag, warena, xn_sc, xn_bb);
  const int GB = (N_+63)/64;
  k_mgemm<1,32><<<GB,256,0,stream>>>(xn_sc, nullptr, wfsc_hi, wfsc_lo, warena+OW_SC_B, hat_h, 0, 0, N_);
  k_mgemm<2,64><<<GB,256,0,stream>>>(xn_bb, nullptr, wfbb_hi, wfbb_lo, warena+OW_BB_B, hbuf, 0, 0, N_);

  hipMemsetAsync(cnt4,0,(size_t)4*N_*4,stream);
  k_count2<<<(ESC+EBB+255)/256,256,0,stream>>>(dst_sc,dst_bb,c_sc,c_bb);
  k_scan1x2<<<2*SCB,1024,0,stream>>>(c_sc,c_bb,rp_sc,rp_bb,part);
  k_scan2x2<<<1,64,0,stream>>>(part);
  k_scan3x2<<<2*SCB,1024,0,stream>>>(rp_sc,rp_bb,part);
  k_fill2<<<(ESC+EBB+255)/256,256,0,stream>>>(src_sc,dst_sc,src_bb,dst_bb,rp_sc,rp_bb,
                                              cur_sc,cur_bb,csr_src_sc,csr_eid_sc,csr_src_bb);
  k_sortx<<<(2*N_+255)/256,256,0,stream>>>(rp_sc,csr_eid_sc,csr_src_sc,rp_bb,csr_src_bb);

  k_w0<<<(ESC+255)/256,256,0,stream>>>(d_in[6],d_in[7],(const int*)d_in[46],(const int*)d_in[47],
                                       flag,dv4,P,sp,qp,we);
  k_deg_bb<<<(N_+255)/256,256,0,stream>>>(rp_bb,disb);

  for(int l=0;l<3;l++){
    if(l==0) k_deg0<<<(N_+255)/256,256,0,stream>>>(rp_sc,csr_eid_sc,we,we_csr,dis);
    else     k_degu<<<(N_+255)/256,256,0,stream>>>(rp_sc,csr_src_sc,an,bn,dv,we_csr,dis);
    k_mgemm<4,128><<<GB,256,0,stream>>>(hat_h, nullptr, wfg_hi, wfg_lo, nullptr, bufX, 0, 0, N_);
    k_agg_sc<<<N_/4,256,0,stream>>>(rp_sc,csr_src_sc,we_csr,dis,bufX,warena,hat_h,dv,an,bn,(l<2)?1:0);
  }

  for(int l=0;l<2;l++){
    k_mgemm2<<<GB,256,0,stream>>>(hbuf, hat_h, wfi1_hi, wfi1_lo, wfbg_hi, wfbg_lo,
                                  warena+OW_IB1, bufH, bufX, N_);
    k_agg_bb<<<N_/4,256,0,stream>>>(rp_bb,csr_src_bb,disb,bufX,warena,hbuf);
    k_mgemm<4,128><<<GB,256,0,stream>>>(bufH, nullptr, wfi2_hi, wfi2_lo, warena+OW_IB2, hbuf, 0, 1, N_);
  }

  k_heads<<<N_/4,256,0,stream>>>(hat_h,hbuf,warena,
                                 d_in[8],d_in[9],d_in[10],d_in[11],d_in[12],flag,d_out);
}

// Round 7
// 758.702 us; speedup vs baseline: 1.5624x; 1.0270x over previous
//
#include <hip/hip_runtime.h>
#include <stdint.h>

#define DEVI __device__ __forceinline__

constexpr int N_   = 50000;
constexpr int ESC  = 600000;
constexpr int EBB  = 100000;
constexpr int NRES = 21;
constexpr float PI_F = 3.14159f;

// radix geometry
constexpr int RCH = 4096;                 // items per block
constexpr int RBS = (ESC + RCH - 1)/RCH;  // 147 sc blocks
constexpr int RBB = (EBB + RCH - 1)/RCH;  // 25 bb blocks

typedef __attribute__((ext_vector_type(8))) short short8v;
typedef __attribute__((ext_vector_type(4))) float f32x4;

// ---------- dtype helpers (runtime f32-vs-bf16 dispatch) ----------
DEVI float bf2f(unsigned short u){ return __uint_as_float(((unsigned)u)<<16); }
DEVI unsigned short f2bf(float f){
  unsigned x = __float_as_uint(f);
  unsigned r = (x + 0x7FFFu + ((x>>16)&1u))>>16;
  return (unsigned short)r;
}
DEVI float ldin(const void* p, long i, int f32){
  return f32 ? ((const float*)p)[i] : bf2f(((const unsigned short*)p)[i]);
}
DEVI void stout(void* p, long i, float v, int f32){
  if(f32) ((float*)p)[i]=v; else ((unsigned short*)p)[i]=f2bf(v);
}
DEVI float wrapf(float a){
  float t = a + PI_F;
  const float TP = 2.f*PI_F;
  t -= floorf(t/TP)*TP;
  return t - PI_F;
}

// ---------- weight arena offsets (floats) ----------
constexpr int OW_SC_LN_G=0;
constexpr int OW_SC_LN_B=OW_SC_LN_G+19;
constexpr int OW_SC_W  = OW_SC_LN_B+19;
constexpr int OW_SC_B  = OW_SC_W+19*128;
constexpr int OW_BB_LN_G=OW_SC_B+128;
constexpr int OW_BB_LN_B=OW_BB_LN_G+38;
constexpr int OW_BB_W = OW_BB_LN_B+38;
constexpr int OW_BB_B = OW_BB_W+38*128;
constexpr int OW_E_LN_G=OW_BB_B+128;
constexpr int OW_E_LN_B=OW_E_LN_G+66;
constexpr int OW_EW1 = OW_E_LN_B+66;
constexpr int OW_EB1 = OW_EW1+66*128;
constexpr int OW_GW  = OW_EB1+128;
constexpr int OW_GB  = OW_GW+128*128;
constexpr int OW_BGW = OW_GB+128;
constexpr int OW_BGB = OW_BGW+128*128;
constexpr int OW_IW1 = OW_BGB+128;
constexpr int OW_IB1 = OW_IW1+256*128;
constexpr int OW_IW2 = OW_IB1+128;
constexpr int OW_IB2 = OW_IW2+128*128;
constexpr int OW_AW  = OW_IB2+128;
constexpr int OW_AB  = OW_AW+128;
constexpr int OW_BAW = OW_AB+1;
constexpr int OW_BAB = OW_BAW+128;
constexpr int OW_CW  = OW_BAB+1;
constexpr int OW_CB  = OW_CW+128*3;
constexpr int OW_XW  = OW_CB+3;
constexpr int OW_XB  = OW_XW+128*3;
constexpr int OW_RES = OW_XB+3;
constexpr int OW_TOT = OW_RES+21*32;

// ---------- kernels ----------
__global__ void k_detect(const void* vcom, int* flag){
  const unsigned short* u = (const unsigned short*)vcom;
  int insane=0;
  for(int i=0;i<64;i+=2){
    float f = bf2f(u[i]);
    float a = fabsf(f);
    if(!(a<1e5f) || (a!=0.0f && a<1e-5f)) insane++;
  }
  *flag = (insane>=8)?1:0;
}

struct CvtArgs { const void* src[29]; };

__global__ void k_cvtw(CvtArgs a, const int* flag, float* w){
  static constexpr int offs[30] = {
    OW_SC_LN_G,OW_SC_LN_B,OW_SC_W,OW_SC_B,OW_BB_LN_G,OW_BB_LN_B,OW_BB_W,OW_BB_B,
    OW_E_LN_G,OW_E_LN_B,OW_EW1,OW_EB1,OW_GW,OW_GB,OW_BGW,OW_BGB,OW_IW1,OW_IB1,
    OW_IW2,OW_IB2,OW_AW,OW_AB,OW_BAW,OW_BAB,OW_CW,OW_CB,OW_XW,OW_XB,OW_RES,OW_TOT};
  int f32=*flag;
  for(int t=blockIdx.x*blockDim.x+threadIdx.x; t<OW_TOT; t+=gridDim.x*blockDim.x){
    int s=0;
    while(t>=offs[s+1]) s++;
    w[t]=ldin(a.src[s], t-offs[s], f32);
  }
}

// W[K x 128] -> MFMA fragment order (zero-padded past Kreal), split hi/lo bf16.
DEVI void wprep_pad(const float* W, int Kreal, unsigned short* hi, unsigned short* lo, int idx){
  int lane=idx&63, nt=(idx>>6)&7, kt=idx>>9;
  int n = nt*16 + (lane&15);
  int kbase = kt*32 + (lane>>4)*8;
  #pragma unroll
  for(int i=0;i<8;i++){
    int k=kbase+i;
    float v = (k<Kreal) ? W[(long)k*128 + n] : 0.f;
    unsigned short h = f2bf(v);
    float r = v - bf2f(h);
    hi[(long)idx*8+i]=h;
    lo[(long)idx*8+i]=f2bf(r);
  }
}
__global__ void k_wprep4(const float* w,
    unsigned short* g_hi, unsigned short* g_lo,
    unsigned short* bg_hi, unsigned short* bg_lo,
    unsigned short* i2_hi, unsigned short* i2_lo,
    unsigned short* i1_hi, unsigned short* i1_lo,
    unsigned short* sc_hi, unsigned short* sc_lo,
    unsigned short* bb_hi, unsigned short* bb_lo){
  int idx = blockIdx.x*blockDim.x + threadIdx.x;
  if(idx<2048)       wprep_pad(w+OW_GW,  128, g_hi,  g_lo,  idx);
  else if(idx<4096)  wprep_pad(w+OW_BGW, 128, bg_hi, bg_lo, idx-2048);
  else if(idx<6144)  wprep_pad(w+OW_IW2, 128, i2_hi, i2_lo, idx-4096);
  else if(idx<10240) wprep_pad(w+OW_IW1, 256, i1_hi, i1_lo, idx-6144);
  else if(idx<10752) wprep_pad(w+OW_SC_W, 19, sc_hi, sc_lo, idx-10240);
  else if(idx<11776) wprep_pad(w+OW_BB_W, 38, bb_hi, bb_lo, idx-10752);
}

__global__ void k_prevec(const float* w, const void* eW2, const void* eb2,
                         const void* euW, const void* eub, const int* flag,
                         float* dv, float* dv4){
  int j=threadIdx.x; int f32=*flag;
  const float* g=w+OW_E_LN_G; const float* b=w+OW_E_LN_B; const float* W1=w+OW_EW1;
  float A=g[0]*W1[j], C=g[1]*W1[128+j];
  float G=0,B=0;
  for(int i=0;i<66;i++){ float wij=W1[i*128+j]; G+=g[i]*wij; B+=b[i]*wij; }
  B += w[OW_EB1+j];
  float v2=0; for(int k=0;k<128;k++) v2+=ldin(eW2,(long)j*128+k,f32);
  float us=0,ud=0;
  for(int k=0;k<128;k++){ us+=ldin(euW,(long)j*128+k,f32); ud+=ldin(euW,(long)(128+j)*128+k,f32); }
  float v2m=v2*(1.f/128.f);
  dv[640+j]=us*(1.f/128.f); dv[768+j]=ud*(1.f/128.f);
  int j4=j>>2, r=j&3;
  dv4[j4*20+0+r]=A; dv4[j4*20+4+r]=C; dv4[j4*20+8+r]=G; dv4[j4*20+12+r]=B; dv4[j4*20+16+r]=v2m;
  if(j==0){
    float s=0,t=0;
    for(int k=0;k<128;k++){ s+=ldin(eb2,k,f32); t+=ldin(eub,k,f32); }
    dv[896]=s*(1.f/128.f); dv[897]=t*(1.f/128.f);
    dv4[640]=s*(1.f/128.f);
  }
}

__global__ void k_preP(const float* w, float* P, float* sp, float* qp){
  __shared__ float pv[64];
  int c=blockIdx.x, ri=c/NRES, rj=c%NRES, j=threadIdx.x;
  const float* res=w+OW_RES;
  if(j<32) pv[j]=res[ri*32+j];
  else if(j<64) pv[j]=res[rj*32+(j-32)];
  __syncthreads();
  const float* g=w+OW_E_LN_G; const float* W1=w+OW_EW1;
  float s=0;
  for(int i=0;i<64;i++) s += pv[i]*g[2+i]*W1[(2+i)*128+j];
  P[c*128+j]=s;
  if(j==0){ float a=0,q=0; for(int i=0;i<64;i++){a+=pv[i]; q+=pv[i]*pv[i];} sp[c]=a; qp[c]=q; }
}

// LN pass: one wave per node
__global__ void k_ln(const void* vcom, const void* sbfchi,
                     const void* xca, const void* vcb, const void* sphi, const void* spsi,
                     const int* flag, const float* w, float* xn_sc, float* xn_bb){
  int wv=threadIdx.x>>6, lane=threadIdx.x&63;
  long gw=(long)blockIdx.x*4+wv;
  int f32=*flag;
  if(gw<N_){
    int n=(int)gw;
    float x=0.f;
    if(lane<3) x=ldin(vcom,(long)n*3+lane,f32);
    else if(lane<19) x=ldin(sbfchi,(long)n*16+(lane-3),f32);
    float s=x, q=x*x;
    for(int m=1;m<64;m<<=1){ s+=__shfl_xor(s,m,64); q+=__shfl_xor(q,m,64); }
    float mean=s*(1.f/19.f);
    float var=fmaxf(q*(1.f/19.f)-mean*mean,0.f);
    float istd=rsqrtf(var+1e-5f);
    if(lane<32){
      float xn=(lane<19)? (x-mean)*istd*w[OW_SC_LN_G+lane]+w[OW_SC_LN_B+lane] : 0.f;
      xn_sc[(long)n*32+lane]=xn;
    }
  } else if(gw<2L*N_){
    int n=(int)(gw-N_);
    float x=0.f;
    if(lane<3) x=ldin(xca,(long)n*3+lane,f32);
    else if(lane<6) x=ldin(vcb,(long)n*3+(lane-3),f32);
    else if(lane<22) x=ldin(sphi,(long)n*16+(lane-6),f32);
    else if(lane<38) x=ldin(spsi,(long)n*16+(lane-22),f32);
    float s=x, q=x*x;
    for(int m=1;m<64;m<<=1){ s+=__shfl_xor(s,m,64); q+=__shfl_xor(q,m,64); }
    float mean=s*(1.f/38.f);
    float var=fmaxf(q*(1.f/38.f)-mean*mean,0.f);
    float istd=rsqrtf(var+1e-5f);
    float xn=(lane<38)? (x-mean)*istd*w[OW_BB_LN_G+lane]+w[OW_BB_LN_B+lane] : 0.f;
    xn_bb[(long)n*64+lane]=xn;
  }
}

// ---------- stable 2-pass radix CSR build ----------
// pass A: per-block digit histogram -> hist[(seg+b)*256+d]
__global__ void k_rhist(const int* key_sc, const int* key_bb, int shift, int* hist){
  __shared__ int h[256];
  h[threadIdx.x]=0; __syncthreads();
  int g = blockIdx.x>=RBS;
  const int* key = g? key_bb : key_sc;
  int E = g? EBB : ESC;
  int b = g? blockIdx.x-RBS : blockIdx.x;
  int base=b*RCH;
  for(int r=0;r<16;r++){
    int idx=base+r*256+threadIdx.x;
    if(idx<E) atomicAdd(&h[(key[idx]>>shift)&255],1);
  }
  __syncthreads();
  hist[(long)blockIdx.x*256+threadIdx.x]=h[threadIdx.x];
}
// pass B: per-graph exclusive scan over (digit, block) with digit bases
__global__ void k_rscan(int* hist){
  __shared__ int tot[256], base[256];
  int d=threadIdx.x;
  int run=0;
  for(int b=0;b<RBS;b++){ int v=hist[b*256+d]; hist[b*256+d]=run; run+=v; }
  tot[d]=run; __syncthreads();
  if(d==0){ int r=0; for(int i=0;i<256;i++){ base[i]=r; r+=tot[i]; } }
  __syncthreads();
  for(int b=0;b<RBS;b++) hist[b*256+d]+=base[d];
  __syncthreads();
  int* H=hist+RBS*256;
  run=0;
  for(int b=0;b<RBB;b++){ int v=H[b*256+d]; H[b*256+d]=run; run+=v; }
  tot[d]=run; __syncthreads();
  if(d==0){ int r=0; for(int i=0;i<256;i++){ base[i]=r; r+=tot[i]; } }
  __syncthreads();
  for(int b=0;b<RBB;b++) H[b*256+d]+=base[d];
}
// pass C: stable scatter (ballot-ranked)
__global__ void k_rscat(int shift, int first,
    const int* kin_sc, const int* srcv_sc, const int2* pin_sc,
    const int* kin_bb, const int* srcv_bb, const int2* pin_bb,
    const int* hist,
    int* kout_sc, int2* pout_sc, int* kout_bb, int2* pout_bb){
  __shared__ int running[256];
  __shared__ int Hb[256];
  __shared__ int whist[4][256];
  __shared__ int pw[4][256];
  int tid=threadIdx.x, lane=tid&63, w=tid>>6;
  int g = blockIdx.x>=RBS;
  const int* kin  = g? kin_bb : kin_sc;
  const int* srcv = g? srcv_bb: srcv_sc;
  const int2* pin = g? pin_bb : pin_sc;
  int* kout  = g? kout_bb : kout_sc;
  int2* pout = g? pout_bb : pout_sc;
  int E = g? EBB : ESC;
  int b = g? blockIdx.x-RBS : blockIdx.x;
  running[tid]=0;
  Hb[tid]=hist[(long)blockIdx.x*256+tid];
  int base=b*RCH;
  for(int r=0;r<16;r++){
    __syncthreads();
    whist[0][tid]=0; whist[1][tid]=0; whist[2][tid]=0; whist[3][tid]=0;
    __syncthreads();
    int idx=base+r*256+tid;
    bool valid = idx<E;
    int key=0, digit=0; int2 pay; pay.x=0; pay.y=0;
    if(valid){
      key=kin[idx];
      digit=(key>>shift)&255;
      if(first){ pay.x=srcv[idx]; pay.y=idx; }
      else pay=pin[idx];
    }
    unsigned long long act=__ballot(valid);
    unsigned long long same=act;
    #pragma unroll
    for(int k=0;k<8;k++){
      unsigned long long m=__ballot(valid && ((digit>>k)&1));
      same &= ((digit>>k)&1)? m : ~m;
    }
    same &= act;
    unsigned long long below=(1ULL<<lane)-1ULL;
    int wrank=__popcll(same & below);
    if(valid && wrank==0) whist[w][digit]=__popcll(same);
    __syncthreads();
    int c0=whist[0][tid], c1=whist[1][tid], c2=whist[2][tid], c3=whist[3][tid];
    pw[0][tid]=0; pw[1][tid]=c0; pw[2][tid]=c0+c1; pw[3][tid]=c0+c1+c2;
    __syncthreads();
    if(valid){
      int pos=Hb[digit]+running[digit]+pw[w][digit]+wrank;
      kout[pos]=key; pout[pos]=pay;
    }
    __syncthreads();
    running[tid]+=c0+c1+c2+c3;
  }
}
// rp from sorted dst boundaries
__global__ void k_bounds(const int* dstS_sc, const int* dstS_bb, int* rp_sc, int* rp_bb){
  long i=(long)blockIdx.x*blockDim.x+threadIdx.x;
  if(i<=ESC){
    int cur = (i<ESC)? dstS_sc[i] : N_;
    int prev= (i>0)? dstS_sc[i-1] : -1;
    for(int d=prev+1; d<=cur; d++) rp_sc[d]=(int)i;
  } else if(i <= (long)ESC+1+EBB){
    long j=i-(ESC+1);
    int cur = (j<EBB)? dstS_bb[j] : N_;
    int prev= (j>0)? dstS_bb[j-1] : -1;
    for(int d=prev+1; d<=cur; d++) rp_bb[d]=(int)j;
  }
}

// ---------- edge MLP: one edge per lane ----------
__global__ void k_w0(const void* dsc, const void* dmin, const int* ri_, const int* rj_,
                     const int* flag, const float* dv4, const float* P,
                     const float* sp, const float* qp, float* we){
  int e=blockIdx.x*blockDim.x+threadIdx.x;
  if(e>=ESC) return;
  int f32=*flag;
  float d1=ldin(dsc,e,f32), d2=ldin(dmin,e,f32);
  int c=ri_[e]*NRES+rj_[e];
  float m=(d1+d2+sp[c])*(1.f/66.f);
  float ms=(d1*d1+d2*d2+qp[c])*(1.f/66.f);
  float istd=rsqrtf(fmaxf(ms-m*m,0.f)+1e-5f);
  float nmi=-m*istd;
  const float4* Pr=(const float4*)&P[(long)c*128];
  float acc=0.f;
  #pragma unroll 8
  for(int j4=0;j4<32;j4++){
    const float4* q=(const float4*)&dv4[j4*20];
    float4 A4=q[0], C4=q[1], G4=q[2], B4=q[3], V4=q[4];
    float4 P4=Pr[j4];
    float t,hid;
    t=fmaf(d1,A4.x,fmaf(d2,C4.x,P4.x)); hid=fmaf(istd,t,fmaf(nmi,G4.x,B4.x)); acc=fmaf(fmaxf(hid,0.f),V4.x,acc);
    t=fmaf(d1,A4.y,fmaf(d2,C4.y,P4.y)); hid=fmaf(istd,t,fmaf(nmi,G4.y,B4.y)); acc=fmaf(fmaxf(hid,0.f),V4.y,acc);
    t=fmaf(d1,A4.z,fmaf(d2,C4.z,P4.z)); hid=fmaf(istd,t,fmaf(nmi,G4.z,B4.z)); acc=fmaf(fmaxf(hid,0.f),V4.z,acc);
    t=fmaf(d1,A4.w,fmaf(d2,C4.w,P4.w)); hid=fmaf(istd,t,fmaf(nmi,G4.w,B4.w)); acc=fmaf(fmaxf(hid,0.f),V4.w,acc);
  }
  we[e]=acc+dv4[640];
}

// ---------- degree passes (we maintained in CSR order) ----------
__global__ void k_deg0(const int* rp, const int2* se, const float* we_edge,
                       float* we_csr, float* dis){
  int n=blockIdx.x*blockDim.x+threadIdx.x;
  if(n>=N_) return;
  float s=1.f;
  int e0=rp[n], e1=rp[n+1];
  for(int p=e0;p<e1;p++){ float w=we_edge[se[p].y]; we_csr[p]=w; s+=w; }
  dis[n]=rsqrtf(fmaxf(s,1e-6f));
}
__global__ void k_degu(const int* rp, const int2* se, const float* an, const float* bn,
                       const float* dv, float* we_csr, float* dis){
  int n=blockIdx.x*blockDim.x+threadIdx.x;
  if(n>=N_) return;
  float add_n = bn[n] + dv[897];
  float s=1.f;
  int e0=rp[n], e1=rp[n+1];
  for(int p=e0;p<e1;p++){
    float w=we_csr[p] + an[se[p].x] + add_n;
    we_csr[p]=w; s+=w;
  }
  dis[n]=rsqrtf(fmaxf(s,1e-6f));
}
__global__ void k_deg_bb(const int* rp, float* dis){
  int n=blockIdx.x*blockDim.x+threadIdx.x;
  if(n>=N_) return;
  float s=1.f+(float)(rp[n+1]-rp[n]);
  dis[n]=rsqrtf(fmaxf(s,1e-6f));
}

// ---------- split-bf16 MFMA GEMM ----------
DEVI f32x4 MFMA(short8v a, short8v b, f32x4 c){
  return __builtin_amdgcn_mfma_f32_16x16x32_bf16(a,b,c,0,0,0);
}
DEVI void cvt8(float4 a0, float4 a1, short8v& hi, short8v& lo){
  float av[8]={a0.x,a0.y,a0.z,a0.w,a1.x,a1.y,a1.z,a1.w};
  union{short8v v; unsigned short u[8];} H,L;
  #pragma unroll
  for(int i=0;i<8;i++){
    unsigned short h=f2bf(av[i]);
    float r=av[i]-bf2f(h);
    H.u[i]=h; L.u[i]=f2bf(r);
  }
  hi=H.v; lo=L.v;
}

template<int KT, int LDA>
__global__ __launch_bounds__(256,4) void k_mgemm(const float* A1, const float* A2,
    const unsigned short* Whi, const unsigned short* Wlo,
    const float* bias, float* C, int relu, int accum, int M){
  const int lane = threadIdx.x & 63;
  const int wid  = threadIdx.x >> 6;
  const int r0   = blockIdx.x*64 + wid*16;
  const int mrow = lane & 15;
  const int kg   = lane >> 4;
  long arow = (long)min(r0 + mrow, M-1);
  f32x4 acc[8];
  #pragma unroll
  for(int t=0;t<8;t++) acc[t]=(f32x4){0.f,0.f,0.f,0.f};

  #pragma unroll
  for(int kt=0; kt<KT; kt++){
    const float* A = (KT==8 && kt>=4) ? A2 : A1;
    int kb = (kt&3)*32 + kg*8;
    float4 a0 = *(const float4*)&A[arow*LDA + kb];
    float4 a1 = *(const float4*)&A[arow*LDA + kb + 4];
    short8v ah, al; cvt8(a0,a1,ah,al);
    #pragma unroll
    for(int nt=0;nt<8;nt++){
      long off = (((long)kt*8+nt)*64 + lane)*8;
      short8v wh = *(const short8v*)&Whi[off];
      short8v wl = *(const short8v*)&Wlo[off];
      acc[nt] = MFMA(ah, wh, acc[nt]);
      acc[nt] = MFMA(al, wh, acc[nt]);
      acc[nt] = MFMA(ah, wl, acc[nt]);
      acc[nt] = MFMA(al, wl, acc[nt]);
    }
  }

  #pragma unroll
  for(int nt=0;nt<8;nt++){
    int col = nt*16 + mrow;
    float bj = bias ? bias[col] : 0.f;
    #pragma unroll
    for(int r=0;r<4;r++){
      int row = r0 + kg*4 + r;
      if(row >= M) continue;
      long idx = (long)row*128 + col;
      float v = acc[nt][r] + bj;
      if(relu) v = fmaxf(v,0.f);
      if(accum) v += C[idx];
      C[idx] = v;
    }
  }
}

// fused dual GEMM: C1 = relu(A1@W1[0:128] + A2@W1[128:256] + b1); C2 = A1@W2
__global__ __launch_bounds__(256,4) void k_mgemm2(const float* A1, const float* A2,
    const unsigned short* W1hi, const unsigned short* W1lo,
    const unsigned short* W2hi, const unsigned short* W2lo,
    const float* b1, float* C1, float* C2, int M){
  const int lane = threadIdx.x & 63;
  const int wid  = threadIdx.x >> 6;
  const int r0   = blockIdx.x*64 + wid*16;
  const int mrow = lane & 15;
  const int kg   = lane >> 4;
  long arow = (long)min(r0 + mrow, M-1);
  f32x4 acc1[8], acc2[8];
  #pragma unroll
  for(int t=0;t<8;t++){ acc1[t]=(f32x4){0,0,0,0}; acc2[t]=(f32x4){0,0,0,0}; }

  #pragma unroll
  for(int kt=0; kt<8; kt++){
    const float* A = (kt>=4) ? A2 : A1;
    int kb = (kt&3)*32 + kg*8;
    float4 a0 = *(const float4*)&A[arow*128 + kb];
    float4 a1 = *(const float4*)&A[arow*128 + kb + 4];
    short8v ah, al; cvt8(a0,a1,ah,al);
    #pragma unroll
    for(int nt=0;nt<8;nt++){
      long off = (((long)kt*8+nt)*64 + lane)*8;
      short8v wh = *(const short8v*)&W1hi[off];
      short8v wl = *(const short8v*)&W1lo[off];
      acc1[nt] = MFMA(ah, wh, acc1[nt]);
      acc1[nt] = MFMA(al, wh, acc1[nt]);
      acc1[nt] = MFMA(ah, wl, acc1[nt]);
      acc1[nt] = MFMA(al, wl, acc1[nt]);
    }
    if(kt<4){
      #pragma unroll
      for(int nt=0;nt<8;nt++){
        long off = (((long)kt*8+nt)*64 + lane)*8;
        short8v wh = *(const short8v*)&W2hi[off];
        short8v wl = *(const short8v*)&W2lo[off];
        acc2[nt] = MFMA(ah, wh, acc2[nt]);
        acc2[nt] = MFMA(al, wh, acc2[nt]);
        acc2[nt] = MFMA(ah, wl, acc2[nt]);
        acc2[nt] = MFMA(al, wl, acc2[nt]);
      }
    }
  }

  #pragma unroll
  for(int nt=0;nt<8;nt++){
    int col = nt*16 + mrow;
    float bj = b1[col];
    #pragma unroll
    for(int r=0;r<4;r++){
      int row = r0 + kg*4 + r;
      if(row >= M) continue;
      long idx = (long)row*128 + col;
      C1[idx] = fmaxf(acc1[nt][r] + bj, 0.f);
      C2[idx] = acc2[nt][r];
    }
  }
}

// ---------- aggregation: wave per node, 2 edges in flight via 32-lane halves ----------
__global__ void k_agg_sc(const int* rp, const int2* se, const float* wc,
                         const float* dis, const float* xw, const float* w,
                         float* hat_h, const float* dv, float* an, float* bn, int withdot){
  int wv=threadIdx.x>>6, lane=threadIdx.x&63;
  int n=blockIdx.x*4+wv;
  int half=lane>>5, l4=(lane&31)*4;
  float disn=dis[n];
  float4 acc={0,0,0,0};
  int e0=rp[n], e1=rp[n+1];
  int p=e0+half;
  for(; p+2<e1; p+=4){
    int s0=se[p].x, s1=se[p+2].x;
    float nw0=dis[s0]*wc[p]*disn;
    float nw1=dis[s1]*wc[p+2]*disn;
    float4 x0=*(const float4*)&xw[(long)s0*128+l4];
    float4 x1=*(const float4*)&xw[(long)s1*128+l4];
    acc.x+=nw0*x0.x+nw1*x1.x; acc.y+=nw0*x0.y+nw1*x1.y;
    acc.z+=nw0*x0.z+nw1*x1.z; acc.w+=nw0*x0.w+nw1*x1.w;
  }
  if(p<e1){
    int s0=se[p].x;
    float nw0=dis[s0]*wc[p]*disn;
    float4 x0=*(const float4*)&xw[(long)s0*128+l4];
    acc.x+=nw0*x0.x; acc.y+=nw0*x0.y; acc.z+=nw0*x0.z; acc.w+=nw0*x0.w;
  }
  acc.x+=__shfl_xor(acc.x,32,64); acc.y+=__shfl_xor(acc.y,32,64);
  acc.z+=__shfl_xor(acc.z,32,64); acc.w+=__shfl_xor(acc.w,32,64);
  float d2=disn*disn;
  float4 xs=*(const float4*)&xw[(long)n*128+l4];
  float4 gb=*(const float4*)&w[OW_GB+l4];
  float4 ho=*(const float4*)&hat_h[(long)n*128+l4];
  float4 h;
  h.x=ho.x+fmaxf(acc.x+d2*xs.x+gb.x,0.f);
  h.y=ho.y+fmaxf(acc.y+d2*xs.y+gb.y,0.f);
  h.z=ho.z+fmaxf(acc.z+d2*xs.z+gb.z,0.f);
  h.w=ho.w+fmaxf(acc.w+d2*xs.w+gb.w,0.f);
  if(half==0) *(float4*)&hat_h[(long)n*128+l4]=h;
  if(withdot){
    float4 us=*(const float4*)&dv[640+l4];
    float4 ud=*(const float4*)&dv[768+l4];
    float a = (half==0)? h.x*us.x+h.y*us.y+h.z*us.z+h.w*us.w : 0.f;
    float b = (half==0)? h.x*ud.x+h.y*ud.y+h.z*ud.z+h.w*ud.w : 0.f;
    for(int m=1;m<64;m<<=1){ a+=__shfl_xor(a,m,64); b+=__shfl_xor(b,m,64); }
    if(lane==0){ an[n]=a; bn[n]=b; }
  }
}

__global__ void k_agg_bb(const int* rp, const int2* se, const float* dis,
                         const float* xw, const float* w, float* h){
  int wv=threadIdx.x>>6, lane=threadIdx.x&63;
  int n=blockIdx.x*4+wv;
  int half=lane>>5, l4=(lane&31)*4;
  float disn=dis[n];
  float4 acc={0,0,0,0};
  int e0=rp[n], e1=rp[n+1];
  int p=e0+half;
  for(; p+2<e1; p+=4){
    int s0=se[p].x, s1=se[p+2].x;
    float nw0=dis[s0]*disn, nw1=dis[s1]*disn;
    float4 x0=*(const float4*)&xw[(long)s0*128+l4];
    float4 x1=*(const float4*)&xw[(long)s1*128+l4];
    acc.x+=nw0*x0.x+nw1*x1.x; acc.y+=nw0*x0.y+nw1*x1.y;
    acc.z+=nw0*x0.z+nw1*x1.z; acc.w+=nw0*x0.w+nw1*x1.w;
  }
  if(p<e1){
    int s0=se[p].x;
    float nw0=dis[s0]*disn;
    float4 x0=*(const float4*)&xw[(long)s0*128+l4];
    acc.x+=nw0*x0.x; acc.y+=nw0*x0.y; acc.z+=nw0*x0.z; acc.w+=nw0*x0.w;
  }
  acc.x+=__shfl_xor(acc.x,32,64); acc.y+=__shfl_xor(acc.y,32,64);
  acc.z+=__shfl_xor(acc.z,32,64); acc.w+=__shfl_xor(acc.w,32,64);
  if(half==0){
    float d2=disn*disn;
    float4 xs=*(const float4*)&xw[(long)n*128+l4];
    float4 gb=*(const float4*)&w[OW_BGB+l4];
    float4 hv=*(float4*)&h[(long)n*128+l4];
    hv.x+=fmaxf(acc.x+d2*xs.x+gb.x,0.f);
    hv.y+=fmaxf(acc.y+d2*xs.y+gb.y,0.f);
    hv.z+=fmaxf(acc.z+d2*xs.z+gb.z,0.f);
    hv.w+=fmaxf(acc.w+d2*xs.w+gb.w,0.f);
    *(float4*)&h[(long)n*128+l4]=hv;
  }
}

__global__ void k_heads(const float* hat_h, const float* h, const float* w,
                        const void* old_chi, const void* old_phi, const void* old_psi,
                        const void* old_cb, const void* old_ca, const int* flag, void* out){
  int wv=threadIdx.x>>6, lane=threadIdx.x&63;
  int n=blockIdx.x*4+wv;
  int f32=*flag;
  float s0=fmaxf(hat_h[(long)n*128+lane],0.f), s1=fmaxf(hat_h[(long)n*128+64+lane],0.f);
  float b0=fmaxf(h[(long)n*128+lane],0.f),    b1=fmaxf(h[(long)n*128+64+lane],0.f);
  float r[8];
  r[0]=s0*w[OW_AW+lane]+s1*w[OW_AW+64+lane];
  r[1]=s0*w[OW_CW+lane*3+0]+s1*w[OW_CW+(64+lane)*3+0];
  r[2]=s0*w[OW_CW+lane*3+1]+s1*w[OW_CW+(64+lane)*3+1];
  r[3]=s0*w[OW_CW+lane*3+2]+s1*w[OW_CW+(64+lane)*3+2];
  r[4]=b0*w[OW_BAW+lane]+b1*w[OW_BAW+64+lane];
  r[5]=b0*w[OW_XW+lane*3+0]+b1*w[OW_XW+(64+lane)*3+0];
  r[6]=b0*w[OW_XW+lane*3+1]+b1*w[OW_XW+(64+lane)*3+1];
  r[7]=b0*w[OW_XW+lane*3+2]+b1*w[OW_XW+(64+lane)*3+2];
  for(int m=1;m<64;m<<=1){
    #pragma unroll
    for(int t=0;t<8;t++) r[t]+=__shfl_xor(r[t],m,64);
  }
  if(lane==0){
    float dchi=r[0]+w[OW_AB];
    for(int k=0;k<4;k++)
      stout(out,(long)k*N_+n, wrapf(ldin(old_chi,(long)k*N_+n,f32)+dchi), f32);
    float dphi=r[4]+w[OW_BAB];
    stout(out,(long)4*N_+n, wrapf(ldin(old_phi,n,f32)+dphi), f32);
    stout(out,(long)5*N_+n, wrapf(ldin(old_psi,n,f32)+dphi), f32);
    for(int t=0;t<3;t++){
      stout(out,(long)6*N_+(long)n*3+t, ldin(old_cb,(long)n*3+t,f32)+r[1+t]+w[OW_CB+t], f32);
      stout(out,(long)9*N_+(long)n*3+t, ldin(old_ca,(long)n*3+t,f32)+r[5+t]+w[OW_XB+t], f32);
    }
  }
}

// ---------- host ----------
extern "C" void kernel_launch(void* const* d_in, const int* in_sizes, int n_in,
                              void* d_out, int out_size, void* d_ws, size_t ws_size,
                              hipStream_t stream) {
  (void)in_sizes; (void)n_in; (void)out_size; (void)ws_size;

  char* p=(char*)d_ws;
  auto alloc=[&](size_t bytes)->void*{ void* r=(void*)p; p+=((bytes+255)&~(size_t)255); return r; };
  int*   flag   =(int*)  alloc(16);
  float* warena =(float*)alloc((size_t)OW_TOT*4);
  float* dv     =(float*)alloc(1024*4);
  float* dv4    =(float*)alloc(1024*4);
  float* P      =(float*)alloc((size_t)441*128*4);
  float* sp     =(float*)alloc(441*4);
  float* qp     =(float*)alloc(441*4);
  float* hat_h  =(float*)alloc((size_t)N_*128*4);
  float* hbuf   =(float*)alloc((size_t)N_*128*4);
  float* bufX   =(float*)alloc((size_t)N_*128*4);
  float* bufH   =(float*)alloc((size_t)N_*128*4);
  float* xn_sc  =(float*)alloc((size_t)N_*32*4);
  float* xn_bb  =(float*)alloc((size_t)N_*64*4);
  float* we     =(float*)alloc((size_t)ESC*4);
  float* we_csr =(float*)alloc((size_t)ESC*4);
  float* an     =(float*)alloc((size_t)N_*4);
  float* bn     =(float*)alloc((size_t)N_*4);
  float* dis    =(float*)alloc((size_t)N_*4);
  float* disb   =(float*)alloc((size_t)N_*4);
  int* rp_sc    =(int*)  alloc((size_t)(N_+1)*4);
  int* rp_bb    =(int*)  alloc((size_t)(N_+1)*4);
  // radix buffers
  int*  key1_sc =(int*)  alloc((size_t)ESC*4);
  int2* pay1_sc =(int2*) alloc((size_t)ESC*8);
  int*  dstS_sc =(int*)  alloc((size_t)ESC*4);
  int2* csr_se_sc=(int2*)alloc((size_t)ESC*8);
  int*  key1_bb =(int*)  alloc((size_t)EBB*4);
  int2* pay1_bb =(int2*) alloc((size_t)EBB*8);
  int*  dstS_bb =(int*)  alloc((size_t)EBB*4);
  int2* csr_se_bb=(int2*)alloc((size_t)EBB*8);
  int*  hist    =(int*)  alloc((size_t)(RBS+RBB)*256*4);
  unsigned short* wfg_hi =(unsigned short*)alloc(2048*8*2);
  unsigned short* wfg_lo =(unsigned short*)alloc(2048*8*2);
  unsigned short* wfbg_hi=(unsigned short*)alloc(2048*8*2);
  unsigned short* wfbg_lo=(unsigned short*)alloc(2048*8*2);
  unsigned short* wfi2_hi=(unsigned short*)alloc(2048*8*2);
  unsigned short* wfi2_lo=(unsigned short*)alloc(2048*8*2);
  unsigned short* wfi1_hi=(unsigned short*)alloc(4096*8*2);
  unsigned short* wfi1_lo=(unsigned short*)alloc(4096*8*2);
  unsigned short* wfsc_hi=(unsigned short*)alloc(512*8*2);
  unsigned short* wfsc_lo=(unsigned short*)alloc(512*8*2);
  unsigned short* wfbb_hi=(unsigned short*)alloc(1024*8*2);
  unsigned short* wfbb_lo=(unsigned short*)alloc(1024*8*2);

  const int* src_sc=(const int*)d_in[48];
  const int* dst_sc=src_sc+ESC;
  const int* src_bb=(const int*)d_in[49];
  const int* dst_bb=src_bb+EBB;

  k_detect<<<1,1,0,stream>>>(d_in[0], flag);

  CvtArgs ca;
  {
    int map[29]={14,15,16,17,18,19,20,21,22,23,24,25,30,31,32,33,34,35,36,37,
                 38,39,40,41,42,43,44,45,13};
    for(int i=0;i<29;i++) ca.src[i]=d_in[map[i]];
  }
  k_cvtw<<<(OW_TOT+255)/256,256,0,stream>>>(ca, flag, warena);

  k_wprep4<<<(11776+255)/256,256,0,stream>>>(warena, wfg_hi,wfg_lo, wfbg_hi,wfbg_lo,
                                             wfi2_hi,wfi2_lo, wfi1_hi,wfi1_lo,
                                             wfsc_hi,wfsc_lo, wfbb_hi,wfbb_lo);
  k_prevec<<<1,128,0,stream>>>(warena, d_in[26], d_in[27], d_in[28], d_in[29], flag, dv, dv4);
  k_preP<<<441,128,0,stream>>>(warena, P, sp, qp);

  // featurizer: LN pass -> padded xn, then MFMA GEMM (+bias)
  k_ln<<<(2*N_+3)/4,256,0,stream>>>(d_in[0], d_in[1], d_in[2], d_in[3], d_in[4], d_in[5],
                                    flag, warena, xn_sc, xn_bb);
  const int GB = (N_+63)/64;
  k_mgemm<1,32><<<GB,256,0,stream>>>(xn_sc, nullptr, wfsc_hi, wfsc_lo, warena+OW_SC_B, hat_h, 0, 0, N_);
  k_mgemm<2,64><<<GB,256,0,stream>>>(xn_bb, nullptr, wfbb_hi, wfbb_lo, warena+OW_BB_B, hbuf, 0, 0, N_);

  // stable radix CSR build (2 passes of 8 bits over dst)
  k_rhist<<<RBS+RBB,256,0,stream>>>(dst_sc, dst_bb, 0, hist);
  k_rscan<<<1,256,0,stream>>>(hist);
  k_rscat<<<RBS+RBB,256,0,stream>>>(0, 1, dst_sc, src_sc, (const int2*)nullptr,
                                    dst_bb, src_bb, (const int2*)nullptr, hist,
                                    key1_sc, pay1_sc, key1_bb, pay1_bb);
  k_rhist<<<RBS+RBB,256,0,stream>>>(key1_sc, key1_bb, 8, hist);
  k_rscan<<<1,256,0,stream>>>(hist);
  k_rscat<<<RBS+RBB,256,0,stream>>>(8, 0, key1_sc, (const int*)nullptr, pay1_sc,
                                    key1_bb, (const int*)nullptr, pay1_bb, hist,
                                    dstS_sc, csr_se_sc, dstS_bb, csr_se_bb);
  k_bounds<<<(int)(((long)ESC+1+EBB+1+255)/256),256,0,stream>>>(dstS_sc, dstS_bb, rp_sc, rp_bb);

  k_w0<<<(ESC+255)/256,256,0,stream>>>(d_in[6],d_in[7],(const int*)d_in[46],(const int*)d_in[47],
                                       flag,dv4,P,sp,qp,we);
  k_deg_bb<<<(N_+255)/256,256,0,stream>>>(rp_bb,disb);

  for(int l=0;l<3;l++){
    if(l==0) k_deg0<<<(N_+255)/256,256,0,stream>>>(rp_sc,csr_se_sc,we,we_csr,dis);
    else     k_degu<<<(N_+255)/256,256,0,stream>>>(rp_sc,csr_se_sc,an,bn,dv,we_csr,dis);
    k_mgemm<4,128><<<GB,256,0,stream>>>(hat_h, nullptr, wfg_hi, wfg_lo, nullptr, bufX, 0, 0, N_);
    k_agg_sc<<<N_/4,256,0,stream>>>(rp_sc,csr_se_sc,we_csr,dis,bufX,warena,hat_h,dv,an,bn,(l<2)?1:0);
  }

  for(int l=0;l<2;l++){
    k_mgemm2<<<GB,256,0,stream>>>(hbuf, hat_h, wfi1_hi, wfi1_lo, wfbg_hi, wfbg_lo,
                                  warena+OW_IB1, bufH, bufX, N_);
    k_agg_bb<<<N_/4,256,0,stream>>>(rp_bb,csr_se_bb,disb,bufX,warena,hbuf);
    k_mgemm<4,128><<<GB,256,0,stream>>>(bufH, nullptr, wfi2_hi, wfi2_lo, warena+OW_IB2, hbuf, 0, 1, N_);
  }

  k_heads<<<N_/4,256,0,stream>>>(hat_h,hbuf,warena,
                                 d_in[8],d_in[9],d_in[10],d_in[11],d_in[12],flag,d_out);
}

// Round 8
// 733.742 us; speedup vs baseline: 1.6156x; 1.0340x over previous
//
#include <hip/hip_runtime.h>
#include <stdint.h>

#define DEVI __device__ __forceinline__

constexpr int N_   = 50000;
constexpr int ESC  = 600000;
constexpr int EBB  = 100000;
constexpr int NRES = 21;
constexpr float PI_F = 3.14159f;

// radix geometry
constexpr int RCH = 4096;
constexpr int RBS = (ESC + RCH - 1)/RCH;  // 147
constexpr int RBB = (EBB + RCH - 1)/RCH;  // 25

typedef __attribute__((ext_vector_type(8))) short short8v;
typedef __attribute__((ext_vector_type(4))) float f32x4;

// ---------- dtype helpers ----------
DEVI float bf2f(unsigned short u){ return __uint_as_float(((unsigned)u)<<16); }
DEVI unsigned short f2bf(float f){
  unsigned x = __float_as_uint(f);
  unsigned r = (x + 0x7FFFu + ((x>>16)&1u))>>16;
  return (unsigned short)r;
}
DEVI float ldin(const void* p, long i, int f32){
  return f32 ? ((const float*)p)[i] : bf2f(((const unsigned short*)p)[i]);
}
DEVI void stout(void* p, long i, float v, int f32){
  if(f32) ((float*)p)[i]=v; else ((unsigned short*)p)[i]=f2bf(v);
}
DEVI float wrapf(float a){
  float t = a + PI_F;
  const float TP = 2.f*PI_F;
  t -= floorf(t/TP)*TP;
  return t - PI_F;
}

// ---------- weight arena offsets ----------
constexpr int OW_SC_LN_G=0;
constexpr int OW_SC_LN_B=OW_SC_LN_G+19;
constexpr int OW_SC_W  = OW_SC_LN_B+19;
constexpr int OW_SC_B  = OW_SC_W+19*128;
constexpr int OW_BB_LN_G=OW_SC_B+128;
constexpr int OW_BB_LN_B=OW_BB_LN_G+38;
constexpr int OW_BB_W = OW_BB_LN_B+38;
constexpr int OW_BB_B = OW_BB_W+38*128;
constexpr int OW_E_LN_G=OW_BB_B+128;
constexpr int OW_E_LN_B=OW_E_LN_G+66;
constexpr int OW_EW1 = OW_E_LN_B+66;
constexpr int OW_EB1 = OW_EW1+66*128;
constexpr int OW_GW  = OW_EB1+128;
constexpr int OW_GB  = OW_GW+128*128;
constexpr int OW_BGW = OW_GB+128;
constexpr int OW_BGB = OW_BGW+128*128;
constexpr int OW_IW1 = OW_BGB+128;
constexpr int OW_IB1 = OW_IW1+256*128;
constexpr int OW_IW2 = OW_IB1+128;
constexpr int OW_IB2 = OW_IW2+128*128;
constexpr int OW_AW  = OW_IB2+128;
constexpr int OW_AB  = OW_AW+128;
constexpr int OW_BAW = OW_AB+1;
constexpr int OW_BAB = OW_BAW+128;
constexpr int OW_CW  = OW_BAB+1;
constexpr int OW_CB  = OW_CW+128*3;
constexpr int OW_XW  = OW_CB+3;
constexpr int OW_XB  = OW_XW+128*3;
constexpr int OW_RES = OW_XB+3;
constexpr int OW_TOT = OW_RES+21*32;

// ---------- basic kernels ----------
__global__ void k_detect(const void* vcom, int* flag){
  const unsigned short* u = (const unsigned short*)vcom;
  int insane=0;
  for(int i=0;i<64;i+=2){
    float f = bf2f(u[i]);
    float a = fabsf(f);
    if(!(a<1e5f) || (a!=0.0f && a<1e-5f)) insane++;
  }
  *flag = (insane>=8)?1:0;
}

struct CvtArgs { const void* src[29]; };

__global__ void k_cvtw(CvtArgs a, const int* flag, float* w){
  static constexpr int offs[30] = {
    OW_SC_LN_G,OW_SC_LN_B,OW_SC_W,OW_SC_B,OW_BB_LN_G,OW_BB_LN_B,OW_BB_W,OW_BB_B,
    OW_E_LN_G,OW_E_LN_B,OW_EW1,OW_EB1,OW_GW,OW_GB,OW_BGW,OW_BGB,OW_IW1,OW_IB1,
    OW_IW2,OW_IB2,OW_AW,OW_AB,OW_BAW,OW_BAB,OW_CW,OW_CB,OW_XW,OW_XB,OW_RES,OW_TOT};
  int f32=*flag;
  for(int t=blockIdx.x*blockDim.x+threadIdx.x; t<OW_TOT; t+=gridDim.x*blockDim.x){
    int s=0;
    while(t>=offs[s+1]) s++;
    w[t]=ldin(a.src[s], t-offs[s], f32);
  }
}

// W[K x 128] -> MFMA fragment order (zero-padded past Kreal), split hi/lo bf16.
DEVI void wprep_pad(const float* W, int Kreal, unsigned short* hi, unsigned short* lo, int idx){
  int lane=idx&63, nt=(idx>>6)&7, kt=idx>>9;
  int n = nt*16 + (lane&15);
  int kbase = kt*32 + (lane>>4)*8;
  #pragma unroll
  for(int i=0;i<8;i++){
    int k=kbase+i;
    float v = (k<Kreal) ? W[(long)k*128 + n] : 0.f;
    unsigned short h = f2bf(v);
    float r = v - bf2f(h);
    hi[(long)idx*8+i]=h;
    lo[(long)idx*8+i]=f2bf(r);
  }
}

// ---------- mega prep kernel: wprep | prevec | preP | LN ----------
constexpr int PB_WP = 46;                  // wprep: 46*256 >= 11776
constexpr int PB_PV = PB_WP+1;             // prevec: 1 block
constexpr int PB_PP = PB_PV+441;           // preP: 441 blocks
constexpr int PB_LN = PB_PP + (2*N_+3)/4;  // ln: 25000 blocks

__global__ void k_prep(const float* w, const int* flag,
    unsigned short* g_hi, unsigned short* g_lo,
    unsigned short* bg_hi, unsigned short* bg_lo,
    unsigned short* i2_hi, unsigned short* i2_lo,
    unsigned short* i1_hi, unsigned short* i1_lo,
    unsigned short* sc_hi, unsigned short* sc_lo,
    unsigned short* bb_hi, unsigned short* bb_lo,
    const void* eW2, const void* eb2, const void* euW, const void* eub,
    float* dv, float* dv4, float* P, float* sp, float* qp,
    const void* vcom, const void* sbfchi,
    const void* xca, const void* vcb, const void* sphi, const void* spsi,
    float* xn_sc, float* xn_bb){
  __shared__ float pv[64];
  int b=blockIdx.x;
  if(b<PB_WP){
    int idx=b*256+threadIdx.x;
    if(idx<2048)       wprep_pad(w+OW_GW,  128, g_hi,  g_lo,  idx);
    else if(idx<4096)  wprep_pad(w+OW_BGW, 128, bg_hi, bg_lo, idx-2048);
    else if(idx<6144)  wprep_pad(w+OW_IW2, 128, i2_hi, i2_lo, idx-4096);
    else if(idx<10240) wprep_pad(w+OW_IW1, 256, i1_hi, i1_lo, idx-6144);
    else if(idx<10752) wprep_pad(w+OW_SC_W, 19, sc_hi, sc_lo, idx-10240);
    else if(idx<11776) wprep_pad(w+OW_BB_W, 38, bb_hi, bb_lo, idx-10752);
  } else if(b<PB_PV){
    int j=threadIdx.x; int f32=*flag;
    if(j<128){
      const float* g=w+OW_E_LN_G; const float* bb=w+OW_E_LN_B; const float* W1=w+OW_EW1;
      float A=g[0]*W1[j], C=g[1]*W1[128+j];
      float G=0,B=0;
      for(int i=0;i<66;i++){ float wij=W1[i*128+j]; G+=g[i]*wij; B+=bb[i]*wij; }
      B += w[OW_EB1+j];
      float v2=0; for(int k=0;k<128;k++) v2+=ldin(eW2,(long)j*128+k,f32);
      float us=0,ud=0;
      for(int k=0;k<128;k++){ us+=ldin(euW,(long)j*128+k,f32); ud+=ldin(euW,(long)(128+j)*128+k,f32); }
      dv[640+j]=us*(1.f/128.f); dv[768+j]=ud*(1.f/128.f);
      int j4=j>>2, r=j&3;
      dv4[j4*20+0+r]=A; dv4[j4*20+4+r]=C; dv4[j4*20+8+r]=G; dv4[j4*20+12+r]=B;
      dv4[j4*20+16+r]=v2*(1.f/128.f);
      if(j==0){
        float s=0,t=0;
        for(int k=0;k<128;k++){ s+=ldin(eb2,k,f32); t+=ldin(eub,k,f32); }
        dv[896]=s*(1.f/128.f); dv[897]=t*(1.f/128.f);
        dv4[640]=s*(1.f/128.f);
      }
    }
  } else if(b<PB_PP){
    int c=b-PB_PV, j=threadIdx.x;
    const float* res=w+OW_RES;
    if(j<32) pv[j]=res[(c/NRES)*32+j];
    else if(j<64) pv[j]=res[(c%NRES)*32+(j-32)];
    __syncthreads();
    if(j<128){
      const float* g=w+OW_E_LN_G; const float* W1=w+OW_EW1;
      float s=0;
      for(int i=0;i<64;i++) s += pv[i]*g[2+i]*W1[(2+i)*128+j];
      P[c*128+j]=s;
      if(j==0){ float a=0,q=0; for(int i=0;i<64;i++){a+=pv[i]; q+=pv[i]*pv[i];} sp[c]=a; qp[c]=q; }
    }
  } else {
    int wv=threadIdx.x>>6, lane=threadIdx.x&63;
    long gw=(long)(b-PB_PP)*4+wv;
    int f32=*flag;
    if(gw<N_){
      int n=(int)gw;
      float x=0.f;
      if(lane<3) x=ldin(vcom,(long)n*3+lane,f32);
      else if(lane<19) x=ldin(sbfchi,(long)n*16+(lane-3),f32);
      float s=x, q=x*x;
      for(int m=1;m<64;m<<=1){ s+=__shfl_xor(s,m,64); q+=__shfl_xor(q,m,64); }
      float mean=s*(1.f/19.f);
      float istd=rsqrtf(fmaxf(q*(1.f/19.f)-mean*mean,0.f)+1e-5f);
      if(lane<32){
        float xn=(lane<19)? (x-mean)*istd*w[OW_SC_LN_G+lane]+w[OW_SC_LN_B+lane] : 0.f;
        xn_sc[(long)n*32+lane]=xn;
      }
    } else if(gw<2L*N_){
      int n=(int)(gw-N_);
      float x=0.f;
      if(lane<3) x=ldin(xca,(long)n*3+lane,f32);
      else if(lane<6) x=ldin(vcb,(long)n*3+(lane-3),f32);
      else if(lane<22) x=ldin(sphi,(long)n*16+(lane-6),f32);
      else if(lane<38) x=ldin(spsi,(long)n*16+(lane-22),f32);
      float s=x, q=x*x;
      for(int m=1;m<64;m<<=1){ s+=__shfl_xor(s,m,64); q+=__shfl_xor(q,m,64); }
      float mean=s*(1.f/38.f);
      float istd=rsqrtf(fmaxf(q*(1.f/38.f)-mean*mean,0.f)+1e-5f);
      float xn=(lane<38)? (x-mean)*istd*w[OW_BB_LN_G+lane]+w[OW_BB_LN_B+lane] : 0.f;
      xn_bb[(long)n*64+lane]=xn;
    }
  }
}

// ---------- stable 2-pass radix CSR build ----------
__global__ void k_rhist(const int* key_sc, const int* key_bb, int shift, int* hist){
  __shared__ int h[256];
  h[threadIdx.x]=0; __syncthreads();
  int g = blockIdx.x>=RBS;
  const int* key = g? key_bb : key_sc;
  int E = g? EBB : ESC;
  int b = g? blockIdx.x-RBS : blockIdx.x;
  int base=b*RCH;
  for(int r=0;r<16;r++){
    int idx=base+r*256+threadIdx.x;
    if(idx<E) atomicAdd(&h[(key[idx]>>shift)&255],1);
  }
  __syncthreads();
  hist[(long)blockIdx.x*256+threadIdx.x]=h[threadIdx.x];
}
__global__ void k_rscan(int* hist){
  __shared__ int tot[256], base[256];
  int d=threadIdx.x;
  int run=0;
  for(int b=0;b<RBS;b++){ int v=hist[b*256+d]; hist[b*256+d]=run; run+=v; }
  tot[d]=run; __syncthreads();
  if(d==0){ int r=0; for(int i=0;i<256;i++){ base[i]=r; r+=tot[i]; } }
  __syncthreads();
  for(int b=0;b<RBS;b++) hist[b*256+d]+=base[d];
  __syncthreads();
  int* H=hist+RBS*256;
  run=0;
  for(int b=0;b<RBB;b++){ int v=H[b*256+d]; H[b*256+d]=run; run+=v; }
  tot[d]=run; __syncthreads();
  if(d==0){ int r=0; for(int i=0;i<256;i++){ base[i]=r; r+=tot[i]; } }
  __syncthreads();
  for(int b=0;b<RBB;b++) H[b*256+d]+=base[d];
}
__global__ void k_rscat(int shift, int first,
    const int* kin_sc, const int* srcv_sc, const int2* pin_sc,
    const int* kin_bb, const int* srcv_bb, const int2* pin_bb,
    const int* hist,
    int* kout_sc, int2* pout_sc, int* kout_bb, int2* pout_bb){
  __shared__ int running[256];
  __shared__ int Hb[256];
  __shared__ int whist[4][256];
  __shared__ int pw[4][256];
  int tid=threadIdx.x, lane=tid&63, w=tid>>6;
  int g = blockIdx.x>=RBS;
  const int* kin  = g? kin_bb : kin_sc;
  const int* srcv = g? srcv_bb: srcv_sc;
  const int2* pin = g? pin_bb : pin_sc;
  int* kout  = g? kout_bb : kout_sc;
  int2* pout = g? pout_bb : pout_sc;
  int E = g? EBB : ESC;
  int b = g? blockIdx.x-RBS : blockIdx.x;
  running[tid]=0;
  Hb[tid]=hist[(long)blockIdx.x*256+tid];
  int base=b*RCH;
  for(int r=0;r<16;r++){
    __syncthreads();
    whist[0][tid]=0; whist[1][tid]=0; whist[2][tid]=0; whist[3][tid]=0;
    __syncthreads();
    int idx=base+r*256+tid;
    bool valid = idx<E;
    int key=0, digit=0; int2 pay; pay.x=0; pay.y=0;
    if(valid){
      key=kin[idx];
      digit=(key>>shift)&255;
      if(first){ pay.x=srcv[idx]; pay.y=idx; }
      else pay=pin[idx];
    }
    unsigned long long act=__ballot(valid);
    unsigned long long same=act;
    #pragma unroll
    for(int k=0;k<8;k++){
      unsigned long long m=__ballot(valid && ((digit>>k)&1));
      same &= ((digit>>k)&1)? m : ~m;
    }
    same &= act;
    unsigned long long below=(1ULL<<lane)-1ULL;
    int wrank=__popcll(same & below);
    if(valid && wrank==0) whist[w][digit]=__popcll(same);
    __syncthreads();
    int c0=whist[0][tid], c1=whist[1][tid], c2=whist[2][tid], c3=whist[3][tid];
    pw[0][tid]=0; pw[1][tid]=c0; pw[2][tid]=c0+c1; pw[3][tid]=c0+c1+c2;
    __syncthreads();
    if(valid){
      int pos=Hb[digit]+running[digit]+pw[w][digit]+wrank;
      kout[pos]=key; pout[pos]=pay;
    }
    __syncthreads();
    running[tid]+=c0+c1+c2+c3;
  }
}
__global__ void k_bounds(const int* dstS_sc, const int* dstS_bb, int* rp_sc, int* rp_bb){
  long i=(long)blockIdx.x*blockDim.x+threadIdx.x;
  if(i<=ESC){
    int cur = (i<ESC)? dstS_sc[i] : N_;
    int prev= (i>0)? dstS_sc[i-1] : -1;
    for(int d=prev+1; d<=cur; d++) rp_sc[d]=(int)i;
  } else if(i <= (long)ESC+1+EBB){
    long j=i-(ESC+1);
    int cur = (j<EBB)? dstS_bb[j] : N_;
    int prev= (j>0)? dstS_bb[j-1] : -1;
    for(int d=prev+1; d<=cur; d++) rp_bb[d]=(int)j;
  }
}

// ---------- w0 edge-MLP + deg_bb (merged) ----------
constexpr int WB_ = (ESC+255)/256;
constexpr int DB_ = (N_+255)/256;
__global__ void k_w0deg(const void* dsc, const void* dmin, const int* ri_, const int* rj_,
                        const int* flag, const float* dv4, const float* P,
                        const float* sp, const float* qp, float* we,
                        const int* rp_bb, float* disb){
  if(blockIdx.x < WB_){
    int e=blockIdx.x*blockDim.x+threadIdx.x;
    if(e>=ESC) return;
    int f32=*flag;
    float d1=ldin(dsc,e,f32), d2=ldin(dmin,e,f32);
    int c=ri_[e]*NRES+rj_[e];
    float m=(d1+d2+sp[c])*(1.f/66.f);
    float ms=(d1*d1+d2*d2+qp[c])*(1.f/66.f);
    float istd=rsqrtf(fmaxf(ms-m*m,0.f)+1e-5f);
    float nmi=-m*istd;
    const float4* Pr=(const float4*)&P[(long)c*128];
    float acc=0.f;
    #pragma unroll 8
    for(int j4=0;j4<32;j4++){
      const float4* q=(const float4*)&dv4[j4*20];
      float4 A4=q[0], C4=q[1], G4=q[2], B4=q[3], V4=q[4];
      float4 P4=Pr[j4];
      float t,hid;
      t=fmaf(d1,A4.x,fmaf(d2,C4.x,P4.x)); hid=fmaf(istd,t,fmaf(nmi,G4.x,B4.x)); acc=fmaf(fmaxf(hid,0.f),V4.x,acc);
      t=fmaf(d1,A4.y,fmaf(d2,C4.y,P4.y)); hid=fmaf(istd,t,fmaf(nmi,G4.y,B4.y)); acc=fmaf(fmaxf(hid,0.f),V4.y,acc);
      t=fmaf(d1,A4.z,fmaf(d2,C4.z,P4.z)); hid=fmaf(istd,t,fmaf(nmi,G4.z,B4.z)); acc=fmaf(fmaxf(hid,0.f),V4.z,acc);
      t=fmaf(d1,A4.w,fmaf(d2,C4.w,P4.w)); hid=fmaf(istd,t,fmaf(nmi,G4.w,B4.w)); acc=fmaf(fmaxf(hid,0.f),V4.w,acc);
    }
    we[e]=acc+dv4[640];
  } else {
    int n=(blockIdx.x-WB_)*blockDim.x+threadIdx.x;
    if(n>=N_) return;
    float s=1.f+(float)(rp_bb[n+1]-rp_bb[n]);
    disb[n]=rsqrtf(fmaxf(s,1e-6f));
  }
}

// ---------- split-bf16 MFMA GEMM core ----------
DEVI f32x4 MFMA(short8v a, short8v b, f32x4 c){
  return __builtin_amdgcn_mfma_f32_16x16x32_bf16(a,b,c,0,0,0);
}
DEVI void cvt8(float4 a0, float4 a1, short8v& hi, short8v& lo){
  float av[8]={a0.x,a0.y,a0.z,a0.w,a1.x,a1.y,a1.z,a1.w};
  union{short8v v; unsigned short u[8];} H,L;
  #pragma unroll
  for(int i=0;i<8;i++){
    unsigned short h=f2bf(av[i]);
    float r=av[i]-bf2f(h);
    H.u[i]=h; L.u[i]=f2bf(r);
  }
  hi=H.v; lo=L.v;
}

template<int KT, int LDA>
DEVI void mgemm_body(int bid, const float* A1, const float* A2,
    const unsigned short* Whi, const unsigned short* Wlo,
    const float* bias, float* C, int relu, int accum, int M){
  const int lane = threadIdx.x & 63;
  const int wid  = threadIdx.x >> 6;
  const int r0   = bid*64 + wid*16;
  const int mrow = lane & 15;
  const int kg   = lane >> 4;
  long arow = (long)min(r0 + mrow, M-1);
  f32x4 acc[8];
  #pragma unroll
  for(int t=0;t<8;t++) acc[t]=(f32x4){0.f,0.f,0.f,0.f};

  #pragma unroll
  for(int kt=0; kt<KT; kt++){
    const float* A = (KT==8 && kt>=4) ? A2 : A1;
    int kb = (kt&3)*32 + kg*8;
    float4 a0 = *(const float4*)&A[arow*LDA + kb];
    float4 a1 = *(const float4*)&A[arow*LDA + kb + 4];
    short8v ah, al; cvt8(a0,a1,ah,al);
    #pragma unroll
    for(int nt=0;nt<8;nt++){
      long off = (((long)kt*8+nt)*64 + lane)*8;
      short8v wh = *(const short8v*)&Whi[off];
      short8v wl = *(const short8v*)&Wlo[off];
      acc[nt] = MFMA(ah, wh, acc[nt]);
      acc[nt] = MFMA(al, wh, acc[nt]);
      acc[nt] = MFMA(ah, wl, acc[nt]);
      acc[nt] = MFMA(al, wl, acc[nt]);
    }
  }

  #pragma unroll
  for(int nt=0;nt<8;nt++){
    int col = nt*16 + mrow;
    float bj = bias ? bias[col] : 0.f;
    #pragma unroll
    for(int r=0;r<4;r++){
      int row = r0 + kg*4 + r;
      if(row >= M) continue;
      long idx = (long)row*128 + col;
      float v = acc[nt][r] + bj;
      if(relu) v = fmaxf(v,0.f);
      if(accum) v += C[idx];
      C[idx] = v;
    }
  }
}

// featurizer: both small GEMMs in one launch
__global__ __launch_bounds__(256,4) void k_mfeat(const float* xn_sc, const float* xn_bb,
    const unsigned short* schi, const unsigned short* sclo,
    const unsigned short* bbhi, const unsigned short* bblo,
    const float* w, float* hat_h, float* hbuf, int M){
  int GBl=(M+63)/64;
  if((int)blockIdx.x < GBl)
    mgemm_body<1,32>(blockIdx.x, xn_sc, nullptr, schi, sclo, w+OW_SC_B, hat_h, 0,0,M);
  else
    mgemm_body<2,64>(blockIdx.x-GBl, xn_bb, nullptr, bbhi, bblo, w+OW_BB_B, hbuf, 0,0,M);
}

// sc layer: gW GEMM overlapped with degree pass (independent producers)
__global__ __launch_bounds__(256,4) void k_gemmdeg(const float* hat_h,
    const unsigned short* Whi, const unsigned short* Wlo, float* C, int M,
    const int* rp, const int2* se, const float* we_edge,
    const float* an, const float* bn, const float* dv,
    float* we_csr, float* dis, int layer){
  int GBl=(M+63)/64;
  if((int)blockIdx.x < GBl){
    mgemm_body<4,128>(blockIdx.x, hat_h, nullptr, Whi, Wlo, nullptr, C, 0, 0, M);
  } else {
    int n=(blockIdx.x-GBl)*blockDim.x+threadIdx.x;
    if(n>=N_) return;
    int e0=rp[n], e1=rp[n+1];
    float s=1.f;
    if(layer==0){
      for(int p=e0;p<e1;p++){ float ww=we_edge[se[p].y]; we_csr[p]=ww; s+=ww; }
    } else {
      float add_n = bn[n] + dv[897];
      for(int p=e0;p<e1;p++){
        float ww=we_csr[p] + an[se[p].x] + add_n;
        we_csr[p]=ww; s+=ww;
      }
    }
    dis[n]=rsqrtf(fmaxf(s,1e-6f));
  }
}

// fused bb layer: hidden=relu([h|hh]@iW1+b1) (regs->LDS), m=hidden@iW2+b2 -> mout,
// xw=h@bgW -> xwout.  (h update happens in k_agg_bb: h += relu(agg)+m)
__global__ __launch_bounds__(256,2) void k_mbb(const float* h, const float* hh,
    const unsigned short* W1hi, const unsigned short* W1lo,
    const unsigned short* W2hi, const unsigned short* W2lo,
    const unsigned short* W3hi, const unsigned short* W3lo,
    const float* b1, const float* b2,
    float* xwout, float* mout, int M){
  __shared__ float hid[64*132];
  const int lane = threadIdx.x & 63;
  const int wid  = threadIdx.x >> 6;
  const int r0   = blockIdx.x*64 + wid*16;
  const int mrow = lane & 15;
  const int kg   = lane >> 4;
  long arow = (long)min(r0 + mrow, M-1);
  f32x4 acc1[8], acc2[8];
  #pragma unroll
  for(int t=0;t<8;t++){ acc1[t]=(f32x4){0,0,0,0}; acc2[t]=(f32x4){0,0,0,0}; }

  #pragma unroll
  for(int kt=0; kt<8; kt++){
    const float* A = (kt>=4) ? hh : h;
    int kb = (kt&3)*32 + kg*8;
    float4 a0 = *(const float4*)&A[arow*128 + kb];
    float4 a1 = *(const float4*)&A[arow*128 + kb + 4];
    short8v ah, al; cvt8(a0,a1,ah,al);
    #pragma unroll
    for(int nt=0;nt<8;nt++){
      long off = (((long)kt*8+nt)*64 + lane)*8;
      short8v wh = *(const short8v*)&W1hi[off];
      short8v wl = *(const short8v*)&W1lo[off];
      acc1[nt] = MFMA(ah, wh, acc1[nt]);
      acc1[nt] = MFMA(al, wh, acc1[nt]);
      acc1[nt] = MFMA(ah, wl, acc1[nt]);
      acc1[nt] = MFMA(al, wl, acc1[nt]);
    }
    if(kt<4){
      #pragma unroll
      for(int nt=0;nt<8;nt++){
        long off = (((long)kt*8+nt)*64 + lane)*8;
        short8v wh = *(const short8v*)&W2hi[off];
        short8v wl = *(const short8v*)&W2lo[off];
        acc2[nt] = MFMA(ah, wh, acc2[nt]);
        acc2[nt] = MFMA(al, wh, acc2[nt]);
        acc2[nt] = MFMA(ah, wl, acc2[nt]);
        acc2[nt] = MFMA(al, wl, acc2[nt]);
      }
    }
  }

  // write xw to global; hidden (relu+b1) to LDS
  #pragma unroll
  for(int nt=0;nt<8;nt++){
    int col = nt*16 + mrow;
    float bj = b1[col];
    #pragma unroll
    for(int r=0;r<4;r++){
      int rloc = wid*16 + kg*4 + r;
      int row = r0 + kg*4 + r;
      hid[rloc*132 + col] = fmaxf(acc1[nt][r] + bj, 0.f);
      if(row < M) xwout[(long)row*128 + col] = acc2[nt][r];
    }
  }
  __syncthreads();

  // m = hidden @ iW2 + b2
  f32x4 acc3[8];
  #pragma unroll
  for(int t=0;t<8;t++) acc3[t]=(f32x4){0,0,0,0};
  int rloc = wid*16 + mrow;
  #pragma unroll
  for(int kt=0; kt<4; kt++){
    int kb = kt*32 + kg*8;
    float4 a0 = *(const float4*)&hid[rloc*132 + kb];
    float4 a1 = *(const float4*)&hid[rloc*132 + kb + 4];
    short8v ah, al; cvt8(a0,a1,ah,al);
    #pragma unroll
    for(int nt=0;nt<8;nt++){
      long off = (((long)kt*8+nt)*64 + lane)*8;
      short8v wh = *(const short8v*)&W3hi[off];
      short8v wl = *(const short8v*)&W3lo[off];
      acc3[nt] = MFMA(ah, wh, acc3[nt]);
      acc3[nt] = MFMA(al, wh, acc3[nt]);
      acc3[nt] = MFMA(ah, wl, acc3[nt]);
      acc3[nt] = MFMA(al, wl, acc3[nt]);
    }
  }
  #pragma unroll
  for(int nt=0;nt<8;nt++){
    int col = nt*16 + mrow;
    float bj = b2[col];
    #pragma unroll
    for(int r=0;r<4;r++){
      int row = r0 + kg*4 + r;
      if(row < M) mout[(long)row*128 + col] = acc3[nt][r] + bj;
    }
  }
}

// ---------- aggregation: 16 lanes/edge, 4 edges in flight ----------
__global__ void k_agg_sc(const int* rp, const int2* se, const float* wc,
                         const float* dis, const float* xw, const float* w,
                         float* hat_h, const float* dv, float* an, float* bn, int withdot){
  int wv=threadIdx.x>>6, lane=threadIdx.x&63;
  int n=blockIdx.x*4+wv;
  int g=lane>>4, l=lane&15, d0=l*8;
  float disn=dis[n];
  float4 aA={0,0,0,0}, aB={0,0,0,0};
  int e0=rp[n], e1=rp[n+1];
  for(int p=e0+g; p<e1; p+=4){
    int s0=se[p].x;
    float nw=dis[s0]*wc[p]*disn;
    float4 xa=*(const float4*)&xw[(long)s0*128+d0];
    float4 xb=*(const float4*)&xw[(long)s0*128+d0+4];
    aA.x+=nw*xa.x; aA.y+=nw*xa.y; aA.z+=nw*xa.z; aA.w+=nw*xa.w;
    aB.x+=nw*xb.x; aB.y+=nw*xb.y; aB.z+=nw*xb.z; aB.w+=nw*xb.w;
  }
  #pragma unroll
  for(int m=16;m<64;m<<=1){
    aA.x+=__shfl_xor(aA.x,m,64); aA.y+=__shfl_xor(aA.y,m,64);
    aA.z+=__shfl_xor(aA.z,m,64); aA.w+=__shfl_xor(aA.w,m,64);
    aB.x+=__shfl_xor(aB.x,m,64); aB.y+=__shfl_xor(aB.y,m,64);
    aB.z+=__shfl_xor(aB.z,m,64); aB.w+=__shfl_xor(aB.w,m,64);
  }
  float d2=disn*disn;
  float4 xsA=*(const float4*)&xw[(long)n*128+d0];
  float4 xsB=*(const float4*)&xw[(long)n*128+d0+4];
  float4 gbA=*(const float4*)&w[OW_GB+d0];
  float4 gbB=*(const float4*)&w[OW_GB+d0+4];
  float4 hoA=*(const float4*)&hat_h[(long)n*128+d0];
  float4 hoB=*(const float4*)&hat_h[(long)n*128+d0+4];
  float4 hA, hB;
  hA.x=hoA.x+fmaxf(aA.x+d2*xsA.x+gbA.x,0.f);
  hA.y=hoA.y+fmaxf(aA.y+d2*xsA.y+gbA.y,0.f);
  hA.z=hoA.z+fmaxf(aA.z+d2*xsA.z+gbA.z,0.f);
  hA.w=hoA.w+fmaxf(aA.w+d2*xsA.w+gbA.w,0.f);
  hB.x=hoB.x+fmaxf(aB.x+d2*xsB.x+gbB.x,0.f);
  hB.y=hoB.y+fmaxf(aB.y+d2*xsB.y+gbB.y,0.f);
  hB.z=hoB.z+fmaxf(aB.z+d2*xsB.z+gbB.z,0.f);
  hB.w=hoB.w+fmaxf(aB.w+d2*xsB.w+gbB.w,0.f);
  if(g==0){
    *(float4*)&hat_h[(long)n*128+d0]=hA;
    *(float4*)&hat_h[(long)n*128+d0+4]=hB;
  }
  if(withdot){
    float4 usA=*(const float4*)&dv[640+d0], usB=*(const float4*)&dv[640+d0+4];
    float4 udA=*(const float4*)&dv[768+d0], udB=*(const float4*)&dv[768+d0+4];
    float a = hA.x*usA.x+hA.y*usA.y+hA.z*usA.z+hA.w*usA.w
            + hB.x*usB.x+hB.y*usB.y+hB.z*usB.z+hB.w*usB.w;
    float b = hA.x*udA.x+hA.y*udA.y+hA.z*udA.z+hA.w*udA.w
            + hB.x*udB.x+hB.y*udB.y+hB.z*udB.z+hB.w*udB.w;
    #pragma unroll
    for(int m=1;m<16;m<<=1){ a+=__shfl_xor(a,m,64); b+=__shfl_xor(b,m,64); }
    if(lane==0){ an[n]=a; bn[n]=b; }
  }
}

__global__ void k_agg_bb(const int* rp, const int2* se, const float* dis,
                         const float* xw, const float* mbuf, const float* w, float* h){
  int wv=threadIdx.x>>6, lane=threadIdx.x&63;
  int n=blockIdx.x*4+wv;
  int g=lane>>4, l=lane&15, d0=l*8;
  float disn=dis[n];
  float4 aA={0,0,0,0}, aB={0,0,0,0};
  int e0=rp[n], e1=rp[n+1];
  for(int p=e0+g; p<e1; p+=4){
    int s0=se[p].x;
    float nw=dis[s0]*disn;
    float4 xa=*(const float4*)&xw[(long)s0*128+d0];
    float4 xb=*(const float4*)&xw[(long)s0*128+d0+4];
    aA.x+=nw*xa.x; aA.y+=nw*xa.y; aA.z+=nw*xa.z; aA.w+=nw*xa.w;
    aB.x+=nw*xb.x; aB.y+=nw*xb.y; aB.z+=nw*xb.z; aB.w+=nw*xb.w;
  }
  #pragma unroll
  for(int m=16;m<64;m<<=1){
    aA.x+=__shfl_xor(aA.x,m,64); aA.y+=__shfl_xor(aA.y,m,64);
    aA.z+=__shfl_xor(aA.z,m,64); aA.w+=__shfl_xor(aA.w,m,64);
    aB.x+=__shfl_xor(aB.x,m,64); aB.y+=__shfl_xor(aB.y,m,64);
    aB.z+=__shfl_xor(aB.z,m,64); aB.w+=__shfl_xor(aB.w,m,64);
  }
  if(g==0){
    float d2=disn*disn;
    float4 xsA=*(const float4*)&xw[(long)n*128+d0];
    float4 xsB=*(const float4*)&xw[(long)n*128+d0+4];
    float4 gbA=*(const float4*)&w[OW_BGB+d0];
    float4 gbB=*(const float4*)&w[OW_BGB+d0+4];
    float4 mA=*(const float4*)&mbuf[(long)n*128+d0];
    float4 mB=*(const float4*)&mbuf[(long)n*128+d0+4];
    float4 hA=*(float4*)&h[(long)n*128+d0];
    float4 hB=*(float4*)&h[(long)n*128+d0+4];
    hA.x+=fmaxf(aA.x+d2*xsA.x+gbA.x,0.f)+mA.x;
    hA.y+=fmaxf(aA.y+d2*xsA.y+gbA.y,0.f)+mA.y;
    hA.z+=fmaxf(aA.z+d2*xsA.z+gbA.z,0.f)+mA.z;
    hA.w+=fmaxf(aA.w+d2*xsA.w+gbA.w,0.f)+mA.w;
    hB.x+=fmaxf(aB.x+d2*xsB.x+gbB.x,0.f)+mB.x;
    hB.y+=fmaxf(aB.y+d2*xsB.y+gbB.y,0.f)+mB.y;
    hB.z+=fmaxf(aB.z+d2*xsB.z+gbB.z,0.f)+mB.z;
    hB.w+=fmaxf(aB.w+d2*xsB.w+gbB.w,0.f)+mB.w;
    *(float4*)&h[(long)n*128+d0]=hA;
    *(float4*)&h[(long)n*128+d0+4]=hB;
  }
}

__global__ void k_heads(const float* hat_h, const float* h, const float* w,
                        const void* old_chi, const void* old_phi, const void* old_psi,
                        const void* old_cb, const void* old_ca, const int* flag, void* out){
  int wv=threadIdx.x>>6, lane=threadIdx.x&63;
  int n=blockIdx.x*4+wv;
  int f32=*flag;
  float s0=fmaxf(hat_h[(long)n*128+lane],0.f), s1=fmaxf(hat_h[(long)n*128+64+lane],0.f);
  float b0=fmaxf(h[(long)n*128+lane],0.f),    b1=fmaxf(h[(long)n*128+64+lane],0.f);
  float r[8];
  r[0]=s0*w[OW_AW+lane]+s1*w[OW_AW+64+lane];
  r[1]=s0*w[OW_CW+lane*3+0]+s1*w[OW_CW+(64+lane)*3+0];
  r[2]=s0*w[OW_CW+lane*3+1]+s1*w[OW_CW+(64+lane)*3+1];
  r[3]=s0*w[OW_CW+lane*3+2]+s1*w[OW_CW+(64+lane)*3+2];
  r[4]=b0*w[OW_BAW+lane]+b1*w[OW_BAW+64+lane];
  r[5]=b0*w[OW_XW+lane*3+0]+b1*w[OW_XW+(64+lane)*3+0];
  r[6]=b0*w[OW_XW+lane*3+1]+b1*w[OW_XW+(64+lane)*3+1];
  r[7]=b0*w[OW_XW+lane*3+2]+b1*w[OW_XW+(64+lane)*3+2];
  for(int m=1;m<64;m<<=1){
    #pragma unroll
    for(int t=0;t<8;t++) r[t]+=__shfl_xor(r[t],m,64);
  }
  if(lane==0){
    float dchi=r[0]+w[OW_AB];
    for(int k=0;k<4;k++)
      stout(out,(long)k*N_+n, wrapf(ldin(old_chi,(long)k*N_+n,f32)+dchi), f32);
    float dphi=r[4]+w[OW_BAB];
    stout(out,(long)4*N_+n, wrapf(ldin(old_phi,n,f32)+dphi), f32);
    stout(out,(long)5*N_+n, wrapf(ldin(old_psi,n,f32)+dphi), f32);
    for(int t=0;t<3;t++){
      stout(out,(long)6*N_+(long)n*3+t, ldin(old_cb,(long)n*3+t,f32)+r[1+t]+w[OW_CB+t], f32);
      stout(out,(long)9*N_+(long)n*3+t, ldin(old_ca,(long)n*3+t,f32)+r[5+t]+w[OW_XB+t], f32);
    }
  }
}

// ---------- host ----------
extern "C" void kernel_launch(void* const* d_in, const int* in_sizes, int n_in,
                              void* d_out, int out_size, void* d_ws, size_t ws_size,
                              hipStream_t stream) {
  (void)in_sizes; (void)n_in; (void)out_size; (void)ws_size;

  char* p=(char*)d_ws;
  auto alloc=[&](size_t bytes)->void*{ void* r=(void*)p; p+=((bytes+255)&~(size_t)255); return r; };
  int*   flag   =(int*)  alloc(16);
  float* warena =(float*)alloc((size_t)OW_TOT*4);
  float* dv     =(float*)alloc(1024*4);
  float* dv4    =(float*)alloc(1024*4);
  float* P      =(float*)alloc((size_t)441*128*4);
  float* sp     =(float*)alloc(441*4);
  float* qp     =(float*)alloc(441*4);
  float* hat_h  =(float*)alloc((size_t)N_*128*4);
  float* hbuf   =(float*)alloc((size_t)N_*128*4);
  float* bufX   =(float*)alloc((size_t)N_*128*4);
  float* bufM   =(float*)alloc((size_t)N_*128*4);
  float* xn_sc  =(float*)alloc((size_t)N_*32*4);
  float* xn_bb  =(float*)alloc((size_t)N_*64*4);
  float* we     =(float*)alloc((size_t)ESC*4);
  float* we_csr =(float*)alloc((size_t)ESC*4);
  float* an     =(float*)alloc((size_t)N_*4);
  float* bn     =(float*)alloc((size_t)N_*4);
  float* dis    =(float*)alloc((size_t)N_*4);
  float* disb   =(float*)alloc((size_t)N_*4);
  int* rp_sc    =(int*)  alloc((size_t)(N_+1)*4);
  int* rp_bb    =(int*)  alloc((size_t)(N_+1)*4);
  int*  key1_sc =(int*)  alloc((size_t)ESC*4);
  int2* pay1_sc =(int2*) alloc((size_t)ESC*8);
  int*  dstS_sc =(int*)  alloc((size_t)ESC*4);
  int2* csr_se_sc=(int2*)alloc((size_t)ESC*8);
  int*  key1_bb =(int*)  alloc((size_t)EBB*4);
  int2* pay1_bb =(int2*) alloc((size_t)EBB*8);
  int*  dstS_bb =(int*)  alloc((size_t)EBB*4);
  int2* csr_se_bb=(int2*)alloc((size_t)EBB*8);
  int*  hist    =(int*)  alloc((size_t)(RBS+RBB)*256*4);
  unsigned short* wfg_hi =(unsigned short*)alloc(2048*8*2);
  unsigned short* wfg_lo =(unsigned short*)alloc(2048*8*2);
  unsigned short* wfbg_hi=(unsigned short*)alloc(2048*8*2);
  unsigned short* wfbg_lo=(unsigned short*)alloc(2048*8*2);
  unsigned short* wfi2_hi=(unsigned short*)alloc(2048*8*2);
  unsigned short* wfi2_lo=(unsigned short*)alloc(2048*8*2);
  unsigned short* wfi1_hi=(unsigned short*)alloc(4096*8*2);
  unsigned short* wfi1_lo=(unsigned short*)alloc(4096*8*2);
  unsigned short* wfsc_hi=(unsigned short*)alloc(512*8*2);
  unsigned short* wfsc_lo=(unsigned short*)alloc(512*8*2);
  unsigned short* wfbb_hi=(unsigned short*)alloc(1024*8*2);
  unsigned short* wfbb_lo=(unsigned short*)alloc(1024*8*2);

  const int* src_sc=(const int*)d_in[48];
  const int* dst_sc=src_sc+ESC;
  const int* src_bb=(const int*)d_in[49];
  const int* dst_bb=src_bb+EBB;

  k_detect<<<1,1,0,stream>>>(d_in[0], flag);

  CvtArgs ca;
  {
    int map[29]={14,15,16,17,18,19,20,21,22,23,24,25,30,31,32,33,34,35,36,37,
                 38,39,40,41,42,43,44,45,13};
    for(int i=0;i<29;i++) ca.src[i]=d_in[map[i]];
  }
  k_cvtw<<<(OW_TOT+255)/256,256,0,stream>>>(ca, flag, warena);

  // mega prep: wprep | prevec | preP | LN
  k_prep<<<PB_LN,256,0,stream>>>(warena, flag,
      wfg_hi,wfg_lo, wfbg_hi,wfbg_lo, wfi2_hi,wfi2_lo, wfi1_hi,wfi1_lo,
      wfsc_hi,wfsc_lo, wfbb_hi,wfbb_lo,
      d_in[26], d_in[27], d_in[28], d_in[29], dv, dv4, P, sp, qp,
      d_in[0], d_in[1], d_in[2], d_in[3], d_in[4], d_in[5], xn_sc, xn_bb);

  // stable radix CSR build
  k_rhist<<<RBS+RBB,256,0,stream>>>(dst_sc, dst_bb, 0, hist);
  k_rscan<<<1,256,0,stream>>>(hist);
  k_rscat<<<RBS+RBB,256,0,stream>>>(0, 1, dst_sc, src_sc, (const int2*)nullptr,
                                    dst_bb, src_bb, (const int2*)nullptr, hist,
                                    key1_sc, pay1_sc, key1_bb, pay1_bb);
  k_rhist<<<RBS+RBB,256,0,stream>>>(key1_sc, key1_bb, 8, hist);
  k_rscan<<<1,256,0,stream>>>(hist);
  k_rscat<<<RBS+RBB,256,0,stream>>>(8, 0, key1_sc, (const int*)nullptr, pay1_sc,
                                    key1_bb, (const int*)nullptr, pay1_bb, hist,
                                    dstS_sc, csr_se_sc, dstS_bb, csr_se_bb);
  k_bounds<<<(int)(((long)ESC+1+EBB+1+255)/256),256,0,stream>>>(dstS_sc, dstS_bb, rp_sc, rp_bb);

  // featurizer GEMMs (merged)
  const int GB = (N_+63)/64;
  k_mfeat<<<2*GB,256,0,stream>>>(xn_sc, xn_bb, wfsc_hi, wfsc_lo, wfbb_hi, wfbb_lo,
                                 warena, hat_h, hbuf, N_);

  // w0 edge MLP + bb degree (merged)
  k_w0deg<<<WB_+DB_,256,0,stream>>>(d_in[6],d_in[7],(const int*)d_in[46],(const int*)d_in[47],
                                    flag,dv4,P,sp,qp,we, rp_bb, disb);

  // sidechain layers
  for(int l=0;l<3;l++){
    k_gemmdeg<<<GB+DB_,256,0,stream>>>(hat_h, wfg_hi, wfg_lo, bufX, N_,
                                       rp_sc, csr_se_sc, we, an, bn, dv, we_csr, dis, l);
    k_agg_sc<<<N_/4,256,0,stream>>>(rp_sc,csr_se_sc,we_csr,dis,bufX,warena,hat_h,dv,an,bn,(l<2)?1:0);
  }

  // backbone layers (fused GEMM trio + agg)
  for(int l=0;l<2;l++){
    k_mbb<<<GB,256,0,stream>>>(hbuf, hat_h, wfi1_hi, wfi1_lo, wfbg_hi, wfbg_lo,
                               wfi2_hi, wfi2_lo, warena+OW_IB1, warena+OW_IB2,
                               bufX, bufM, N_);
    k_agg_bb<<<N_/4,256,0,stream>>>(rp_bb,csr_se_bb,disb,bufX,bufM,warena,hbuf);
  }

  k_heads<<<N_/4,256,0,stream>>>(hat_h,hbuf,warena,
                                 d_in[8],d_in[9],d_in[10],d_in[11],d_in[12],flag,d_out);
}